// Round 1
// baseline (9377.483 us; speedup 1.0000x reference)
//
#include <hip/hip_runtime.h>
#include <hip/hip_bf16.h>
#include <cstddef>

#define NN 50000
#define EE 400000
#define FF 128
#define HH 8
#define CC 16
#define GG 64

// ---------- helpers ----------
__device__ __forceinline__ unsigned f2key(float f) {
    unsigned u = __float_as_uint(f);
    return (u & 0x80000000u) ? ~u : (u | 0x80000000u);
}
__device__ __forceinline__ float key2f(unsigned k) {
    unsigned u = (k & 0x80000000u) ? (k ^ 0x80000000u) : ~k;
    return __uint_as_float(u);
}

// ---------- M[l][h][d] = sum_c lin_edge[l][h*16+c][d] * att[l][2][h][c] ----------
__global__ void compute_M_kernel(const float* __restrict__ lin_edge,
                                 const float* __restrict__ att,
                                 float* __restrict__ M) {
    int t = blockIdx.x * 256 + threadIdx.x;
    if (t >= 3 * 128) return;
    int l = t >> 7, r = t & 127, h = r >> 4, d = r & 15;
    const float* le = lin_edge + (size_t)l * 128 * 16;
    const float* av = att + ((l * 3 + 2) * 128) + h * 16;
    float acc = 0.f;
#pragma unroll
    for (int c = 0; c < 16; ++c) acc += le[(h * 16 + c) * 16 + d] * av[c];
    M[t] = acc;
}

// ---------- QKV GEMM: out[n][o] = sum_i h[n][i]*W[o][i], opt. *attv[o] ----------
// block: 256 thr, 64 nodes x 128 outs. grid: (ceil(N/64), 3)
__global__ __launch_bounds__(256)
void qkv_gemm_kernel(const float* __restrict__ hin,
                     const float* __restrict__ lin_qkv_l,  // layer base: 3 mats of 128x128
                     const float* __restrict__ att_l,      // att[l][0] base (2x128 used)
                     float* __restrict__ qa, float* __restrict__ ka, float* __restrict__ vv,
                     int nrows) {
    __shared__ __align__(16) float hT[128][68];  // [k][node], padded
    __shared__ __align__(16) float Wc[16][128];  // [kk][o]

    const int t = threadIdx.x;
    const int m = blockIdx.y;
    const float* W = lin_qkv_l + (size_t)m * 16384;
    const float* attv = (m == 0) ? att_l : (m == 1 ? att_l + 128 : nullptr);
    float* outb = (m == 0) ? qa : (m == 1 ? ka : vv);
    const int n0blk = blockIdx.x * 64;

    // stage hT (transposed)
    {
        int nl = t >> 2;
        int n = n0blk + nl;
        int c0 = (t & 3) * 32;
        if (n < nrows) {
            const float4* src = reinterpret_cast<const float4*>(hin + (size_t)n * 128 + c0);
#pragma unroll
            for (int j = 0; j < 8; ++j) {
                float4 v = src[j];
                int c = c0 + j * 4;
                hT[c + 0][nl] = v.x; hT[c + 1][nl] = v.y; hT[c + 2][nl] = v.z; hT[c + 3][nl] = v.w;
            }
        } else {
#pragma unroll
            for (int j = 0; j < 32; ++j) hT[c0 + j][nl] = 0.f;
        }
    }

    const int tx = t & 31;   // out tile: o0 = tx*4
    const int ty = t >> 5;   // node tile: n local = ty*8
    float acc[8][4];
#pragma unroll
    for (int i = 0; i < 8; ++i)
#pragma unroll
        for (int j = 0; j < 4; ++j) acc[i][j] = 0.f;

    for (int kb = 0; kb < 8; ++kb) {
        // stage Wc[16][128]
        {
            int o = t >> 1, part = t & 1;
            const float4* wrow = reinterpret_cast<const float4*>(W + (size_t)o * 128 + kb * 16 + part * 8);
            float4 w0 = wrow[0], w1 = wrow[1];
            int d0 = part * 8;
            Wc[d0 + 0][o] = w0.x; Wc[d0 + 1][o] = w0.y; Wc[d0 + 2][o] = w0.z; Wc[d0 + 3][o] = w0.w;
            Wc[d0 + 4][o] = w1.x; Wc[d0 + 5][o] = w1.y; Wc[d0 + 6][o] = w1.z; Wc[d0 + 7][o] = w1.w;
        }
        __syncthreads();
#pragma unroll
        for (int d = 0; d < 16; ++d) {
            int k = kb * 16 + d;
            const float4* hp = reinterpret_cast<const float4*>(&hT[k][ty * 8]);
            float4 h0 = hp[0], h1 = hp[1];
            const float4* wp = reinterpret_cast<const float4*>(&Wc[d][tx * 4]);
            float4 wv = wp[0];
            float hv[8] = {h0.x, h0.y, h0.z, h0.w, h1.x, h1.y, h1.z, h1.w};
            float wa[4] = {wv.x, wv.y, wv.z, wv.w};
#pragma unroll
            for (int i = 0; i < 8; ++i)
#pragma unroll
                for (int j = 0; j < 4; ++j) acc[i][j] += hv[i] * wa[j];
        }
        __syncthreads();
    }

    float sc[4] = {1.f, 1.f, 1.f, 1.f};
    if (attv) {
#pragma unroll
        for (int j = 0; j < 4; ++j) sc[j] = attv[tx * 4 + j];
    }
#pragma unroll
    for (int i = 0; i < 8; ++i) {
        int n = n0blk + ty * 8 + i;
        if (n < nrows) {
            float4 r = make_float4(acc[i][0] * sc[0], acc[i][1] * sc[1], acc[i][2] * sc[2], acc[i][3] * sc[3]);
            reinterpret_cast<float4*>(outb + (size_t)n * 128)[tx] = r;
        }
    }
}

// ---------- edge scores + atomic max ----------
__global__ __launch_bounds__(256)
void edge_score_kernel(const float* __restrict__ qa, const float* __restrict__ ka,
                       const int* __restrict__ ei, const float* __restrict__ edge_attr,
                       const float* __restrict__ Ml, float* __restrict__ s,
                       unsigned* __restrict__ nmaxKey) {
    int idx = blockIdx.x * 256 + threadIdx.x;  // exactly E*8
    int e = idx >> 3, h = idx & 7;
    int src = ei[e], dst = ei[EE + e];
    const float4* qp = reinterpret_cast<const float4*>(qa + (size_t)dst * 128 + h * 16);
    const float4* kp = reinterpret_cast<const float4*>(ka + (size_t)src * 128 + h * 16);
    float a = 0.f;
#pragma unroll
    for (int j = 0; j < 4; ++j) {
        float4 q4 = qp[j], k4 = kp[j];
        a += q4.x * k4.x + q4.y * k4.y + q4.z * k4.z + q4.w * k4.w;
    }
    const float4* ep = reinterpret_cast<const float4*>(edge_attr + (size_t)e * 16);
    const float4* mp = reinterpret_cast<const float4*>(Ml + h * 16);
#pragma unroll
    for (int j = 0; j < 4; ++j) {
        float4 e4 = ep[j], m4 = mp[j];
        a += e4.x * m4.x + e4.y * m4.y + e4.z * m4.z + e4.w * m4.w;
    }
    a = a > 0.f ? a : 0.2f * a;  // leaky relu
    s[idx] = a;
    atomicMax(&nmaxKey[dst * 8 + h], f2key(a));
}

// ---------- exp + atomic denom ----------
__global__ __launch_bounds__(256)
void edge_expsum_kernel(const int* __restrict__ ei, float* __restrict__ s,
                        const unsigned* __restrict__ nmaxKey, float* __restrict__ denom) {
    int idx = blockIdx.x * 256 + threadIdx.x;
    int e = idx >> 3, h = idx & 7;
    int dst = ei[EE + e];
    float m = key2f(nmaxKey[dst * 8 + h]);
    float p = __expf(s[idx] - m);
    s[idx] = p;
    unsafeAtomicAdd(&denom[dst * 8 + h], p);
}

// ---------- aggregate: out[dst] += (p/denom) * v[src] ----------
__global__ __launch_bounds__(256)
void edge_aggregate_kernel(const int* __restrict__ ei, const float* __restrict__ s,
                           const float* __restrict__ denom, const float* __restrict__ vv,
                           float* __restrict__ hout) {
    int idx = blockIdx.x * 256 + threadIdx.x;
    int e = idx >> 3, h = idx & 7;
    int src = ei[e], dst = ei[EE + e];
    float coef = s[idx] / (denom[dst * 8 + h] + 1e-16f);
    const float4* vp = reinterpret_cast<const float4*>(vv + (size_t)src * 128 + h * 16);
    float* op = hout + (size_t)dst * 128 + h * 16;
#pragma unroll
    for (int j = 0; j < 4; ++j) {
        float4 v4 = vp[j];
        unsafeAtomicAdd(op + j * 4 + 0, coef * v4.x);
        unsafeAtomicAdd(op + j * 4 + 1, coef * v4.y);
        unsafeAtomicAdd(op + j * 4 + 2, coef * v4.z);
        unsafeAtomicAdd(op + j * 4 + 3, coef * v4.w);
    }
}

// ---------- BN stats (sum, sumsq per channel) ----------
__global__ __launch_bounds__(256)
void bn_stats_kernel(const float* __restrict__ h, float* __restrict__ sums, int nrows) {
    int t = threadIdx.x;
    int c = t & 127, half = t >> 7;
    float s1 = 0.f, s2 = 0.f;
    int rend = min(nrows, (int)(blockIdx.x * 64 + 64));
    for (int r = blockIdx.x * 64 + half; r < rend; r += 2) {
        float v = h[(size_t)r * 128 + c];
        s1 += v; s2 += v * v;
    }
    __shared__ float red[256];
    red[t] = s1; __syncthreads();
    if (half == 0) unsafeAtomicAdd(&sums[c], red[t] + red[t + 128]);
    __syncthreads();
    red[t] = s2; __syncthreads();
    if (half == 0) unsafeAtomicAdd(&sums[128 + c], red[t] + red[t + 128]);
}

// ---------- BN apply (+opt relu), in place ----------
__global__ __launch_bounds__(256)
void bn_apply_kernel(float* __restrict__ h, const float* __restrict__ sums,
                     const float* __restrict__ scale, const float* __restrict__ shift,
                     int relu) {
    int idx = blockIdx.x * 256 + threadIdx.x;  // exactly N*128
    int c = idx & 127;
    const float invN = 1.f / (float)NN;
    float mu = sums[c] * invN;
    float var = sums[128 + c] * invN - mu * mu;
    float v = (h[idx] - mu) * rsqrtf(var + 1e-5f) * scale[c] + shift[c];
    if (relu) v = v > 0.f ? v : 0.f;
    h[idx] = v;
}

// ---------- global max pool ----------
__global__ __launch_bounds__(256)
void pool_kernel(const float* __restrict__ h, const int* __restrict__ batch,
                 unsigned* __restrict__ gkey) {
    int idx = blockIdx.x * 256 + threadIdx.x;  // exactly N*128
    int n = idx >> 7, c = idx & 127;
    atomicMax(&gkey[batch[n] * 128 + c], f2key(h[idx]));
}

// ---------- head MLP (single block) ----------
__global__ __launch_bounds__(256)
void head_kernel(const unsigned* __restrict__ gkey,
                 const float* __restrict__ W1, const float* __restrict__ b1,
                 const float* __restrict__ bn1s, const float* __restrict__ bn1b,
                 const float* __restrict__ W2, const float* __restrict__ b2,
                 const float* __restrict__ bn2s, const float* __restrict__ bn2b,
                 const float* __restrict__ Wout, const float* __restrict__ bout,
                 float* __restrict__ out) {
    __shared__ float g[64][128];
    __shared__ float z1[64][64];
    __shared__ float z2[64][32];
    int t = threadIdx.x;
    for (int i = t; i < 64 * 128; i += 256) g[i >> 7][i & 127] = key2f(gkey[i]);
    __syncthreads();
    // z1 = g @ W1^T + b1
    for (int i = t; i < 64 * 64; i += 256) {
        int r = i >> 6, o = i & 63;
        const float* gr = g[r];
        const float* wr = W1 + (size_t)o * 128;
        float acc = b1[o];
        for (int k2 = 0; k2 < 128; ++k2) acc += gr[k2] * wr[k2];
        z1[r][o] = acc;
    }
    __syncthreads();
    if (t < 64) {
        float s1 = 0.f, s2 = 0.f;
        for (int r = 0; r < 64; ++r) { float v = z1[r][t]; s1 += v; s2 += v * v; }
        float mu = s1 * (1.f / 64.f), var = s2 * (1.f / 64.f) - mu * mu;
        float inv = rsqrtf(var + 1e-5f) * bn1s[t];
        float sh = bn1b[t];
        for (int r = 0; r < 64; ++r) {
            float v = (z1[r][t] - mu) * inv + sh;
            z1[r][t] = v > 0.f ? v : 0.f;
        }
    }
    __syncthreads();
    // z2 = z1 @ W2^T + b2
    for (int i = t; i < 64 * 32; i += 256) {
        int r = i >> 5, o = i & 31;
        const float* wr = W2 + (size_t)o * 64;
        float acc = b2[o];
        for (int k2 = 0; k2 < 64; ++k2) acc += z1[r][k2] * wr[k2];
        z2[r][o] = acc;
    }
    __syncthreads();
    if (t < 32) {
        float s1 = 0.f, s2 = 0.f;
        for (int r = 0; r < 64; ++r) { float v = z2[r][t]; s1 += v; s2 += v * v; }
        float mu = s1 * (1.f / 64.f), var = s2 * (1.f / 64.f) - mu * mu;
        float inv = rsqrtf(var + 1e-5f) * bn2s[t];
        float sh = bn2b[t];
        for (int r = 0; r < 64; ++r) {
            float v = (z2[r][t] - mu) * inv + sh;
            z2[r][t] = v > 0.f ? v : 0.f;
        }
    }
    __syncthreads();
    // out = z2 @ Wout^T + bout
    for (int i = t; i < 64 * 64; i += 256) {
        int r = i >> 6, o = i & 63;
        const float* wr = Wout + (size_t)o * 32;
        float acc = bout[o];
        for (int k2 = 0; k2 < 32; ++k2) acc += z2[r][k2] * wr[k2];
        out[r * 64 + o] = acc;
    }
}

extern "C" void kernel_launch(void* const* d_in, const int* in_sizes, int n_in,
                              void* d_out, int out_size, void* d_ws, size_t ws_size,
                              hipStream_t stream) {
    const float* x         = (const float*)d_in[0];
    const int*   ei        = (const int*)d_in[1];
    const float* edge_attr = (const float*)d_in[2];
    const int*   batch     = (const int*)d_in[3];
    const float* lin_qkv   = (const float*)d_in[4];
    const float* lin_edge  = (const float*)d_in[5];
    const float* att       = (const float*)d_in[6];
    // d_in[7] gat_bias: cancels exactly under training-mode BN (mean-subtracted)
    const float* bn_scale  = (const float*)d_in[8];
    const float* bn_bias   = (const float*)d_in[9];
    const float* W1   = (const float*)d_in[10];
    const float* b1   = (const float*)d_in[11];
    const float* bn1s = (const float*)d_in[12];
    const float* bn1b = (const float*)d_in[13];
    const float* W2   = (const float*)d_in[14];
    const float* b2   = (const float*)d_in[15];
    const float* bn2s = (const float*)d_in[16];
    const float* bn2b = (const float*)d_in[17];
    const float* Wout = (const float*)d_in[18];
    const float* bout = (const float*)d_in[19];

    float* ws = (float*)d_ws;
    size_t off = 0;
    auto alloc = [&](size_t n) { float* p = ws + off; off += n; return p; };
    float* bufA = alloc((size_t)NN * 128);
    float* bufB = alloc((size_t)NN * 128);
    float* qa   = alloc((size_t)NN * 128);
    float* ka   = alloc((size_t)NN * 128);
    float* vv   = alloc((size_t)NN * 128);
    float* s    = alloc((size_t)EE * 8);
    float* denom = alloc((size_t)NN * 8);
    unsigned* nmaxKey = (unsigned*)alloc((size_t)NN * 8);
    float* gsums = alloc(256);
    float* M     = alloc(3 * 128);
    unsigned* gkey = (unsigned*)alloc(64 * 128);

    compute_M_kernel<<<2, 256, 0, stream>>>(lin_edge, att, M);

    const int gemmBlocks = (NN + 63) / 64;       // 782
    const int edgeBlocks = (EE * 8) / 256;       // 12500
    const int nodeBlocks = (NN * 128) / 256;     // 25000

    for (int l = 0; l < 3; ++l) {
        const float* hin = (l == 0) ? x : (l == 1 ? bufA : bufB);
        float* hout = (l == 0) ? bufA : (l == 1 ? bufB : bufA);

        qkv_gemm_kernel<<<dim3(gemmBlocks, 3), 256, 0, stream>>>(
            hin, lin_qkv + (size_t)l * 3 * 16384, att + (size_t)l * 3 * 128, qa, ka, vv, NN);

        hipMemsetAsync(hout, 0, (size_t)NN * 128 * 4, stream);
        hipMemsetAsync(nmaxKey, 0, (size_t)NN * 8 * 4, stream);
        hipMemsetAsync(denom, 0, (size_t)NN * 8 * 4, stream);

        edge_score_kernel<<<edgeBlocks, 256, 0, stream>>>(qa, ka, ei, edge_attr, M + l * 128, s, nmaxKey);
        edge_expsum_kernel<<<edgeBlocks, 256, 0, stream>>>(ei, s, nmaxKey, denom);
        edge_aggregate_kernel<<<edgeBlocks, 256, 0, stream>>>(ei, s, denom, vv, hout);

        hipMemsetAsync(gsums, 0, 256 * 4, stream);
        bn_stats_kernel<<<gemmBlocks, 256, 0, stream>>>(hout, gsums, NN);
        bn_apply_kernel<<<nodeBlocks, 256, 0, stream>>>(hout, gsums, bn_scale + l * 128, bn_bias + l * 128, l < 2 ? 1 : 0);
    }

    hipMemsetAsync(gkey, 0, 64 * 128 * 4, stream);
    pool_kernel<<<nodeBlocks, 256, 0, stream>>>(bufA, batch, gkey);
    head_kernel<<<1, 256, 0, stream>>>(gkey, W1, b1, bn1s, bn1b, W2, b2, bn2s, bn2b, Wout, bout, (float*)d_out);
}

// Round 2
// 831.273 us; speedup vs baseline: 11.2809x; 11.2809x over previous
//
#include <hip/hip_runtime.h>
#include <hip/hip_bf16.h>
#include <cstddef>

#define NN 50000
#define EE 400000
#define FF 128
#define HH 8
#define CC 16
#define GG 64

// ---------- helpers ----------
__device__ __forceinline__ unsigned f2key(float f) {
    unsigned u = __float_as_uint(f);
    return (u & 0x80000000u) ? ~u : (u | 0x80000000u);
}
__device__ __forceinline__ float key2f(unsigned k) {
    unsigned u = (k & 0x80000000u) ? (k ^ 0x80000000u) : ~k;
    return __uint_as_float(u);
}

// ---------- M[l][h][d] = sum_c lin_edge[l][h*16+c][d] * att[l][2][h][c] ----------
__global__ void compute_M_kernel(const float* __restrict__ lin_edge,
                                 const float* __restrict__ att,
                                 float* __restrict__ M) {
    int t = blockIdx.x * 256 + threadIdx.x;
    if (t >= 3 * 128) return;
    int l = t >> 7, r = t & 127, h = r >> 4, d = r & 15;
    const float* le = lin_edge + (size_t)l * 128 * 16;
    const float* av = att + ((l * 3 + 2) * 128) + h * 16;
    float acc = 0.f;
#pragma unroll
    for (int c = 0; c < 16; ++c) acc += le[(h * 16 + c) * 16 + d] * av[c];
    M[t] = acc;
}

// ---------- CSR build ----------
__global__ __launch_bounds__(256)
void deg_count_kernel(const int* __restrict__ ei, int* __restrict__ deg) {
    int e = blockIdx.x * 256 + threadIdx.x;
    if (e < EE) atomicAdd(&deg[ei[EE + e]], 1);
}

// single block, 1024 threads: exclusive scan of deg[NN] -> offs, cursor
__global__ __launch_bounds__(1024)
void scan_kernel(const int* __restrict__ deg, int* __restrict__ offs, int* __restrict__ cursor) {
    __shared__ int tile[1024];
    __shared__ int carry;
    int t = threadIdx.x;
    if (t == 0) carry = 0;
    __syncthreads();
    for (int base = 0; base < NN; base += 1024) {
        int v = (base + t < NN) ? deg[base + t] : 0;
        tile[t] = v;
        __syncthreads();
        for (int ofs = 1; ofs < 1024; ofs <<= 1) {
            int add = (t >= ofs) ? tile[t - ofs] : 0;
            __syncthreads();
            tile[t] += add;
            __syncthreads();
        }
        int c = carry;
        int excl = c + tile[t] - v;
        if (base + t < NN) { offs[base + t] = excl; cursor[base + t] = excl; }
        __syncthreads();
        if (t == 1023) carry = c + tile[1023];
        __syncthreads();
    }
}

__global__ __launch_bounds__(256)
void scatter_kernel(const int* __restrict__ ei, int* __restrict__ cursor,
                    int2* __restrict__ csr) {
    int e = blockIdx.x * 256 + threadIdx.x;
    if (e < EE) {
        int src = ei[e], dst = ei[EE + e];
        int pos = atomicAdd(&cursor[dst], 1);
        csr[pos] = make_int2(src, e);
    }
}

// ---------- QKV GEMM: out[n][o] = sum_i h[n][i]*W[o][i], opt. *attv[o] ----------
// block: 256 thr, 64 nodes x 128 outs. grid: (ceil(N/64), 3)
__global__ __launch_bounds__(256)
void qkv_gemm_kernel(const float* __restrict__ hin,
                     const float* __restrict__ lin_qkv_l,  // layer base: 3 mats of 128x128
                     const float* __restrict__ att_l,      // att[l][0] base (2x128 used)
                     float* __restrict__ qa, float* __restrict__ ka, float* __restrict__ vv,
                     int nrows) {
    __shared__ __align__(16) float hT[128][68];  // [k][node], padded
    __shared__ __align__(16) float Wc[16][128];  // [kk][o]

    const int t = threadIdx.x;
    const int m = blockIdx.y;
    const float* W = lin_qkv_l + (size_t)m * 16384;
    const float* attv = (m == 0) ? att_l : (m == 1 ? att_l + 128 : nullptr);
    float* outb = (m == 0) ? qa : (m == 1 ? ka : vv);
    const int n0blk = blockIdx.x * 64;

    // stage hT (transposed)
    {
        int nl = t >> 2;
        int n = n0blk + nl;
        int c0 = (t & 3) * 32;
        if (n < nrows) {
            const float4* src = reinterpret_cast<const float4*>(hin + (size_t)n * 128 + c0);
#pragma unroll
            for (int j = 0; j < 8; ++j) {
                float4 v = src[j];
                int c = c0 + j * 4;
                hT[c + 0][nl] = v.x; hT[c + 1][nl] = v.y; hT[c + 2][nl] = v.z; hT[c + 3][nl] = v.w;
            }
        } else {
#pragma unroll
            for (int j = 0; j < 32; ++j) hT[c0 + j][nl] = 0.f;
        }
    }

    const int tx = t & 31;   // out tile: o0 = tx*4
    const int ty = t >> 5;   // node tile: n local = ty*8
    float acc[8][4];
#pragma unroll
    for (int i = 0; i < 8; ++i)
#pragma unroll
        for (int j = 0; j < 4; ++j) acc[i][j] = 0.f;

    for (int kb = 0; kb < 8; ++kb) {
        // stage Wc[16][128]
        {
            int o = t >> 1, part = t & 1;
            const float4* wrow = reinterpret_cast<const float4*>(W + (size_t)o * 128 + kb * 16 + part * 8);
            float4 w0 = wrow[0], w1 = wrow[1];
            int d0 = part * 8;
            Wc[d0 + 0][o] = w0.x; Wc[d0 + 1][o] = w0.y; Wc[d0 + 2][o] = w0.z; Wc[d0 + 3][o] = w0.w;
            Wc[d0 + 4][o] = w1.x; Wc[d0 + 5][o] = w1.y; Wc[d0 + 6][o] = w1.z; Wc[d0 + 7][o] = w1.w;
        }
        __syncthreads();
#pragma unroll
        for (int d = 0; d < 16; ++d) {
            int k = kb * 16 + d;
            const float4* hp = reinterpret_cast<const float4*>(&hT[k][ty * 8]);
            float4 h0 = hp[0], h1 = hp[1];
            const float4* wp = reinterpret_cast<const float4*>(&Wc[d][tx * 4]);
            float4 wv = wp[0];
            float hv[8] = {h0.x, h0.y, h0.z, h0.w, h1.x, h1.y, h1.z, h1.w};
            float wa[4] = {wv.x, wv.y, wv.z, wv.w};
#pragma unroll
            for (int i = 0; i < 8; ++i)
#pragma unroll
                for (int j = 0; j < 4; ++j) acc[i][j] += hv[i] * wa[j];
        }
        __syncthreads();
    }

    float sc[4] = {1.f, 1.f, 1.f, 1.f};
    if (attv) {
#pragma unroll
        for (int j = 0; j < 4; ++j) sc[j] = attv[tx * 4 + j];
    }
#pragma unroll
    for (int i = 0; i < 8; ++i) {
        int n = n0blk + ty * 8 + i;
        if (n < nrows) {
            float4 r = make_float4(acc[i][0] * sc[0], acc[i][1] * sc[1], acc[i][2] * sc[2], acc[i][3] * sc[3]);
            reinterpret_cast<float4*>(outb + (size_t)n * 128)[tx] = r;
        }
    }
}

// ---------- fused attention: score + softmax + aggregate, one wave per dst ----------
__global__ __launch_bounds__(256)
void fused_gat_kernel(const float* __restrict__ qa, const float* __restrict__ ka,
                      const float* __restrict__ vv, const float* __restrict__ edge_attr,
                      const float* __restrict__ Ml,
                      const int* __restrict__ offs, const int* __restrict__ deg,
                      const int2* __restrict__ csr, float* __restrict__ hout) {
    int wid = threadIdx.x >> 6;
    int lane = threadIdx.x & 63;
    int n = blockIdx.x * 4 + wid;
    if (n >= NN) return;
    int h = lane >> 3;          // head 0..7
    int c2 = (lane & 7) * 2;    // channel pair within head
    int ch = h * 16 + c2;       // global channel

    float2 q = *reinterpret_cast<const float2*>(qa + (size_t)n * 128 + ch);
    float2 Mh = *reinterpret_cast<const float2*>(Ml + h * 16 + c2);

    int start = offs[n], d = deg[n];
    float m = -INFINITY, den = 0.f, acc0 = 0.f, acc1 = 0.f;
    for (int i = 0; i < d; ++i) {
        int2 se = csr[start + i];
        int src = se.x, e = se.y;
        float2 k = *reinterpret_cast<const float2*>(ka + (size_t)src * 128 + ch);
        float2 v = *reinterpret_cast<const float2*>(vv + (size_t)src * 128 + ch);
        float2 ea = *reinterpret_cast<const float2*>(edge_attr + (size_t)e * 16 + c2);
        float part = q.x * k.x + q.y * k.y + ea.x * Mh.x + ea.y * Mh.y;
        part += __shfl_xor(part, 1);
        part += __shfl_xor(part, 2);
        part += __shfl_xor(part, 4);
        float a = part > 0.f ? part : 0.2f * part;  // leaky relu
        float mn = fmaxf(m, a);
        float scale = __expf(m - mn);   // first iter: exp(-inf)=0
        float p = __expf(a - mn);
        den = den * scale + p;
        acc0 = acc0 * scale + p * v.x;
        acc1 = acc1 * scale + p * v.y;
        m = mn;
    }
    float inv = 1.f / (den + 1e-16f);
    *reinterpret_cast<float2*>(hout + (size_t)n * 128 + ch) = make_float2(acc0 * inv, acc1 * inv);
}

// ---------- BN stats (sum, sumsq per channel) ----------
__global__ __launch_bounds__(256)
void bn_stats_kernel(const float* __restrict__ h, float* __restrict__ sums, int nrows) {
    int t = threadIdx.x;
    int c = t & 127, half = t >> 7;
    float s1 = 0.f, s2 = 0.f;
    int rend = min(nrows, (int)(blockIdx.x * 64 + 64));
    for (int r = blockIdx.x * 64 + half; r < rend; r += 2) {
        float v = h[(size_t)r * 128 + c];
        s1 += v; s2 += v * v;
    }
    __shared__ float red[256];
    red[t] = s1; __syncthreads();
    if (half == 0) unsafeAtomicAdd(&sums[c], red[t] + red[t + 128]);
    __syncthreads();
    red[t] = s2; __syncthreads();
    if (half == 0) unsafeAtomicAdd(&sums[128 + c], red[t] + red[t + 128]);
}

// ---------- BN apply (+opt relu), in place ----------
__global__ __launch_bounds__(256)
void bn_apply_kernel(float* __restrict__ h, const float* __restrict__ sums,
                     const float* __restrict__ scale, const float* __restrict__ shift,
                     int relu) {
    int idx = blockIdx.x * 256 + threadIdx.x;  // exactly N*128
    int c = idx & 127;
    const float invN = 1.f / (float)NN;
    float mu = sums[c] * invN;
    float var = sums[128 + c] * invN - mu * mu;
    float v = (h[idx] - mu) * rsqrtf(var + 1e-5f) * scale[c] + shift[c];
    if (relu) v = v > 0.f ? v : 0.f;
    h[idx] = v;
}

// ---------- global max pool ----------
__global__ __launch_bounds__(256)
void pool_kernel(const float* __restrict__ h, const int* __restrict__ batch,
                 unsigned* __restrict__ gkey) {
    int idx = blockIdx.x * 256 + threadIdx.x;  // exactly N*128
    int n = idx >> 7, c = idx & 127;
    atomicMax(&gkey[batch[n] * 128 + c], f2key(h[idx]));
}

// ---------- head MLP (single block) ----------
__global__ __launch_bounds__(256)
void head_kernel(const unsigned* __restrict__ gkey,
                 const float* __restrict__ W1, const float* __restrict__ b1,
                 const float* __restrict__ bn1s, const float* __restrict__ bn1b,
                 const float* __restrict__ W2, const float* __restrict__ b2,
                 const float* __restrict__ bn2s, const float* __restrict__ bn2b,
                 const float* __restrict__ Wout, const float* __restrict__ bout,
                 float* __restrict__ out) {
    __shared__ float g[64][128];
    __shared__ float z1[64][64];
    __shared__ float z2[64][32];
    int t = threadIdx.x;
    for (int i = t; i < 64 * 128; i += 256) g[i >> 7][i & 127] = key2f(gkey[i]);
    __syncthreads();
    for (int i = t; i < 64 * 64; i += 256) {
        int r = i >> 6, o = i & 63;
        const float* gr = g[r];
        const float* wr = W1 + (size_t)o * 128;
        float acc = b1[o];
        for (int k2 = 0; k2 < 128; ++k2) acc += gr[k2] * wr[k2];
        z1[r][o] = acc;
    }
    __syncthreads();
    if (t < 64) {
        float s1 = 0.f, s2 = 0.f;
        for (int r = 0; r < 64; ++r) { float v = z1[r][t]; s1 += v; s2 += v * v; }
        float mu = s1 * (1.f / 64.f), var = s2 * (1.f / 64.f) - mu * mu;
        float inv = rsqrtf(var + 1e-5f) * bn1s[t];
        float sh = bn1b[t];
        for (int r = 0; r < 64; ++r) {
            float v = (z1[r][t] - mu) * inv + sh;
            z1[r][t] = v > 0.f ? v : 0.f;
        }
    }
    __syncthreads();
    for (int i = t; i < 64 * 32; i += 256) {
        int r = i >> 5, o = i & 31;
        const float* wr = W2 + (size_t)o * 64;
        float acc = b2[o];
        for (int k2 = 0; k2 < 64; ++k2) acc += z1[r][k2] * wr[k2];
        z2[r][o] = acc;
    }
    __syncthreads();
    if (t < 32) {
        float s1 = 0.f, s2 = 0.f;
        for (int r = 0; r < 64; ++r) { float v = z2[r][t]; s1 += v; s2 += v * v; }
        float mu = s1 * (1.f / 64.f), var = s2 * (1.f / 64.f) - mu * mu;
        float inv = rsqrtf(var + 1e-5f) * bn2s[t];
        float sh = bn2b[t];
        for (int r = 0; r < 64; ++r) {
            float v = (z2[r][t] - mu) * inv + sh;
            z2[r][t] = v > 0.f ? v : 0.f;
        }
    }
    __syncthreads();
    for (int i = t; i < 64 * 64; i += 256) {
        int r = i >> 6, o = i & 63;
        const float* wr = Wout + (size_t)o * 32;
        float acc = bout[o];
        for (int k2 = 0; k2 < 32; ++k2) acc += z2[r][k2] * wr[k2];
        out[r * 64 + o] = acc;
    }
}

extern "C" void kernel_launch(void* const* d_in, const int* in_sizes, int n_in,
                              void* d_out, int out_size, void* d_ws, size_t ws_size,
                              hipStream_t stream) {
    const float* x         = (const float*)d_in[0];
    const int*   ei        = (const int*)d_in[1];
    const float* edge_attr = (const float*)d_in[2];
    const int*   batch     = (const int*)d_in[3];
    const float* lin_qkv   = (const float*)d_in[4];
    const float* lin_edge  = (const float*)d_in[5];
    const float* att       = (const float*)d_in[6];
    // d_in[7] gat_bias: cancels exactly under training-mode BN (mean-subtracted)
    const float* bn_scale  = (const float*)d_in[8];
    const float* bn_bias   = (const float*)d_in[9];
    const float* W1   = (const float*)d_in[10];
    const float* b1   = (const float*)d_in[11];
    const float* bn1s = (const float*)d_in[12];
    const float* bn1b = (const float*)d_in[13];
    const float* W2   = (const float*)d_in[14];
    const float* b2   = (const float*)d_in[15];
    const float* bn2s = (const float*)d_in[16];
    const float* bn2b = (const float*)d_in[17];
    const float* Wout = (const float*)d_in[18];
    const float* bout = (const float*)d_in[19];

    float* ws = (float*)d_ws;
    size_t off = 0;
    auto alloc = [&](size_t n) { float* p = ws + off; off += n; return p; };
    float* bufA = alloc((size_t)NN * 128);
    float* bufB = alloc((size_t)NN * 128);
    float* qa   = alloc((size_t)NN * 128);
    float* ka   = alloc((size_t)NN * 128);
    float* vv   = alloc((size_t)NN * 128);
    int*   deg    = (int*)alloc(NN);
    int*   offs   = (int*)alloc(NN);
    int*   cursor = (int*)alloc(NN);
    int2*  csr    = (int2*)alloc((size_t)EE * 2);
    float* gsums = alloc(256);
    float* M     = alloc(3 * 128);
    unsigned* gkey = (unsigned*)alloc(64 * 128);

    const int gemmBlocks = (NN + 63) / 64;       // 782
    const int nodeBlocks = (NN * 128) / 256;     // 25000
    const int edgeThreadBlocks = (EE + 255) / 256;
    const int fusedBlocks = (NN + 3) / 4;        // 12500

    // CSR build (once per call)
    hipMemsetAsync(deg, 0, NN * 4, stream);
    compute_M_kernel<<<2, 256, 0, stream>>>(lin_edge, att, M);
    deg_count_kernel<<<edgeThreadBlocks, 256, 0, stream>>>(ei, deg);
    scan_kernel<<<1, 1024, 0, stream>>>(deg, offs, cursor);
    scatter_kernel<<<edgeThreadBlocks, 256, 0, stream>>>(ei, cursor, csr);

    for (int l = 0; l < 3; ++l) {
        const float* hin = (l == 0) ? x : (l == 1 ? bufA : bufB);
        float* hout = (l == 0) ? bufA : (l == 1 ? bufB : bufA);

        qkv_gemm_kernel<<<dim3(gemmBlocks, 3), 256, 0, stream>>>(
            hin, lin_qkv + (size_t)l * 3 * 16384, att + (size_t)l * 3 * 128, qa, ka, vv, NN);

        fused_gat_kernel<<<fusedBlocks, 256, 0, stream>>>(
            qa, ka, vv, edge_attr, M + l * 128, offs, deg, csr, hout);

        hipMemsetAsync(gsums, 0, 256 * 4, stream);
        bn_stats_kernel<<<gemmBlocks, 256, 0, stream>>>(hout, gsums, NN);
        bn_apply_kernel<<<nodeBlocks, 256, 0, stream>>>(hout, gsums, bn_scale + l * 128, bn_bias + l * 128, l < 2 ? 1 : 0);
    }

    hipMemsetAsync(gkey, 0, 64 * 128 * 4, stream);
    pool_kernel<<<nodeBlocks, 256, 0, stream>>>(bufA, batch, gkey);
    head_kernel<<<1, 256, 0, stream>>>(gkey, W1, b1, bn1s, bn1b, W2, b2, bn2s, bn2b, Wout, bout, (float*)d_out);
}

// Round 3
// 683.219 us; speedup vs baseline: 13.7254x; 1.2167x over previous
//
#include <hip/hip_runtime.h>
#include <hip/hip_bf16.h>
#include <cstddef>
#include <cstdint>

#define NN 50000
#define EE 400000
#define GG 64
#define MB 391   // ceil(NN/128)

typedef __attribute__((ext_vector_type(8))) short bf16x8;
typedef __attribute__((ext_vector_type(4))) float f32x4;

#define GLOAD_LDS16(g, l) __builtin_amdgcn_global_load_lds( \
    (const __attribute__((address_space(1))) void*)(g), \
    (__attribute__((address_space(3))) void*)(l), 16, 0, 0)

// ---------- helpers ----------
__device__ __forceinline__ unsigned f2key(float f) {
    unsigned u = __float_as_uint(f);
    return (u & 0x80000000u) ? ~u : (u | 0x80000000u);
}
__device__ __forceinline__ float key2f(unsigned k) {
    unsigned u = (k & 0x80000000u) ? (k ^ 0x80000000u) : ~k;
    return __uint_as_float(u);
}
__device__ __forceinline__ unsigned short f2bf(float f) {
    unsigned u = __float_as_uint(f);
    unsigned r = u + 0x7fffu + ((u >> 16) & 1u);
    return (unsigned short)(r >> 16);
}
__device__ __forceinline__ float bf2f(unsigned short b) {
    return __uint_as_float(((unsigned)b) << 16);
}

// ---------- M[l][h][d] = sum_c lin_edge[l][h*16+c][d] * att[l][2][h][c] ----------
__global__ void compute_M_kernel(const float* __restrict__ lin_edge,
                                 const float* __restrict__ att,
                                 float* __restrict__ M) {
    int t = blockIdx.x * 256 + threadIdx.x;
    if (t >= 3 * 128) return;
    int l = t >> 7, r = t & 127, h = r >> 4, d = r & 15;
    const float* le = lin_edge + (size_t)l * 128 * 16;
    const float* av = att + ((l * 3 + 2) * 128) + h * 16;
    float acc = 0.f;
#pragma unroll
    for (int c = 0; c < 16; ++c) acc += le[(h * 16 + c) * 16 + d] * av[c];
    M[t] = acc;
}

// ---------- weight packing: Wpack[l*3+mat][pc 8][kg 4][n 128][8k] bf16 ----------
// pc 0-3: hi of k-block pc; pc 4-7: lo of k-block pc-4.
__global__ __launch_bounds__(256)
void wpack_kernel(const float* __restrict__ lin_qkv, unsigned short* __restrict__ Wpack) {
    int g = blockIdx.x * 256 + threadIdx.x;   // [0, 9*4096)
    int lm = g >> 12;
    int r = g & 4095;
    int pc = r >> 9;
    int kg = (r >> 7) & 3;
    int n  = r & 127;
    int k0 = (pc & 3) * 32 + kg * 8;
    const float* row = lin_qkv + ((size_t)lm * 128 + n) * 128 + k0;
    unsigned short o[8] __attribute__((aligned(16)));
#pragma unroll
    for (int i = 0; i < 8; ++i) {
        float v = row[i];
        unsigned short h = f2bf(v);
        o[i] = (pc < 4) ? h : f2bf(v - bf2f(h));
    }
    *reinterpret_cast<uint4*>(Wpack + (size_t)g * 8) = *reinterpret_cast<const uint4*>(o);
}

// ---------- h packing (+optional BN+relu): Apack[mb][pc 8][kg 4][m 128][8k] ----------
__global__ __launch_bounds__(256)
void pack_kernel(const float* __restrict__ hin, const float* __restrict__ sums,
                 const float* __restrict__ scale, const float* __restrict__ shift,
                 int mode, unsigned short* __restrict__ Apack) {
    int s = blockIdx.x * 256 + threadIdx.x;   // [0, MB*2048)
    int mb = s >> 11;
    int r  = s & 2047;
    int kb = r >> 9;
    int kg = (r >> 7) & 3;
    int m  = r & 127;
    int node = mb * 128 + m;
    int k0 = kb * 32 + kg * 8;
    size_t hiSlot = ((size_t)(mb * 8 + kb) * 512 + (size_t)kg * 128 + m) * 8;
    size_t loSlot = ((size_t)(mb * 8 + kb + 4) * 512 + (size_t)kg * 128 + m) * 8;
    unsigned short hi[8] __attribute__((aligned(16)));
    unsigned short lo[8] __attribute__((aligned(16)));
    if (node < NN) {
        const float* row = hin + (size_t)node * 128 + k0;
#pragma unroll
        for (int i = 0; i < 8; ++i) {
            float v = row[i];
            if (mode) {
                int c = k0 + i;
                float mu = sums[c] * (1.f / NN);
                float var = sums[128 + c] * (1.f / NN) - mu * mu;
                v = (v - mu) * rsqrtf(var + 1e-5f) * scale[c] + shift[c];
                v = v > 0.f ? v : 0.f;
            }
            unsigned short h = f2bf(v);
            hi[i] = h;
            lo[i] = f2bf(v - bf2f(h));
        }
    } else {
#pragma unroll
        for (int i = 0; i < 8; ++i) { hi[i] = 0; lo[i] = 0; }
    }
    *reinterpret_cast<uint4*>(Apack + hiSlot) = *reinterpret_cast<const uint4*>(hi);
    *reinterpret_cast<uint4*>(Apack + loSlot) = *reinterpret_cast<const uint4*>(lo);
}

// ---------- QKV GEMM via MFMA, split-bf16 (K'=384: hi*hi + hi*lo + lo*hi) ----------
// grid (MB, 3 mats), block 256 = 4 waves as 2x2, wave tile 64x64, 16x16x32 frags.
__global__ __launch_bounds__(256, 3)
void qkv_mfma_kernel(const unsigned short* __restrict__ Apack,
                     const unsigned short* __restrict__ Wpack,
                     int layer,
                     const float* __restrict__ att_l,
                     float* __restrict__ qa, float* __restrict__ ka, float* __restrict__ vv) {
    __shared__ unsigned short Ab[2][4096];   // [kg 4][m 128][8k]
    __shared__ unsigned short Bb[2][4096];   // [kg 4][n 128][8k]
    const int t = threadIdx.x;
    const int lane = t & 63;
    const int wave = t >> 6;
    const int wr = wave >> 1, wc = wave & 1;
    const int mb = blockIdx.x, mat = blockIdx.y;

    const unsigned short* Abase = Apack + (size_t)mb * 32768;
    const unsigned short* Bbase = Wpack + (size_t)(layer * 3 + mat) * 32768;

    f32x4 acc[4][4];
#pragma unroll
    for (int i = 0; i < 4; ++i)
#pragma unroll
        for (int j = 0; j < 4; ++j) acc[i][j] = (f32x4){0.f, 0.f, 0.f, 0.f};

    auto stage = [&](int c, int buf) {
        int ap = (c < 8) ? (c & 3) : (c - 4);   // A' = [hi, hi, lo]
        int bp = (c < 8) ? c : (c - 8);         // B' = [hi, lo, hi]
        const unsigned short* ga = Abase + (size_t)ap * 4096;
        const unsigned short* gb = Bbase + (size_t)bp * 4096;
        GLOAD_LDS16(ga + (size_t)(wave * 64 + lane) * 8,        &Ab[buf][(wave * 64) * 8]);
        GLOAD_LDS16(ga + (size_t)(256 + wave * 64 + lane) * 8,  &Ab[buf][(256 + wave * 64) * 8]);
        GLOAD_LDS16(gb + (size_t)(wave * 64 + lane) * 8,        &Bb[buf][(wave * 64) * 8]);
        GLOAD_LDS16(gb + (size_t)(256 + wave * 64 + lane) * 8,  &Bb[buf][(256 + wave * 64) * 8]);
    };

    stage(0, 0);
    __syncthreads();
    const int abase = ((lane >> 4) * 128 + wr * 64 + (lane & 15)) * 8;
    const int bbase = ((lane >> 4) * 128 + wc * 64 + (lane & 15)) * 8;
#pragma unroll
    for (int c = 0; c < 12; ++c) {
        int cur = c & 1;
        if (c < 11) stage(c + 1, cur ^ 1);
        bf16x8 aF[4], bF[4];
#pragma unroll
        for (int mf = 0; mf < 4; ++mf)
            aF[mf] = *reinterpret_cast<const bf16x8*>(&Ab[cur][abase + mf * 128]);
#pragma unroll
        for (int nf = 0; nf < 4; ++nf)
            bF[nf] = *reinterpret_cast<const bf16x8*>(&Bb[cur][bbase + nf * 128]);
#pragma unroll
        for (int mf = 0; mf < 4; ++mf)
#pragma unroll
            for (int nf = 0; nf < 4; ++nf)
                acc[mf][nf] = __builtin_amdgcn_mfma_f32_16x16x32_bf16(aF[mf], bF[nf], acc[mf][nf], 0, 0, 0);
        __syncthreads();
    }

    float* outb = (mat == 0) ? qa : (mat == 1 ? ka : vv);
    float sc[4];
#pragma unroll
    for (int nf = 0; nf < 4; ++nf) {
        int col = wc * 64 + nf * 16 + (lane & 15);
        sc[nf] = (mat == 2) ? 1.f : att_l[mat * 128 + col];
    }
    const int rowq = (lane >> 4) * 4;
#pragma unroll
    for (int mf = 0; mf < 4; ++mf) {
        int row0 = mb * 128 + wr * 64 + mf * 16 + rowq;
#pragma unroll
        for (int reg = 0; reg < 4; ++reg) {
            int row = row0 + reg;
            if (row < NN) {
#pragma unroll
                for (int nf = 0; nf < 4; ++nf) {
                    int col = wc * 64 + nf * 16 + (lane & 15);
                    outb[(size_t)row * 128 + col] = acc[mf][nf][reg] * sc[nf];
                }
            }
        }
    }
}

// ---------- CSR build ----------
__global__ __launch_bounds__(256)
void deg_count_kernel(const int* __restrict__ ei, int* __restrict__ deg) {
    int e = blockIdx.x * 256 + threadIdx.x;
    if (e < EE) atomicAdd(&deg[ei[EE + e]], 1);
}

__global__ __launch_bounds__(256)
void scan_partial_kernel(const int* __restrict__ deg, int* __restrict__ psum) {
    __shared__ int red[256];
    int i = blockIdx.x * 256 + threadIdx.x;
    red[threadIdx.x] = (i < NN) ? deg[i] : 0;
    __syncthreads();
    for (int o = 128; o > 0; o >>= 1) {
        if (threadIdx.x < o) red[threadIdx.x] += red[threadIdx.x + o];
        __syncthreads();
    }
    if (threadIdx.x == 0) psum[blockIdx.x] = red[0];
}

__global__ __launch_bounds__(256)
void scan_top_kernel(const int* __restrict__ psum, int* __restrict__ psx) {
    __shared__ int sh[256];
    int t = threadIdx.x;
    int v = (t < 196) ? psum[t] : 0;
    sh[t] = v;
    __syncthreads();
    for (int o = 1; o < 256; o <<= 1) {
        int add = (t >= o) ? sh[t - o] : 0;
        __syncthreads();
        sh[t] += add;
        __syncthreads();
    }
    if (t < 196) psx[t] = sh[t] - v;
}

__global__ __launch_bounds__(256)
void scan_final_kernel(const int* __restrict__ deg, const int* __restrict__ psx,
                       int* __restrict__ offs, int* __restrict__ cursor) {
    __shared__ int sh[256];
    int t = threadIdx.x;
    int i = blockIdx.x * 256 + t;
    int v = (i < NN) ? deg[i] : 0;
    sh[t] = v;
    __syncthreads();
    for (int o = 1; o < 256; o <<= 1) {
        int add = (t >= o) ? sh[t - o] : 0;
        __syncthreads();
        sh[t] += add;
        __syncthreads();
    }
    if (i < NN) {
        int excl = sh[t] - v + psx[blockIdx.x];
        offs[i] = excl;
        cursor[i] = excl;
    }
}

__global__ __launch_bounds__(256)
void scatter_kernel(const int* __restrict__ ei, int* __restrict__ cursor,
                    int2* __restrict__ csr) {
    int e = blockIdx.x * 256 + threadIdx.x;
    if (e < EE) {
        int src = ei[e], dst = ei[EE + e];
        int pos = atomicAdd(&cursor[dst], 1);
        csr[pos] = make_int2(src, e);
    }
}

// ---------- fused attention: score + softmax + aggregate, one wave per dst ----------
__global__ __launch_bounds__(256)
void fused_gat_kernel(const float* __restrict__ qa, const float* __restrict__ ka,
                      const float* __restrict__ vv, const float* __restrict__ edge_attr,
                      const float* __restrict__ Ml,
                      const int* __restrict__ offs, const int* __restrict__ deg,
                      const int2* __restrict__ csr, float* __restrict__ hout) {
    int wid = threadIdx.x >> 6;
    int lane = threadIdx.x & 63;
    int n = blockIdx.x * 4 + wid;
    if (n >= NN) return;
    int h = lane >> 3;
    int c2 = (lane & 7) * 2;
    int ch = h * 16 + c2;

    float2 q = *reinterpret_cast<const float2*>(qa + (size_t)n * 128 + ch);
    float2 Mh = *reinterpret_cast<const float2*>(Ml + h * 16 + c2);

    int start = offs[n], d = deg[n];
    float m = -INFINITY, den = 0.f, acc0 = 0.f, acc1 = 0.f;
    for (int i = 0; i < d; ++i) {
        int2 se = csr[start + i];
        int src = se.x, e = se.y;
        float2 k = *reinterpret_cast<const float2*>(ka + (size_t)src * 128 + ch);
        float2 v = *reinterpret_cast<const float2*>(vv + (size_t)src * 128 + ch);
        float2 ea = *reinterpret_cast<const float2*>(edge_attr + (size_t)e * 16 + c2);
        float part = q.x * k.x + q.y * k.y + ea.x * Mh.x + ea.y * Mh.y;
        part += __shfl_xor(part, 1);
        part += __shfl_xor(part, 2);
        part += __shfl_xor(part, 4);
        float a = part > 0.f ? part : 0.2f * part;
        float mn = fmaxf(m, a);
        float scale = __expf(m - mn);
        float p = __expf(a - mn);
        den = den * scale + p;
        acc0 = acc0 * scale + p * v.x;
        acc1 = acc1 * scale + p * v.y;
        m = mn;
    }
    float inv = 1.f / (den + 1e-16f);
    *reinterpret_cast<float2*>(hout + (size_t)n * 128 + ch) = make_float2(acc0 * inv, acc1 * inv);
}

// ---------- BN stats (sum, sumsq per channel) ----------
__global__ __launch_bounds__(256)
void bn_stats_kernel(const float* __restrict__ h, float* __restrict__ sums, int nrows) {
    int t = threadIdx.x;
    int c = t & 127, half = t >> 7;
    float s1 = 0.f, s2 = 0.f;
    int rend = min(nrows, (int)(blockIdx.x * 64 + 64));
    for (int r = blockIdx.x * 64 + half; r < rend; r += 2) {
        float v = h[(size_t)r * 128 + c];
        s1 += v; s2 += v * v;
    }
    __shared__ float red[256];
    red[t] = s1; __syncthreads();
    if (half == 0) unsafeAtomicAdd(&sums[c], red[t] + red[t + 128]);
    __syncthreads();
    red[t] = s2; __syncthreads();
    if (half == 0) unsafeAtomicAdd(&sums[128 + c], red[t] + red[t + 128]);
}

// ---------- BN apply (no relu), in place — last layer only ----------
__global__ __launch_bounds__(256)
void bn_apply_kernel(float* __restrict__ h, const float* __restrict__ sums,
                     const float* __restrict__ scale, const float* __restrict__ shift) {
    int idx = blockIdx.x * 256 + threadIdx.x;
    int c = idx & 127;
    const float invN = 1.f / (float)NN;
    float mu = sums[c] * invN;
    float var = sums[128 + c] * invN - mu * mu;
    h[idx] = (h[idx] - mu) * rsqrtf(var + 1e-5f) * scale[c] + shift[c];
}

// ---------- global max pool ----------
__global__ __launch_bounds__(256)
void pool_kernel(const float* __restrict__ h, const int* __restrict__ batch,
                 unsigned* __restrict__ gkey) {
    int idx = blockIdx.x * 256 + threadIdx.x;
    int n = idx >> 7, c = idx & 127;
    atomicMax(&gkey[batch[n] * 128 + c], f2key(h[idx]));
}

// ---------- head MLP (single block) ----------
__global__ __launch_bounds__(256)
void head_kernel(const unsigned* __restrict__ gkey,
                 const float* __restrict__ W1, const float* __restrict__ b1,
                 const float* __restrict__ bn1s, const float* __restrict__ bn1b,
                 const float* __restrict__ W2, const float* __restrict__ b2,
                 const float* __restrict__ bn2s, const float* __restrict__ bn2b,
                 const float* __restrict__ Wout, const float* __restrict__ bout,
                 float* __restrict__ out) {
    __shared__ float g[64][128];
    __shared__ float z1[64][64];
    __shared__ float z2[64][32];
    int t = threadIdx.x;
    for (int i = t; i < 64 * 128; i += 256) g[i >> 7][i & 127] = key2f(gkey[i]);
    __syncthreads();
    for (int i = t; i < 64 * 64; i += 256) {
        int r = i >> 6, o = i & 63;
        const float* gr = g[r];
        const float* wr = W1 + (size_t)o * 128;
        float acc = b1[o];
        for (int k2 = 0; k2 < 128; ++k2) acc += gr[k2] * wr[k2];
        z1[r][o] = acc;
    }
    __syncthreads();
    if (t < 64) {
        float s1 = 0.f, s2 = 0.f;
        for (int r = 0; r < 64; ++r) { float v = z1[r][t]; s1 += v; s2 += v * v; }
        float mu = s1 * (1.f / 64.f), var = s2 * (1.f / 64.f) - mu * mu;
        float inv = rsqrtf(var + 1e-5f) * bn1s[t];
        float sh = bn1b[t];
        for (int r = 0; r < 64; ++r) {
            float v = (z1[r][t] - mu) * inv + sh;
            z1[r][t] = v > 0.f ? v : 0.f;
        }
    }
    __syncthreads();
    for (int i = t; i < 64 * 32; i += 256) {
        int r = i >> 5, o = i & 31;
        const float* wr = W2 + (size_t)o * 64;
        float acc = b2[o];
        for (int k2 = 0; k2 < 64; ++k2) acc += z1[r][k2] * wr[k2];
        z2[r][o] = acc;
    }
    __syncthreads();
    if (t < 32) {
        float s1 = 0.f, s2 = 0.f;
        for (int r = 0; r < 64; ++r) { float v = z2[r][t]; s1 += v; s2 += v * v; }
        float mu = s1 * (1.f / 64.f), var = s2 * (1.f / 64.f) - mu * mu;
        float inv = rsqrtf(var + 1e-5f) * bn2s[t];
        float sh = bn2b[t];
        for (int r = 0; r < 64; ++r) {
            float v = (z2[r][t] - mu) * inv + sh;
            z2[r][t] = v > 0.f ? v : 0.f;
        }
    }
    __syncthreads();
    for (int i = t; i < 64 * 64; i += 256) {
        int r = i >> 6, o = i & 63;
        const float* wr = Wout + (size_t)o * 32;
        float acc = bout[o];
        for (int k2 = 0; k2 < 32; ++k2) acc += z2[r][k2] * wr[k2];
        out[r * 64 + o] = acc;
    }
}

extern "C" void kernel_launch(void* const* d_in, const int* in_sizes, int n_in,
                              void* d_out, int out_size, void* d_ws, size_t ws_size,
                              hipStream_t stream) {
    const float* x         = (const float*)d_in[0];
    const int*   ei        = (const int*)d_in[1];
    const float* edge_attr = (const float*)d_in[2];
    const int*   batch     = (const int*)d_in[3];
    const float* lin_qkv   = (const float*)d_in[4];
    const float* lin_edge  = (const float*)d_in[5];
    const float* att       = (const float*)d_in[6];
    // d_in[7] gat_bias: cancels exactly under training-mode BN (mean-subtracted)
    const float* bn_scale  = (const float*)d_in[8];
    const float* bn_bias   = (const float*)d_in[9];
    const float* W1   = (const float*)d_in[10];
    const float* b1   = (const float*)d_in[11];
    const float* bn1s = (const float*)d_in[12];
    const float* bn1b = (const float*)d_in[13];
    const float* W2   = (const float*)d_in[14];
    const float* b2   = (const float*)d_in[15];
    const float* bn2s = (const float*)d_in[16];
    const float* bn2b = (const float*)d_in[17];
    const float* Wout = (const float*)d_in[18];
    const float* bout = (const float*)d_in[19];

    float* ws = (float*)d_ws;
    size_t off = 0;
    auto alloc = [&](size_t n) { float* p = ws + off; off += n; return p; };
    // contiguous zero-region first: deg | gkey | gsums[3][256]
    int*      deg   = (int*)alloc(NN);
    unsigned* gkey  = (unsigned*)alloc(64 * 128);
    float*    gsums = alloc(3 * 256);
    const size_t zeroBytes = ((size_t)NN + 64 * 128 + 3 * 256) * 4;
    float* hout = alloc((size_t)NN * 128);
    float* qa   = alloc((size_t)NN * 128);
    float* ka   = alloc((size_t)NN * 128);
    float* vv   = alloc((size_t)NN * 128);
    unsigned short* Apack = (unsigned short*)alloc((size_t)MB * 16384);  // MB*32768 ushorts
    unsigned short* Wpack = (unsigned short*)alloc(9 * 16384);           // 9*32768 ushorts
    int*   offs   = (int*)alloc(NN);
    int*   cursor = (int*)alloc(NN);
    int2*  csr    = (int2*)alloc((size_t)EE * 2);
    int*   psum   = (int*)alloc(256);
    int*   psx    = (int*)alloc(256);
    float* M      = alloc(3 * 128);

    const int edgeBlocks = (EE + 255) / 256;     // 1563
    const int scanBlocks = (NN + 255) / 256;     // 196
    const int packBlocks = MB * 8;               // 3128
    const int nodeBlocks = (NN * 128) / 256;     // 25000
    const int statBlocks = (NN + 63) / 64;       // 782
    const int fusedBlocks = (NN + 3) / 4;        // 12500

    hipMemsetAsync(deg, 0, zeroBytes, stream);
    wpack_kernel<<<144, 256, 0, stream>>>(lin_qkv, Wpack);
    compute_M_kernel<<<2, 256, 0, stream>>>(lin_edge, att, M);
    deg_count_kernel<<<edgeBlocks, 256, 0, stream>>>(ei, deg);
    scan_partial_kernel<<<scanBlocks, 256, 0, stream>>>(deg, psum);
    scan_top_kernel<<<1, 256, 0, stream>>>(psum, psx);
    scan_final_kernel<<<scanBlocks, 256, 0, stream>>>(deg, psx, offs, cursor);
    scatter_kernel<<<edgeBlocks, 256, 0, stream>>>(ei, cursor, csr);
    pack_kernel<<<packBlocks, 256, 0, stream>>>(x, nullptr, nullptr, nullptr, 0, Apack);

    for (int l = 0; l < 3; ++l) {
        qkv_mfma_kernel<<<dim3(MB, 3), 256, 0, stream>>>(
            Apack, Wpack, l, att + (size_t)l * 384, qa, ka, vv);

        fused_gat_kernel<<<fusedBlocks, 256, 0, stream>>>(
            qa, ka, vv, edge_attr, M + l * 128, offs, deg, csr, hout);

        bn_stats_kernel<<<statBlocks, 256, 0, stream>>>(hout, gsums + l * 256, NN);

        if (l < 2) {
            pack_kernel<<<packBlocks, 256, 0, stream>>>(
                hout, gsums + l * 256, bn_scale + l * 128, bn_bias + l * 128, 1, Apack);
        } else {
            bn_apply_kernel<<<nodeBlocks, 256, 0, stream>>>(
                hout, gsums + l * 256, bn_scale + l * 128, bn_bias + l * 128);
        }
    }

    pool_kernel<<<nodeBlocks, 256, 0, stream>>>(hout, batch, gkey);
    head_kernel<<<1, 256, 0, stream>>>(gkey, W1, b1, bn1s, bn1b, W2, b2, bn2s, bn2b, Wout, bout, (float*)d_out);
}

// Round 4
// 566.598 us; speedup vs baseline: 16.5505x; 1.2058x over previous
//
#include <hip/hip_runtime.h>
#include <hip/hip_bf16.h>
#include <hip/hip_fp16.h>
#include <cstddef>
#include <cstdint>

#define NN 50000
#define EE 400000
#define GG 64
#define MB 391   // ceil(NN/128)

typedef __attribute__((ext_vector_type(8))) short bf16x8;
typedef __attribute__((ext_vector_type(4))) float f32x4;

#define GLOAD_LDS16(g, l) __builtin_amdgcn_global_load_lds( \
    (const __attribute__((address_space(1))) void*)(g), \
    (__attribute__((address_space(3))) void*)(l), 16, 0, 0)

// ---------- helpers ----------
__device__ __forceinline__ unsigned f2key(float f) {
    unsigned u = __float_as_uint(f);
    return (u & 0x80000000u) ? ~u : (u | 0x80000000u);
}
__device__ __forceinline__ float key2f(unsigned k) {
    unsigned u = (k & 0x80000000u) ? (k ^ 0x80000000u) : ~k;
    return __uint_as_float(u);
}
__device__ __forceinline__ unsigned short f2bf(float f) {
    unsigned u = __float_as_uint(f);
    unsigned r = u + 0x7fffu + ((u >> 16) & 1u);
    return (unsigned short)(r >> 16);
}
__device__ __forceinline__ float bf2f(unsigned short b) {
    return __uint_as_float(((unsigned)b) << 16);
}

// ---------- M[l][h][d] = sum_c lin_edge[l][h*16+c][d] * att[l][2][h][c] ----------
__global__ void compute_M_kernel(const float* __restrict__ lin_edge,
                                 const float* __restrict__ att,
                                 float* __restrict__ M) {
    int t = blockIdx.x * 256 + threadIdx.x;
    if (t >= 3 * 128) return;
    int l = t >> 7, r = t & 127, h = r >> 4, d = r & 15;
    const float* le = lin_edge + (size_t)l * 128 * 16;
    const float* av = att + ((l * 3 + 2) * 128) + h * 16;
    float acc = 0.f;
#pragma unroll
    for (int c = 0; c < 16; ++c) acc += le[(h * 16 + c) * 16 + d] * av[c];
    M[t] = acc;
}

// ---------- weight packing: Wpack[l*3+mat][pc 8][kg 4][n 128][8k] bf16 ----------
__global__ __launch_bounds__(256)
void wpack_kernel(const float* __restrict__ lin_qkv, unsigned short* __restrict__ Wpack) {
    int g = blockIdx.x * 256 + threadIdx.x;   // [0, 9*4096)
    int lm = g >> 12;
    int r = g & 4095;
    int pc = r >> 9;
    int kg = (r >> 7) & 3;
    int n  = r & 127;
    int k0 = (pc & 3) * 32 + kg * 8;
    const float* row = lin_qkv + ((size_t)lm * 128 + n) * 128 + k0;
    unsigned short o[8] __attribute__((aligned(16)));
#pragma unroll
    for (int i = 0; i < 8; ++i) {
        float v = row[i];
        unsigned short h = f2bf(v);
        o[i] = (pc < 4) ? h : f2bf(v - bf2f(h));
    }
    *reinterpret_cast<uint4*>(Wpack + (size_t)g * 8) = *reinterpret_cast<const uint4*>(o);
}

// ---------- h packing (+optional BN+relu): Apack[mb][pc 8][kg 4][m 128][8k] ----------
__global__ __launch_bounds__(256)
void pack_kernel(const float* __restrict__ hin, const float* __restrict__ sums,
                 const float* __restrict__ scale, const float* __restrict__ shift,
                 int mode, unsigned short* __restrict__ Apack) {
    int s = blockIdx.x * 256 + threadIdx.x;   // [0, MB*2048)
    int mb = s >> 11;
    int r  = s & 2047;
    int kb = r >> 9;
    int kg = (r >> 7) & 3;
    int m  = r & 127;
    int node = mb * 128 + m;
    int k0 = kb * 32 + kg * 8;
    size_t hiSlot = ((size_t)(mb * 8 + kb) * 512 + (size_t)kg * 128 + m) * 8;
    size_t loSlot = ((size_t)(mb * 8 + kb + 4) * 512 + (size_t)kg * 128 + m) * 8;
    unsigned short hi[8] __attribute__((aligned(16)));
    unsigned short lo[8] __attribute__((aligned(16)));
    if (node < NN) {
        const float* row = hin + (size_t)node * 128 + k0;
#pragma unroll
        for (int i = 0; i < 8; ++i) {
            float v = row[i];
            if (mode) {
                int c = k0 + i;
                float mu = sums[c] * (1.f / NN);
                float var = sums[128 + c] * (1.f / NN) - mu * mu;
                v = (v - mu) * rsqrtf(var + 1e-5f) * scale[c] + shift[c];
                v = v > 0.f ? v : 0.f;
            }
            unsigned short h = f2bf(v);
            hi[i] = h;
            lo[i] = f2bf(v - bf2f(h));
        }
    } else {
#pragma unroll
        for (int i = 0; i < 8; ++i) { hi[i] = 0; lo[i] = 0; }
    }
    *reinterpret_cast<uint4*>(Apack + hiSlot) = *reinterpret_cast<const uint4*>(hi);
    *reinterpret_cast<uint4*>(Apack + loSlot) = *reinterpret_cast<const uint4*>(lo);
}

// ---------- QKV GEMM via MFMA, split-bf16 (K'=384), fp16 output ----------
__global__ __launch_bounds__(256, 3)
void qkv_mfma_kernel(const unsigned short* __restrict__ Apack,
                     const unsigned short* __restrict__ Wpack,
                     int layer,
                     const float* __restrict__ att_l,
                     __half* __restrict__ qa, __half* __restrict__ ka, __half* __restrict__ vv) {
    __shared__ unsigned short Ab[2][4096];
    __shared__ unsigned short Bb[2][4096];
    const int t = threadIdx.x;
    const int lane = t & 63;
    const int wave = t >> 6;
    const int wr = wave >> 1, wc = wave & 1;
    const int mb = blockIdx.x, mat = blockIdx.y;

    const unsigned short* Abase = Apack + (size_t)mb * 32768;
    const unsigned short* Bbase = Wpack + (size_t)(layer * 3 + mat) * 32768;

    f32x4 acc[4][4];
#pragma unroll
    for (int i = 0; i < 4; ++i)
#pragma unroll
        for (int j = 0; j < 4; ++j) acc[i][j] = (f32x4){0.f, 0.f, 0.f, 0.f};

    auto stage = [&](int c, int buf) {
        int ap = (c < 8) ? (c & 3) : (c - 4);   // A' = [hi, hi, lo]
        int bp = (c < 8) ? c : (c - 8);         // B' = [hi, lo, hi]
        const unsigned short* ga = Abase + (size_t)ap * 4096;
        const unsigned short* gb = Bbase + (size_t)bp * 4096;
        GLOAD_LDS16(ga + (size_t)(wave * 64 + lane) * 8,        &Ab[buf][(wave * 64) * 8]);
        GLOAD_LDS16(ga + (size_t)(256 + wave * 64 + lane) * 8,  &Ab[buf][(256 + wave * 64) * 8]);
        GLOAD_LDS16(gb + (size_t)(wave * 64 + lane) * 8,        &Bb[buf][(wave * 64) * 8]);
        GLOAD_LDS16(gb + (size_t)(256 + wave * 64 + lane) * 8,  &Bb[buf][(256 + wave * 64) * 8]);
    };

    stage(0, 0);
    __syncthreads();
    const int abase = ((lane >> 4) * 128 + wr * 64 + (lane & 15)) * 8;
    const int bbase = ((lane >> 4) * 128 + wc * 64 + (lane & 15)) * 8;
#pragma unroll
    for (int c = 0; c < 12; ++c) {
        int cur = c & 1;
        if (c < 11) stage(c + 1, cur ^ 1);
        bf16x8 aF[4], bF[4];
#pragma unroll
        for (int mf = 0; mf < 4; ++mf)
            aF[mf] = *reinterpret_cast<const bf16x8*>(&Ab[cur][abase + mf * 128]);
#pragma unroll
        for (int nf = 0; nf < 4; ++nf)
            bF[nf] = *reinterpret_cast<const bf16x8*>(&Bb[cur][bbase + nf * 128]);
#pragma unroll
        for (int mf = 0; mf < 4; ++mf)
#pragma unroll
            for (int nf = 0; nf < 4; ++nf)
                acc[mf][nf] = __builtin_amdgcn_mfma_f32_16x16x32_bf16(aF[mf], bF[nf], acc[mf][nf], 0, 0, 0);
        __syncthreads();
    }

    __half* outb = (mat == 0) ? qa : (mat == 1 ? ka : vv);
    float sc[4];
#pragma unroll
    for (int nf = 0; nf < 4; ++nf) {
        int col = wc * 64 + nf * 16 + (lane & 15);
        sc[nf] = (mat == 2) ? 1.f : att_l[mat * 128 + col];
    }
    const int rowq = (lane >> 4) * 4;
#pragma unroll
    for (int mf = 0; mf < 4; ++mf) {
        int row0 = mb * 128 + wr * 64 + mf * 16 + rowq;
#pragma unroll
        for (int reg = 0; reg < 4; ++reg) {
            int row = row0 + reg;
            if (row < NN) {
#pragma unroll
                for (int nf = 0; nf < 4; ++nf) {
                    int col = wc * 64 + nf * 16 + (lane & 15);
                    outb[(size_t)row * 128 + col] = __float2half(acc[mf][nf][reg] * sc[nf]);
                }
            }
        }
    }
}

// ---------- CSR build ----------
__global__ __launch_bounds__(256)
void deg_count_kernel(const int* __restrict__ ei, int* __restrict__ deg) {
    int e = blockIdx.x * 256 + threadIdx.x;
    if (e < EE) atomicAdd(&deg[ei[EE + e]], 1);
}

__global__ __launch_bounds__(256)
void scan_partial_kernel(const int* __restrict__ deg, int* __restrict__ psum) {
    __shared__ int red[256];
    int i = blockIdx.x * 256 + threadIdx.x;
    red[threadIdx.x] = (i < NN) ? deg[i] : 0;
    __syncthreads();
    for (int o = 128; o > 0; o >>= 1) {
        if (threadIdx.x < o) red[threadIdx.x] += red[threadIdx.x + o];
        __syncthreads();
    }
    if (threadIdx.x == 0) psum[blockIdx.x] = red[0];
}

__global__ __launch_bounds__(256)
void scan_top_kernel(const int* __restrict__ psum, int* __restrict__ psx) {
    __shared__ int sh[256];
    int t = threadIdx.x;
    int v = (t < 196) ? psum[t] : 0;
    sh[t] = v;
    __syncthreads();
    for (int o = 1; o < 256; o <<= 1) {
        int add = (t >= o) ? sh[t - o] : 0;
        __syncthreads();
        sh[t] += add;
        __syncthreads();
    }
    if (t < 196) psx[t] = sh[t] - v;
}

__global__ __launch_bounds__(256)
void scan_final_kernel(const int* __restrict__ deg, const int* __restrict__ psx,
                       int* __restrict__ offs, int* __restrict__ cursor) {
    __shared__ int sh[256];
    int t = threadIdx.x;
    int i = blockIdx.x * 256 + t;
    int v = (i < NN) ? deg[i] : 0;
    sh[t] = v;
    __syncthreads();
    for (int o = 1; o < 256; o <<= 1) {
        int add = (t >= o) ? sh[t - o] : 0;
        __syncthreads();
        sh[t] += add;
        __syncthreads();
    }
    if (i < NN) {
        int excl = sh[t] - v + psx[blockIdx.x];
        offs[i] = excl;
        cursor[i] = excl;
    }
}

__global__ __launch_bounds__(256)
void scatter_kernel(const int* __restrict__ ei, int* __restrict__ cursor,
                    int* __restrict__ csrc, int* __restrict__ ceid) {
    int e = blockIdx.x * 256 + threadIdx.x;
    if (e < EE) {
        int src = ei[e], dst = ei[EE + e];
        int pos = atomicAdd(&cursor[dst], 1);
        csrc[pos] = src;
        ceid[pos] = e;
    }
}

// ---------- eatt[l][pos][h] = edge_attr[ceid[pos]] . M[l][h]  (CSR order) ----------
__global__ __launch_bounds__(256)
void eatt_kernel(const float* __restrict__ edge_attr, const int* __restrict__ ceid,
                 const float* __restrict__ M, float* __restrict__ eatt) {
    int pos = blockIdx.x * 256 + threadIdx.x;
    if (pos >= EE) return;
    int e = ceid[pos];
    const float4* ep = reinterpret_cast<const float4*>(edge_attr + (size_t)e * 16);
    float4 a0 = ep[0], a1 = ep[1], a2 = ep[2], a3 = ep[3];
    float ea[16] = {a0.x, a0.y, a0.z, a0.w, a1.x, a1.y, a1.z, a1.w,
                    a2.x, a2.y, a2.z, a2.w, a3.x, a3.y, a3.z, a3.w};
#pragma unroll
    for (int l = 0; l < 3; ++l) {
        float o[8];
#pragma unroll
        for (int h = 0; h < 8; ++h) {
            const float* mp = M + l * 128 + h * 16;
            float acc = 0.f;
#pragma unroll
            for (int d = 0; d < 16; ++d) acc += ea[d] * mp[d];
            o[h] = acc;
        }
        float* outp = eatt + ((size_t)l * EE + pos) * 8;
#pragma unroll
        for (int h = 0; h < 8; ++h) outp[h] = o[h];
    }
}

// ---------- fused attention: one wave per dst, fp16 gathers, 2-edge unroll ----------
__global__ __launch_bounds__(256)
void fused_gat_kernel(const __half* __restrict__ qa, const __half* __restrict__ ka,
                      const __half* __restrict__ vv, const float* __restrict__ eatt_l,
                      const int* __restrict__ offs, const int* __restrict__ deg,
                      const int* __restrict__ csrc, float* __restrict__ hout) {
    int wid = threadIdx.x >> 6;
    int lane = threadIdx.x & 63;
    int n = blockIdx.x * 4 + wid;
    int h = lane >> 3;
    int c2 = (lane & 7) * 2;
    int ch = h * 16 + c2;

    float2 q = __half22float2(*reinterpret_cast<const __half2*>(qa + (size_t)n * 128 + ch));

    int start = offs[n], d = deg[n];
    const float* ebase = eatt_l + (size_t)start * 8 + h;
    const int* sbase = csrc + start;

    float m = -INFINITY, den = 0.f, acc0 = 0.f, acc1 = 0.f;
    int i = 0;
    for (; i + 2 <= d; i += 2) {
        int s0 = sbase[i], s1 = sbase[i + 1];
        float e0 = ebase[(size_t)i * 8];
        float e1 = ebase[(size_t)(i + 1) * 8];
        float2 k0 = __half22float2(*reinterpret_cast<const __half2*>(ka + (size_t)s0 * 128 + ch));
        float2 v0 = __half22float2(*reinterpret_cast<const __half2*>(vv + (size_t)s0 * 128 + ch));
        float2 k1 = __half22float2(*reinterpret_cast<const __half2*>(ka + (size_t)s1 * 128 + ch));
        float2 v1 = __half22float2(*reinterpret_cast<const __half2*>(vv + (size_t)s1 * 128 + ch));
        float p0 = q.x * k0.x + q.y * k0.y;
        float p1 = q.x * k1.x + q.y * k1.y;
        p0 += __shfl_xor(p0, 1); p0 += __shfl_xor(p0, 2); p0 += __shfl_xor(p0, 4);
        p1 += __shfl_xor(p1, 1); p1 += __shfl_xor(p1, 2); p1 += __shfl_xor(p1, 4);
        float a0 = p0 + e0; a0 = a0 > 0.f ? a0 : 0.2f * a0;
        float a1 = p1 + e1; a1 = a1 > 0.f ? a1 : 0.2f * a1;
        float mn = fmaxf(m, a0);
        float scl = __expf(m - mn);
        float p = __expf(a0 - mn);
        den = den * scl + p; acc0 = acc0 * scl + p * v0.x; acc1 = acc1 * scl + p * v0.y; m = mn;
        mn = fmaxf(m, a1);
        scl = __expf(m - mn);
        p = __expf(a1 - mn);
        den = den * scl + p; acc0 = acc0 * scl + p * v1.x; acc1 = acc1 * scl + p * v1.y; m = mn;
    }
    for (; i < d; ++i) {
        int s0 = sbase[i];
        float e0 = ebase[(size_t)i * 8];
        float2 k0 = __half22float2(*reinterpret_cast<const __half2*>(ka + (size_t)s0 * 128 + ch));
        float2 v0 = __half22float2(*reinterpret_cast<const __half2*>(vv + (size_t)s0 * 128 + ch));
        float p0 = q.x * k0.x + q.y * k0.y;
        p0 += __shfl_xor(p0, 1); p0 += __shfl_xor(p0, 2); p0 += __shfl_xor(p0, 4);
        float a0 = p0 + e0; a0 = a0 > 0.f ? a0 : 0.2f * a0;
        float mn = fmaxf(m, a0);
        float scl = __expf(m - mn);
        float p = __expf(a0 - mn);
        den = den * scl + p; acc0 = acc0 * scl + p * v0.x; acc1 = acc1 * scl + p * v0.y; m = mn;
    }
    float inv = 1.f / (den + 1e-16f);
    *reinterpret_cast<float2*>(hout + (size_t)n * 128 + ch) = make_float2(acc0 * inv, acc1 * inv);
}

// ---------- BN stats (sum, sumsq per channel) ----------
__global__ __launch_bounds__(256)
void bn_stats_kernel(const float* __restrict__ h, float* __restrict__ sums, int nrows) {
    int t = threadIdx.x;
    int c = t & 127, half = t >> 7;
    float s1 = 0.f, s2 = 0.f;
    int rend = min(nrows, (int)(blockIdx.x * 64 + 64));
    for (int r = blockIdx.x * 64 + half; r < rend; r += 2) {
        float v = h[(size_t)r * 128 + c];
        s1 += v; s2 += v * v;
    }
    __shared__ float red[256];
    red[t] = s1; __syncthreads();
    if (half == 0) unsafeAtomicAdd(&sums[c], red[t] + red[t + 128]);
    __syncthreads();
    red[t] = s2; __syncthreads();
    if (half == 0) unsafeAtomicAdd(&sums[128 + c], red[t] + red[t + 128]);
}

// ---------- last layer: BN apply + global max pool fused ----------
__global__ __launch_bounds__(256)
void bn_pool_kernel(const float* __restrict__ h, const float* __restrict__ sums,
                    const float* __restrict__ scale, const float* __restrict__ shift,
                    const int* __restrict__ batch, unsigned* __restrict__ gkey) {
    int idx = blockIdx.x * 256 + threadIdx.x;  // exactly N*128
    int n = idx >> 7, c = idx & 127;
    const float invN = 1.f / (float)NN;
    float mu = sums[c] * invN;
    float var = sums[128 + c] * invN - mu * mu;
    float v = (h[idx] - mu) * rsqrtf(var + 1e-5f) * scale[c] + shift[c];
    atomicMax(&gkey[batch[n] * 128 + c], f2key(v));
}

// ---------- head MLP (single block) ----------
__global__ __launch_bounds__(256)
void head_kernel(const unsigned* __restrict__ gkey,
                 const float* __restrict__ W1, const float* __restrict__ b1,
                 const float* __restrict__ bn1s, const float* __restrict__ bn1b,
                 const float* __restrict__ W2, const float* __restrict__ b2,
                 const float* __restrict__ bn2s, const float* __restrict__ bn2b,
                 const float* __restrict__ Wout, const float* __restrict__ bout,
                 float* __restrict__ out) {
    __shared__ float g[64][128];
    __shared__ float z1[64][64];
    __shared__ float z2[64][32];
    int t = threadIdx.x;
    for (int i = t; i < 64 * 128; i += 256) g[i >> 7][i & 127] = key2f(gkey[i]);
    __syncthreads();
    for (int i = t; i < 64 * 64; i += 256) {
        int r = i >> 6, o = i & 63;
        const float* gr = g[r];
        const float* wr = W1 + (size_t)o * 128;
        float acc = b1[o];
        for (int k2 = 0; k2 < 128; ++k2) acc += gr[k2] * wr[k2];
        z1[r][o] = acc;
    }
    __syncthreads();
    if (t < 64) {
        float s1 = 0.f, s2 = 0.f;
        for (int r = 0; r < 64; ++r) { float v = z1[r][t]; s1 += v; s2 += v * v; }
        float mu = s1 * (1.f / 64.f), var = s2 * (1.f / 64.f) - mu * mu;
        float inv = rsqrtf(var + 1e-5f) * bn1s[t];
        float sh = bn1b[t];
        for (int r = 0; r < 64; ++r) {
            float v = (z1[r][t] - mu) * inv + sh;
            z1[r][t] = v > 0.f ? v : 0.f;
        }
    }
    __syncthreads();
    for (int i = t; i < 64 * 32; i += 256) {
        int r = i >> 5, o = i & 31;
        const float* wr = W2 + (size_t)o * 64;
        float acc = b2[o];
        for (int k2 = 0; k2 < 64; ++k2) acc += z1[r][k2] * wr[k2];
        z2[r][o] = acc;
    }
    __syncthreads();
    if (t < 32) {
        float s1 = 0.f, s2 = 0.f;
        for (int r = 0; r < 64; ++r) { float v = z2[r][t]; s1 += v; s2 += v * v; }
        float mu = s1 * (1.f / 64.f), var = s2 * (1.f / 64.f) - mu * mu;
        float inv = rsqrtf(var + 1e-5f) * bn2s[t];
        float sh = bn2b[t];
        for (int r = 0; r < 64; ++r) {
            float v = (z2[r][t] - mu) * inv + sh;
            z2[r][t] = v > 0.f ? v : 0.f;
        }
    }
    __syncthreads();
    for (int i = t; i < 64 * 64; i += 256) {
        int r = i >> 6, o = i & 63;
        const float* wr = Wout + (size_t)o * 32;
        float acc = bout[o];
        for (int k2 = 0; k2 < 32; ++k2) acc += z2[r][k2] * wr[k2];
        out[r * 64 + o] = acc;
    }
}

extern "C" void kernel_launch(void* const* d_in, const int* in_sizes, int n_in,
                              void* d_out, int out_size, void* d_ws, size_t ws_size,
                              hipStream_t stream) {
    const float* x         = (const float*)d_in[0];
    const int*   ei        = (const int*)d_in[1];
    const float* edge_attr = (const float*)d_in[2];
    const int*   batch     = (const int*)d_in[3];
    const float* lin_qkv   = (const float*)d_in[4];
    const float* lin_edge  = (const float*)d_in[5];
    const float* att       = (const float*)d_in[6];
    // d_in[7] gat_bias: cancels exactly under training-mode BN (mean-subtracted)
    const float* bn_scale  = (const float*)d_in[8];
    const float* bn_bias   = (const float*)d_in[9];
    const float* W1   = (const float*)d_in[10];
    const float* b1   = (const float*)d_in[11];
    const float* bn1s = (const float*)d_in[12];
    const float* bn1b = (const float*)d_in[13];
    const float* W2   = (const float*)d_in[14];
    const float* b2   = (const float*)d_in[15];
    const float* bn2s = (const float*)d_in[16];
    const float* bn2b = (const float*)d_in[17];
    const float* Wout = (const float*)d_in[18];
    const float* bout = (const float*)d_in[19];

    float* ws = (float*)d_ws;
    size_t off = 0;
    auto alloc = [&](size_t n) { float* p = ws + off; off += n; return p; };
    // contiguous zero-region first: deg | gkey | gsums[3][256]
    int*      deg   = (int*)alloc(NN);
    unsigned* gkey  = (unsigned*)alloc(64 * 128);
    float*    gsums = alloc(3 * 256);
    const size_t zeroBytes = ((size_t)NN + 64 * 128 + 3 * 256) * 4;
    float*  hout = alloc((size_t)NN * 128);
    __half* qa   = (__half*)alloc((size_t)NN * 64);
    __half* ka   = (__half*)alloc((size_t)NN * 64);
    __half* vv   = (__half*)alloc((size_t)NN * 64);
    unsigned short* Apack = (unsigned short*)alloc((size_t)MB * 16384);  // MB*32768 ushorts
    unsigned short* Wpack = (unsigned short*)alloc(9 * 16384);           // 9*32768 ushorts
    int*   offs   = (int*)alloc(NN);
    int*   cursor = (int*)alloc(NN);
    int*   csrc   = (int*)alloc(EE);
    int*   ceid   = (int*)alloc(EE);
    float* eatt   = alloc((size_t)3 * EE * 8);
    int*   psum   = (int*)alloc(256);
    int*   psx    = (int*)alloc(256);
    float* M      = alloc(3 * 128);

    const int edgeBlocks = (EE + 255) / 256;     // 1563
    const int scanBlocks = (NN + 255) / 256;     // 196
    const int packBlocks = MB * 8;               // 3128
    const int nodeBlocks = (NN * 128) / 256;     // 25000
    const int statBlocks = (NN + 63) / 64;       // 782
    const int fusedBlocks = (NN + 3) / 4;        // 12500

    hipMemsetAsync(deg, 0, zeroBytes, stream);
    wpack_kernel<<<144, 256, 0, stream>>>(lin_qkv, Wpack);
    compute_M_kernel<<<2, 256, 0, stream>>>(lin_edge, att, M);
    deg_count_kernel<<<edgeBlocks, 256, 0, stream>>>(ei, deg);
    scan_partial_kernel<<<scanBlocks, 256, 0, stream>>>(deg, psum);
    scan_top_kernel<<<1, 256, 0, stream>>>(psum, psx);
    scan_final_kernel<<<scanBlocks, 256, 0, stream>>>(deg, psx, offs, cursor);
    scatter_kernel<<<edgeBlocks, 256, 0, stream>>>(ei, cursor, csrc, ceid);
    eatt_kernel<<<edgeBlocks, 256, 0, stream>>>(edge_attr, ceid, M, eatt);
    pack_kernel<<<packBlocks, 256, 0, stream>>>(x, nullptr, nullptr, nullptr, 0, Apack);

    for (int l = 0; l < 3; ++l) {
        qkv_mfma_kernel<<<dim3(MB, 3), 256, 0, stream>>>(
            Apack, Wpack, l, att + (size_t)l * 384, qa, ka, vv);

        fused_gat_kernel<<<fusedBlocks, 256, 0, stream>>>(
            qa, ka, vv, eatt + (size_t)l * EE * 8, offs, deg, csrc, hout);

        bn_stats_kernel<<<statBlocks, 256, 0, stream>>>(hout, gsums + l * 256, NN);

        if (l < 2) {
            pack_kernel<<<packBlocks, 256, 0, stream>>>(
                hout, gsums + l * 256, bn_scale + l * 128, bn_bias + l * 128, 1, Apack);
        } else {
            bn_pool_kernel<<<nodeBlocks, 256, 0, stream>>>(
                hout, gsums + l * 256, bn_scale + l * 128, bn_bias + l * 128, batch, gkey);
        }
    }

    head_kernel<<<1, 256, 0, stream>>>(gkey, W1, b1, bn1s, bn1b, W2, b2, bn2s, bn2b, Wout, bout, (float*)d_out);
}

// Round 5
// 539.272 us; speedup vs baseline: 17.3891x; 1.0507x over previous
//
#include <hip/hip_runtime.h>
#include <hip/hip_bf16.h>
#include <hip/hip_fp16.h>
#include <cstddef>
#include <cstdint>

#define NN 50000
#define EE 400000
#define GG 64
#define MB 391   // ceil(NN/128)

typedef __attribute__((ext_vector_type(8))) short bf16x8;
typedef __attribute__((ext_vector_type(4))) float f32x4;

#define GLOAD_LDS16(g, l) __builtin_amdgcn_global_load_lds( \
    (const __attribute__((address_space(1))) void*)(g), \
    (__attribute__((address_space(3))) void*)(l), 16, 0, 0)

// ---------- helpers ----------
__device__ __forceinline__ unsigned f2key(float f) {
    unsigned u = __float_as_uint(f);
    return (u & 0x80000000u) ? ~u : (u | 0x80000000u);
}
__device__ __forceinline__ float key2f(unsigned k) {
    unsigned u = (k & 0x80000000u) ? (k ^ 0x80000000u) : ~k;
    return __uint_as_float(u);
}
__device__ __forceinline__ unsigned short f2bf(float f) {
    unsigned u = __float_as_uint(f);
    unsigned r = u + 0x7fffu + ((u >> 16) & 1u);
    return (unsigned short)(r >> 16);
}
__device__ __forceinline__ float bf2f(unsigned short b) {
    return __uint_as_float(((unsigned)b) << 16);
}

// ---------- M[l][h][d] = sum_c lin_edge[l][h*16+c][d] * att[l][2][h][c] ----------
__global__ void compute_M_kernel(const float* __restrict__ lin_edge,
                                 const float* __restrict__ att,
                                 float* __restrict__ M) {
    int t = blockIdx.x * 256 + threadIdx.x;
    if (t >= 3 * 128) return;
    int l = t >> 7, r = t & 127, h = r >> 4, d = r & 15;
    const float* le = lin_edge + (size_t)l * 128 * 16;
    const float* av = att + ((l * 3 + 2) * 128) + h * 16;
    float acc = 0.f;
#pragma unroll
    for (int c = 0; c < 16; ++c) acc += le[(h * 16 + c) * 16 + d] * av[c];
    M[t] = acc;
}

// ---------- weight packing: Wpack[l*3+mat][pc 8][kg 4][n 128][8k] bf16 ----------
__global__ __launch_bounds__(256)
void wpack_kernel(const float* __restrict__ lin_qkv, unsigned short* __restrict__ Wpack) {
    int g = blockIdx.x * 256 + threadIdx.x;   // [0, 9*4096)
    int lm = g >> 12;
    int r = g & 4095;
    int pc = r >> 9;
    int kg = (r >> 7) & 3;
    int n  = r & 127;
    int k0 = (pc & 3) * 32 + kg * 8;
    const float* row = lin_qkv + ((size_t)lm * 128 + n) * 128 + k0;
    unsigned short o[8] __attribute__((aligned(16)));
#pragma unroll
    for (int i = 0; i < 8; ++i) {
        float v = row[i];
        unsigned short h = f2bf(v);
        o[i] = (pc < 4) ? h : f2bf(v - bf2f(h));
    }
    *reinterpret_cast<uint4*>(Wpack + (size_t)g * 8) = *reinterpret_cast<const uint4*>(o);
}

// ---------- h packing (+optional BN+relu): Apack[mb][pc 8][kg 4][m 128][8k] ----------
__global__ __launch_bounds__(256)
void pack_kernel(const float* __restrict__ hin, const float* __restrict__ sums,
                 const float* __restrict__ scale, const float* __restrict__ shift,
                 int mode, unsigned short* __restrict__ Apack) {
    int s = blockIdx.x * 256 + threadIdx.x;   // [0, MB*2048)
    int mb = s >> 11;
    int r  = s & 2047;
    int kb = r >> 9;
    int kg = (r >> 7) & 3;
    int m  = r & 127;
    int node = mb * 128 + m;
    int k0 = kb * 32 + kg * 8;
    size_t hiSlot = ((size_t)(mb * 8 + kb) * 512 + (size_t)kg * 128 + m) * 8;
    size_t loSlot = ((size_t)(mb * 8 + kb + 4) * 512 + (size_t)kg * 128 + m) * 8;
    unsigned short hi[8] __attribute__((aligned(16)));
    unsigned short lo[8] __attribute__((aligned(16)));
    if (node < NN) {
        const float* row = hin + (size_t)node * 128 + k0;
#pragma unroll
        for (int i = 0; i < 8; ++i) {
            float v = row[i];
            if (mode) {
                int c = k0 + i;
                float mu = sums[c] * (1.f / NN);
                float var = sums[128 + c] * (1.f / NN) - mu * mu;
                v = (v - mu) * rsqrtf(var + 1e-5f) * scale[c] + shift[c];
                v = v > 0.f ? v : 0.f;
            }
            unsigned short h = f2bf(v);
            hi[i] = h;
            lo[i] = f2bf(v - bf2f(h));
        }
    } else {
#pragma unroll
        for (int i = 0; i < 8; ++i) { hi[i] = 0; lo[i] = 0; }
    }
    *reinterpret_cast<uint4*>(Apack + hiSlot) = *reinterpret_cast<const uint4*>(hi);
    *reinterpret_cast<uint4*>(Apack + loSlot) = *reinterpret_cast<const uint4*>(lo);
}

// ---------- QKV GEMM via MFMA, split-bf16 (K'=384), fp16 output ----------
__global__ __launch_bounds__(256, 3)
void qkv_mfma_kernel(const unsigned short* __restrict__ Apack,
                     const unsigned short* __restrict__ Wpack,
                     int layer,
                     const float* __restrict__ att_l,
                     __half* __restrict__ qa, __half* __restrict__ ka, __half* __restrict__ vv) {
    __shared__ unsigned short Ab[2][4096];
    __shared__ unsigned short Bb[2][4096];
    const int t = threadIdx.x;
    const int lane = t & 63;
    const int wave = t >> 6;
    const int wr = wave >> 1, wc = wave & 1;
    const int mb = blockIdx.x, mat = blockIdx.y;

    const unsigned short* Abase = Apack + (size_t)mb * 32768;
    const unsigned short* Bbase = Wpack + (size_t)(layer * 3 + mat) * 32768;

    f32x4 acc[4][4];
#pragma unroll
    for (int i = 0; i < 4; ++i)
#pragma unroll
        for (int j = 0; j < 4; ++j) acc[i][j] = (f32x4){0.f, 0.f, 0.f, 0.f};

    auto stage = [&](int c, int buf) {
        int ap = (c < 8) ? (c & 3) : (c - 4);   // A' = [hi, hi, lo]
        int bp = (c < 8) ? c : (c - 8);         // B' = [hi, lo, hi]
        const unsigned short* ga = Abase + (size_t)ap * 4096;
        const unsigned short* gb = Bbase + (size_t)bp * 4096;
        GLOAD_LDS16(ga + (size_t)(wave * 64 + lane) * 8,        &Ab[buf][(wave * 64) * 8]);
        GLOAD_LDS16(ga + (size_t)(256 + wave * 64 + lane) * 8,  &Ab[buf][(256 + wave * 64) * 8]);
        GLOAD_LDS16(gb + (size_t)(wave * 64 + lane) * 8,        &Bb[buf][(wave * 64) * 8]);
        GLOAD_LDS16(gb + (size_t)(256 + wave * 64 + lane) * 8,  &Bb[buf][(256 + wave * 64) * 8]);
    };

    stage(0, 0);
    __syncthreads();
    const int abase = ((lane >> 4) * 128 + wr * 64 + (lane & 15)) * 8;
    const int bbase = ((lane >> 4) * 128 + wc * 64 + (lane & 15)) * 8;
#pragma unroll
    for (int c = 0; c < 12; ++c) {
        int cur = c & 1;
        if (c < 11) stage(c + 1, cur ^ 1);
        bf16x8 aF[4], bF[4];
#pragma unroll
        for (int mf = 0; mf < 4; ++mf)
            aF[mf] = *reinterpret_cast<const bf16x8*>(&Ab[cur][abase + mf * 128]);
#pragma unroll
        for (int nf = 0; nf < 4; ++nf)
            bF[nf] = *reinterpret_cast<const bf16x8*>(&Bb[cur][bbase + nf * 128]);
#pragma unroll
        for (int mf = 0; mf < 4; ++mf)
#pragma unroll
            for (int nf = 0; nf < 4; ++nf)
                acc[mf][nf] = __builtin_amdgcn_mfma_f32_16x16x32_bf16(aF[mf], bF[nf], acc[mf][nf], 0, 0, 0);
        __syncthreads();
    }

    __half* outb = (mat == 0) ? qa : (mat == 1 ? ka : vv);
    float sc[4];
#pragma unroll
    for (int nf = 0; nf < 4; ++nf) {
        int col = wc * 64 + nf * 16 + (lane & 15);
        sc[nf] = (mat == 2) ? 1.f : att_l[mat * 128 + col];
    }
    const int rowq = (lane >> 4) * 4;
#pragma unroll
    for (int mf = 0; mf < 4; ++mf) {
        int row0 = mb * 128 + wr * 64 + mf * 16 + rowq;
#pragma unroll
        for (int reg = 0; reg < 4; ++reg) {
            int row = row0 + reg;
            if (row < NN) {
#pragma unroll
                for (int nf = 0; nf < 4; ++nf) {
                    int col = wc * 64 + nf * 16 + (lane & 15);
                    outb[(size_t)row * 128 + col] = __float2half(acc[mf][nf][reg] * sc[nf]);
                }
            }
        }
    }
}

// ---------- CSR build ----------
__global__ __launch_bounds__(256)
void deg_count_kernel(const int* __restrict__ ei, int* __restrict__ deg) {
    int e = blockIdx.x * 256 + threadIdx.x;
    if (e < EE) atomicAdd(&deg[ei[EE + e]], 1);
}

__global__ __launch_bounds__(256)
void scan_partial_kernel(const int* __restrict__ deg, int* __restrict__ psum) {
    __shared__ int red[256];
    int i = blockIdx.x * 256 + threadIdx.x;
    red[threadIdx.x] = (i < NN) ? deg[i] : 0;
    __syncthreads();
    for (int o = 128; o > 0; o >>= 1) {
        if (threadIdx.x < o) red[threadIdx.x] += red[threadIdx.x + o];
        __syncthreads();
    }
    if (threadIdx.x == 0) psum[blockIdx.x] = red[0];
}

__global__ __launch_bounds__(256)
void scan_top_kernel(const int* __restrict__ psum, int* __restrict__ psx) {
    __shared__ int sh[256];
    int t = threadIdx.x;
    int v = (t < 196) ? psum[t] : 0;
    sh[t] = v;
    __syncthreads();
    for (int o = 1; o < 256; o <<= 1) {
        int add = (t >= o) ? sh[t - o] : 0;
        __syncthreads();
        sh[t] += add;
        __syncthreads();
    }
    if (t < 196) psx[t] = sh[t] - v;
}

__global__ __launch_bounds__(256)
void scan_final_kernel(const int* __restrict__ deg, const int* __restrict__ psx,
                       int* __restrict__ offs, int* __restrict__ cursor) {
    __shared__ int sh[256];
    int t = threadIdx.x;
    int i = blockIdx.x * 256 + t;
    int v = (i < NN) ? deg[i] : 0;
    sh[t] = v;
    __syncthreads();
    for (int o = 1; o < 256; o <<= 1) {
        int add = (t >= o) ? sh[t - o] : 0;
        __syncthreads();
        sh[t] += add;
        __syncthreads();
    }
    if (i < NN) {
        int excl = sh[t] - v + psx[blockIdx.x];
        offs[i] = excl;
        cursor[i] = excl;
    }
}

__global__ __launch_bounds__(256)
void scatter_kernel(const int* __restrict__ ei, int* __restrict__ cursor,
                    int* __restrict__ csrc, int* __restrict__ ceid) {
    int e = blockIdx.x * 256 + threadIdx.x;
    if (e < EE) {
        int src = ei[e], dst = ei[EE + e];
        int pos = atomicAdd(&cursor[dst], 1);
        csrc[pos] = src;
        ceid[pos] = e;
    }
}

// ---------- eatt[l][pos][h] = edge_attr[ceid[pos]] . M[l][h]  (CSR order) ----------
__global__ __launch_bounds__(256)
void eatt_kernel(const float* __restrict__ edge_attr, const int* __restrict__ ceid,
                 const float* __restrict__ M, float* __restrict__ eatt) {
    int pos = blockIdx.x * 256 + threadIdx.x;
    if (pos >= EE) return;
    int e = ceid[pos];
    const float4* ep = reinterpret_cast<const float4*>(edge_attr + (size_t)e * 16);
    float4 a0 = ep[0], a1 = ep[1], a2 = ep[2], a3 = ep[3];
    float ea[16] = {a0.x, a0.y, a0.z, a0.w, a1.x, a1.y, a1.z, a1.w,
                    a2.x, a2.y, a2.z, a2.w, a3.x, a3.y, a3.z, a3.w};
#pragma unroll
    for (int l = 0; l < 3; ++l) {
        float o[8];
#pragma unroll
        for (int h = 0; h < 8; ++h) {
            const float* mp = M + l * 128 + h * 16;
            float acc = 0.f;
#pragma unroll
            for (int d = 0; d < 16; ++d) acc += ea[d] * mp[d];
            o[h] = acc;
        }
        float* outp = eatt + ((size_t)l * EE + pos) * 8;
#pragma unroll
        for (int h = 0; h < 8; ++h) outp[h] = o[h];
    }
}

// ---------- fused attention: one wave per dst, fp16 gathers, 4-edge unroll ----------
__global__ __launch_bounds__(256)
void fused_gat_kernel(const __half* __restrict__ qa, const __half* __restrict__ ka,
                      const __half* __restrict__ vv, const float* __restrict__ eatt_l,
                      const int* __restrict__ offs, const int* __restrict__ deg,
                      const int* __restrict__ csrc, float* __restrict__ hout) {
    int wid = threadIdx.x >> 6;
    int lane = threadIdx.x & 63;
    int n = blockIdx.x * 4 + wid;
    int h = lane >> 3;
    int c2 = (lane & 7) * 2;
    int ch = h * 16 + c2;

    float2 q = __half22float2(*reinterpret_cast<const __half2*>(qa + (size_t)n * 128 + ch));

    int start = offs[n], d = deg[n];
    const float* ebase = eatt_l + (size_t)start * 8 + h;
    const int* sbase = csrc + start;

    float m = -INFINITY, den = 0.f, acc0 = 0.f, acc1 = 0.f;
    int i = 0;
    for (; i + 4 <= d; i += 4) {
        int s0 = sbase[i], s1 = sbase[i + 1], s2 = sbase[i + 2], s3 = sbase[i + 3];
        float e0 = ebase[(size_t)i * 8];
        float e1 = ebase[(size_t)(i + 1) * 8];
        float e2 = ebase[(size_t)(i + 2) * 8];
        float e3 = ebase[(size_t)(i + 3) * 8];
        float2 k0 = __half22float2(*reinterpret_cast<const __half2*>(ka + (size_t)s0 * 128 + ch));
        float2 k1 = __half22float2(*reinterpret_cast<const __half2*>(ka + (size_t)s1 * 128 + ch));
        float2 k2 = __half22float2(*reinterpret_cast<const __half2*>(ka + (size_t)s2 * 128 + ch));
        float2 k3 = __half22float2(*reinterpret_cast<const __half2*>(ka + (size_t)s3 * 128 + ch));
        float2 v0 = __half22float2(*reinterpret_cast<const __half2*>(vv + (size_t)s0 * 128 + ch));
        float2 v1 = __half22float2(*reinterpret_cast<const __half2*>(vv + (size_t)s1 * 128 + ch));
        float2 v2 = __half22float2(*reinterpret_cast<const __half2*>(vv + (size_t)s2 * 128 + ch));
        float2 v3 = __half22float2(*reinterpret_cast<const __half2*>(vv + (size_t)s3 * 128 + ch));
        float p0 = q.x * k0.x + q.y * k0.y;
        float p1 = q.x * k1.x + q.y * k1.y;
        float p2 = q.x * k2.x + q.y * k2.y;
        float p3 = q.x * k3.x + q.y * k3.y;
        p0 += __shfl_xor(p0, 1); p0 += __shfl_xor(p0, 2); p0 += __shfl_xor(p0, 4);
        p1 += __shfl_xor(p1, 1); p1 += __shfl_xor(p1, 2); p1 += __shfl_xor(p1, 4);
        p2 += __shfl_xor(p2, 1); p2 += __shfl_xor(p2, 2); p2 += __shfl_xor(p2, 4);
        p3 += __shfl_xor(p3, 1); p3 += __shfl_xor(p3, 2); p3 += __shfl_xor(p3, 4);
        float a0 = p0 + e0; a0 = a0 > 0.f ? a0 : 0.2f * a0;
        float a1 = p1 + e1; a1 = a1 > 0.f ? a1 : 0.2f * a1;
        float a2 = p2 + e2; a2 = a2 > 0.f ? a2 : 0.2f * a2;
        float a3 = p3 + e3; a3 = a3 > 0.f ? a3 : 0.2f * a3;
        float mn, scl, p;
        mn = fmaxf(m, a0); scl = __expf(m - mn); p = __expf(a0 - mn);
        den = den * scl + p; acc0 = acc0 * scl + p * v0.x; acc1 = acc1 * scl + p * v0.y; m = mn;
        mn = fmaxf(m, a1); scl = __expf(m - mn); p = __expf(a1 - mn);
        den = den * scl + p; acc0 = acc0 * scl + p * v1.x; acc1 = acc1 * scl + p * v1.y; m = mn;
        mn = fmaxf(m, a2); scl = __expf(m - mn); p = __expf(a2 - mn);
        den = den * scl + p; acc0 = acc0 * scl + p * v2.x; acc1 = acc1 * scl + p * v2.y; m = mn;
        mn = fmaxf(m, a3); scl = __expf(m - mn); p = __expf(a3 - mn);
        den = den * scl + p; acc0 = acc0 * scl + p * v3.x; acc1 = acc1 * scl + p * v3.y; m = mn;
    }
    for (; i < d; ++i) {
        int s0 = sbase[i];
        float e0 = ebase[(size_t)i * 8];
        float2 k0 = __half22float2(*reinterpret_cast<const __half2*>(ka + (size_t)s0 * 128 + ch));
        float2 v0 = __half22float2(*reinterpret_cast<const __half2*>(vv + (size_t)s0 * 128 + ch));
        float p0 = q.x * k0.x + q.y * k0.y;
        p0 += __shfl_xor(p0, 1); p0 += __shfl_xor(p0, 2); p0 += __shfl_xor(p0, 4);
        float a0 = p0 + e0; a0 = a0 > 0.f ? a0 : 0.2f * a0;
        float mn = fmaxf(m, a0);
        float scl = __expf(m - mn);
        float p = __expf(a0 - mn);
        den = den * scl + p; acc0 = acc0 * scl + p * v0.x; acc1 = acc1 * scl + p * v0.y; m = mn;
    }
    float inv = 1.f / (den + 1e-16f);
    *reinterpret_cast<float2*>(hout + (size_t)n * 128 + ch) = make_float2(acc0 * inv, acc1 * inv);
}

// ---------- BN stats (sum, sumsq per channel) ----------
__global__ __launch_bounds__(256)
void bn_stats_kernel(const float* __restrict__ h, float* __restrict__ sums, int nrows) {
    int t = threadIdx.x;
    int c = t & 127, half = t >> 7;
    float s1 = 0.f, s2 = 0.f;
    int rend = min(nrows, (int)(blockIdx.x * 64 + 64));
    for (int r = blockIdx.x * 64 + half; r < rend; r += 2) {
        float v = h[(size_t)r * 128 + c];
        s1 += v; s2 += v * v;
    }
    __shared__ float red[256];
    red[t] = s1; __syncthreads();
    if (half == 0) unsafeAtomicAdd(&sums[c], red[t] + red[t + 128]);
    __syncthreads();
    red[t] = s2; __syncthreads();
    if (half == 0) unsafeAtomicAdd(&sums[128 + c], red[t] + red[t + 128]);
}

// ---------- last layer: BN apply + segmented global max pool (batch sorted) ----------
__global__ __launch_bounds__(256)
void bn_pool_kernel(const float* __restrict__ h, const float* __restrict__ sums,
                    const float* __restrict__ scale, const float* __restrict__ shift,
                    const int* __restrict__ batch, unsigned* __restrict__ gkey) {
    int t = threadIdx.x;
    int c = t & 127, half = t >> 7;
    int r0 = blockIdx.x * 256;
    int rend = min(NN, r0 + 256);
    const float invN = 1.f / (float)NN;
    float mu = sums[c] * invN;
    float var = sums[128 + c] * invN - mu * mu;
    float iscl = rsqrtf(var + 1e-5f) * scale[c];
    float sh = shift[c];
    int curg = -1;
    float lmax = -INFINITY;
    for (int r = r0 + half; r < rend; r += 2) {
        int g = batch[r];
        if (g != curg) {
            if (curg >= 0) atomicMax(&gkey[curg * 128 + c], f2key(lmax));
            curg = g;
            lmax = -INFINITY;
        }
        float v = (h[(size_t)r * 128 + c] - mu) * iscl + sh;
        lmax = fmaxf(lmax, v);
    }
    if (curg >= 0) atomicMax(&gkey[curg * 128 + c], f2key(lmax));
}

// ---------- head MLP (single block) ----------
__global__ __launch_bounds__(256)
void head_kernel(const unsigned* __restrict__ gkey,
                 const float* __restrict__ W1, const float* __restrict__ b1,
                 const float* __restrict__ bn1s, const float* __restrict__ bn1b,
                 const float* __restrict__ W2, const float* __restrict__ b2,
                 const float* __restrict__ bn2s, const float* __restrict__ bn2b,
                 const float* __restrict__ Wout, const float* __restrict__ bout,
                 float* __restrict__ out) {
    __shared__ float g[64][128];
    __shared__ float z1[64][64];
    __shared__ float z2[64][32];
    int t = threadIdx.x;
    for (int i = t; i < 64 * 128; i += 256) g[i >> 7][i & 127] = key2f(gkey[i]);
    __syncthreads();
    for (int i = t; i < 64 * 64; i += 256) {
        int r = i >> 6, o = i & 63;
        const float* gr = g[r];
        const float* wr = W1 + (size_t)o * 128;
        float acc = b1[o];
        for (int k2 = 0; k2 < 128; ++k2) acc += gr[k2] * wr[k2];
        z1[r][o] = acc;
    }
    __syncthreads();
    if (t < 64) {
        float s1 = 0.f, s2 = 0.f;
        for (int r = 0; r < 64; ++r) { float v = z1[r][t]; s1 += v; s2 += v * v; }
        float mu = s1 * (1.f / 64.f), var = s2 * (1.f / 64.f) - mu * mu;
        float inv = rsqrtf(var + 1e-5f) * bn1s[t];
        float sh = bn1b[t];
        for (int r = 0; r < 64; ++r) {
            float v = (z1[r][t] - mu) * inv + sh;
            z1[r][t] = v > 0.f ? v : 0.f;
        }
    }
    __syncthreads();
    for (int i = t; i < 64 * 32; i += 256) {
        int r = i >> 5, o = i & 31;
        const float* wr = W2 + (size_t)o * 64;
        float acc = b2[o];
        for (int k2 = 0; k2 < 64; ++k2) acc += z1[r][k2] * wr[k2];
        z2[r][o] = acc;
    }
    __syncthreads();
    if (t < 32) {
        float s1 = 0.f, s2 = 0.f;
        for (int r = 0; r < 64; ++r) { float v = z2[r][t]; s1 += v; s2 += v * v; }
        float mu = s1 * (1.f / 64.f), var = s2 * (1.f / 64.f) - mu * mu;
        float inv = rsqrtf(var + 1e-5f) * bn2s[t];
        float sh = bn2b[t];
        for (int r = 0; r < 64; ++r) {
            float v = (z2[r][t] - mu) * inv + sh;
            z2[r][t] = v > 0.f ? v : 0.f;
        }
    }
    __syncthreads();
    for (int i = t; i < 64 * 64; i += 256) {
        int r = i >> 6, o = i & 63;
        const float* wr = Wout + (size_t)o * 32;
        float acc = bout[o];
        for (int k2 = 0; k2 < 32; ++k2) acc += z2[r][k2] * wr[k2];
        out[r * 64 + o] = acc;
    }
}

extern "C" void kernel_launch(void* const* d_in, const int* in_sizes, int n_in,
                              void* d_out, int out_size, void* d_ws, size_t ws_size,
                              hipStream_t stream) {
    const float* x         = (const float*)d_in[0];
    const int*   ei        = (const int*)d_in[1];
    const float* edge_attr = (const float*)d_in[2];
    const int*   batch     = (const int*)d_in[3];
    const float* lin_qkv   = (const float*)d_in[4];
    const float* lin_edge  = (const float*)d_in[5];
    const float* att       = (const float*)d_in[6];
    // d_in[7] gat_bias: cancels exactly under training-mode BN (mean-subtracted)
    const float* bn_scale  = (const float*)d_in[8];
    const float* bn_bias   = (const float*)d_in[9];
    const float* W1   = (const float*)d_in[10];
    const float* b1   = (const float*)d_in[11];
    const float* bn1s = (const float*)d_in[12];
    const float* bn1b = (const float*)d_in[13];
    const float* W2   = (const float*)d_in[14];
    const float* b2   = (const float*)d_in[15];
    const float* bn2s = (const float*)d_in[16];
    const float* bn2b = (const float*)d_in[17];
    const float* Wout = (const float*)d_in[18];
    const float* bout = (const float*)d_in[19];

    float* ws = (float*)d_ws;
    size_t off = 0;
    auto alloc = [&](size_t n) { float* p = ws + off; off += n; return p; };
    // contiguous zero-region first: deg | gkey | gsums[3][256]
    int*      deg   = (int*)alloc(NN);
    unsigned* gkey  = (unsigned*)alloc(64 * 128);
    float*    gsums = alloc(3 * 256);
    const size_t zeroBytes = ((size_t)NN + 64 * 128 + 3 * 256) * 4;
    float*  hout = alloc((size_t)NN * 128);
    __half* qa   = (__half*)alloc((size_t)NN * 64);
    __half* ka   = (__half*)alloc((size_t)NN * 64);
    __half* vv   = (__half*)alloc((size_t)NN * 64);
    unsigned short* Apack = (unsigned short*)alloc((size_t)MB * 16384);  // MB*32768 ushorts
    unsigned short* Wpack = (unsigned short*)alloc(9 * 16384);           // 9*32768 ushorts
    int*   offs   = (int*)alloc(NN);
    int*   cursor = (int*)alloc(NN);
    int*   csrc   = (int*)alloc(EE);
    int*   ceid   = (int*)alloc(EE);
    float* eatt   = alloc((size_t)3 * EE * 8);
    int*   psum   = (int*)alloc(256);
    int*   psx    = (int*)alloc(256);
    float* M      = alloc(3 * 128);

    const int edgeBlocks = (EE + 255) / 256;     // 1563
    const int scanBlocks = (NN + 255) / 256;     // 196
    const int packBlocks = MB * 8;               // 3128
    const int statBlocks = (NN + 63) / 64;       // 782
    const int fusedBlocks = (NN + 3) / 4;        // 12500

    hipMemsetAsync(deg, 0, zeroBytes, stream);
    wpack_kernel<<<144, 256, 0, stream>>>(lin_qkv, Wpack);
    compute_M_kernel<<<2, 256, 0, stream>>>(lin_edge, att, M);
    deg_count_kernel<<<edgeBlocks, 256, 0, stream>>>(ei, deg);
    scan_partial_kernel<<<scanBlocks, 256, 0, stream>>>(deg, psum);
    scan_top_kernel<<<1, 256, 0, stream>>>(psum, psx);
    scan_final_kernel<<<scanBlocks, 256, 0, stream>>>(deg, psx, offs, cursor);
    scatter_kernel<<<edgeBlocks, 256, 0, stream>>>(ei, cursor, csrc, ceid);
    eatt_kernel<<<edgeBlocks, 256, 0, stream>>>(edge_attr, ceid, M, eatt);
    pack_kernel<<<packBlocks, 256, 0, stream>>>(x, nullptr, nullptr, nullptr, 0, Apack);

    for (int l = 0; l < 3; ++l) {
        qkv_mfma_kernel<<<dim3(MB, 3), 256, 0, stream>>>(
            Apack, Wpack, l, att + (size_t)l * 384, qa, ka, vv);

        fused_gat_kernel<<<fusedBlocks, 256, 0, stream>>>(
            qa, ka, vv, eatt + (size_t)l * EE * 8, offs, deg, csrc, hout);

        bn_stats_kernel<<<statBlocks, 256, 0, stream>>>(hout, gsums + l * 256, NN);

        if (l < 2) {
            pack_kernel<<<packBlocks, 256, 0, stream>>>(
                hout, gsums + l * 256, bn_scale + l * 128, bn_bias + l * 128, 1, Apack);
        } else {
            bn_pool_kernel<<<scanBlocks, 256, 0, stream>>>(
                hout, gsums + l * 256, bn_scale + l * 128, bn_bias + l * 128, batch, gkey);
        }
    }

    head_kernel<<<1, 256, 0, stream>>>(gkey, W1, b1, bn1s, bn1b, W2, b2, bn2s, bn2b, Wout, bout, (float*)d_out);
}

// Round 6
// 518.845 us; speedup vs baseline: 18.0738x; 1.0394x over previous
//
#include <hip/hip_runtime.h>
#include <hip/hip_bf16.h>
#include <hip/hip_fp16.h>
#include <cstddef>
#include <cstdint>

#define NN 50000
#define EE 400000
#define GG 64
#define MB 391   // ceil(NN/128)

typedef __attribute__((ext_vector_type(8))) short bf16x8;
typedef __attribute__((ext_vector_type(4))) float f32x4;

#define GLOAD_LDS16(g, l) __builtin_amdgcn_global_load_lds( \
    (const __attribute__((address_space(1))) void*)(g), \
    (__attribute__((address_space(3))) void*)(l), 16, 0, 0)

// ---------- helpers ----------
__device__ __forceinline__ unsigned f2key(float f) {
    unsigned u = __float_as_uint(f);
    return (u & 0x80000000u) ? ~u : (u | 0x80000000u);
}
__device__ __forceinline__ float key2f(unsigned k) {
    unsigned u = (k & 0x80000000u) ? (k ^ 0x80000000u) : ~k;
    return __uint_as_float(u);
}
__device__ __forceinline__ unsigned short f2bf(float f) {
    unsigned u = __float_as_uint(f);
    unsigned r = u + 0x7fffu + ((u >> 16) & 1u);
    return (unsigned short)(r >> 16);
}
__device__ __forceinline__ float bf2f(unsigned short b) {
    return __uint_as_float(((unsigned)b) << 16);
}

// ---------- M[l][h][d] = sum_c lin_edge[l][h*16+c][d] * att[l][2][h][c] ----------
__global__ void compute_M_kernel(const float* __restrict__ lin_edge,
                                 const float* __restrict__ att,
                                 float* __restrict__ M) {
    int t = blockIdx.x * 256 + threadIdx.x;
    if (t >= 3 * 128) return;
    int l = t >> 7, r = t & 127, h = r >> 4, d = r & 15;
    const float* le = lin_edge + (size_t)l * 128 * 16;
    const float* av = att + ((l * 3 + 2) * 128) + h * 16;
    float acc = 0.f;
#pragma unroll
    for (int c = 0; c < 16; ++c) acc += le[(h * 16 + c) * 16 + d] * av[c];
    M[t] = acc;
}

// ---------- weight packing: Wpack[l*3+mat][pc 8][kg 4][n 128][8k] bf16 ----------
__global__ __launch_bounds__(256)
void wpack_kernel(const float* __restrict__ lin_qkv, unsigned short* __restrict__ Wpack) {
    int g = blockIdx.x * 256 + threadIdx.x;   // [0, 9*4096)
    int lm = g >> 12;
    int r = g & 4095;
    int pc = r >> 9;
    int kg = (r >> 7) & 3;
    int n  = r & 127;
    int k0 = (pc & 3) * 32 + kg * 8;
    const float* row = lin_qkv + ((size_t)lm * 128 + n) * 128 + k0;
    unsigned short o[8] __attribute__((aligned(16)));
#pragma unroll
    for (int i = 0; i < 8; ++i) {
        float v = row[i];
        unsigned short h = f2bf(v);
        o[i] = (pc < 4) ? h : f2bf(v - bf2f(h));
    }
    *reinterpret_cast<uint4*>(Wpack + (size_t)g * 8) = *reinterpret_cast<const uint4*>(o);
}

// ---------- h packing (+optional BN+relu): Apack[mb][pc 8][kg 4][m 128][8k] ----------
__global__ __launch_bounds__(256)
void pack_kernel(const float* __restrict__ hin, const float* __restrict__ sums,
                 const float* __restrict__ scale, const float* __restrict__ shift,
                 int mode, unsigned short* __restrict__ Apack) {
    int s = blockIdx.x * 256 + threadIdx.x;   // [0, MB*2048)
    int mb = s >> 11;
    int r  = s & 2047;
    int kb = r >> 9;
    int kg = (r >> 7) & 3;
    int m  = r & 127;
    int node = mb * 128 + m;
    int k0 = kb * 32 + kg * 8;
    size_t hiSlot = ((size_t)(mb * 8 + kb) * 512 + (size_t)kg * 128 + m) * 8;
    size_t loSlot = ((size_t)(mb * 8 + kb + 4) * 512 + (size_t)kg * 128 + m) * 8;
    unsigned short hi[8] __attribute__((aligned(16)));
    unsigned short lo[8] __attribute__((aligned(16)));
    if (node < NN) {
        const float* row = hin + (size_t)node * 128 + k0;
#pragma unroll
        for (int i = 0; i < 8; ++i) {
            float v = row[i];
            if (mode) {
                int c = k0 + i;
                float mu = sums[c] * (1.f / NN);
                float var = sums[128 + c] * (1.f / NN) - mu * mu;
                v = (v - mu) * rsqrtf(var + 1e-5f) * scale[c] + shift[c];
                v = v > 0.f ? v : 0.f;
            }
            unsigned short h = f2bf(v);
            hi[i] = h;
            lo[i] = f2bf(v - bf2f(h));
        }
    } else {
#pragma unroll
        for (int i = 0; i < 8; ++i) { hi[i] = 0; lo[i] = 0; }
    }
    *reinterpret_cast<uint4*>(Apack + hiSlot) = *reinterpret_cast<const uint4*>(hi);
    *reinterpret_cast<uint4*>(Apack + loSlot) = *reinterpret_cast<const uint4*>(lo);
}

// ---------- QKV GEMM via MFMA, split-bf16 (K'=384), fp16 output ----------
// q -> qa[n][128]; k -> kv[n][0:128]; v -> kv[n][128:256]
__global__ __launch_bounds__(256, 3)
void qkv_mfma_kernel(const unsigned short* __restrict__ Apack,
                     const unsigned short* __restrict__ Wpack,
                     int layer,
                     const float* __restrict__ att_l,
                     __half* __restrict__ qa, __half* __restrict__ kv) {
    __shared__ unsigned short Ab[2][4096];
    __shared__ unsigned short Bb[2][4096];
    const int t = threadIdx.x;
    const int lane = t & 63;
    const int wave = t >> 6;
    const int wr = wave >> 1, wc = wave & 1;
    const int mb = blockIdx.x, mat = blockIdx.y;

    const unsigned short* Abase = Apack + (size_t)mb * 32768;
    const unsigned short* Bbase = Wpack + (size_t)(layer * 3 + mat) * 32768;

    f32x4 acc[4][4];
#pragma unroll
    for (int i = 0; i < 4; ++i)
#pragma unroll
        for (int j = 0; j < 4; ++j) acc[i][j] = (f32x4){0.f, 0.f, 0.f, 0.f};

    auto stage = [&](int c, int buf) {
        int ap = (c < 8) ? (c & 3) : (c - 4);   // A' = [hi, hi, lo]
        int bp = (c < 8) ? c : (c - 8);         // B' = [hi, lo, hi]
        const unsigned short* ga = Abase + (size_t)ap * 4096;
        const unsigned short* gb = Bbase + (size_t)bp * 4096;
        GLOAD_LDS16(ga + (size_t)(wave * 64 + lane) * 8,        &Ab[buf][(wave * 64) * 8]);
        GLOAD_LDS16(ga + (size_t)(256 + wave * 64 + lane) * 8,  &Ab[buf][(256 + wave * 64) * 8]);
        GLOAD_LDS16(gb + (size_t)(wave * 64 + lane) * 8,        &Bb[buf][(wave * 64) * 8]);
        GLOAD_LDS16(gb + (size_t)(256 + wave * 64 + lane) * 8,  &Bb[buf][(256 + wave * 64) * 8]);
    };

    stage(0, 0);
    __syncthreads();
    const int abase = ((lane >> 4) * 128 + wr * 64 + (lane & 15)) * 8;
    const int bbase = ((lane >> 4) * 128 + wc * 64 + (lane & 15)) * 8;
#pragma unroll
    for (int c = 0; c < 12; ++c) {
        int cur = c & 1;
        if (c < 11) stage(c + 1, cur ^ 1);
        bf16x8 aF[4], bF[4];
#pragma unroll
        for (int mf = 0; mf < 4; ++mf)
            aF[mf] = *reinterpret_cast<const bf16x8*>(&Ab[cur][abase + mf * 128]);
#pragma unroll
        for (int nf = 0; nf < 4; ++nf)
            bF[nf] = *reinterpret_cast<const bf16x8*>(&Bb[cur][bbase + nf * 128]);
#pragma unroll
        for (int mf = 0; mf < 4; ++mf)
#pragma unroll
            for (int nf = 0; nf < 4; ++nf)
                acc[mf][nf] = __builtin_amdgcn_mfma_f32_16x16x32_bf16(aF[mf], bF[nf], acc[mf][nf], 0, 0, 0);
        __syncthreads();
    }

    __half* outb = (mat == 0) ? qa : kv;
    const size_t stride = (mat == 0) ? 128 : 256;
    const int coloff = (mat == 2) ? 128 : 0;
    float sc[4];
#pragma unroll
    for (int nf = 0; nf < 4; ++nf) {
        int col = wc * 64 + nf * 16 + (lane & 15);
        sc[nf] = (mat == 2) ? 1.f : att_l[mat * 128 + col];
    }
    const int rowq = (lane >> 4) * 4;
#pragma unroll
    for (int mf = 0; mf < 4; ++mf) {
        int row0 = mb * 128 + wr * 64 + mf * 16 + rowq;
#pragma unroll
        for (int reg = 0; reg < 4; ++reg) {
            int row = row0 + reg;
            if (row < NN) {
#pragma unroll
                for (int nf = 0; nf < 4; ++nf) {
                    int col = wc * 64 + nf * 16 + (lane & 15);
                    outb[(size_t)row * stride + coloff + col] = __float2half(acc[mf][nf][reg] * sc[nf]);
                }
            }
        }
    }
}

// ---------- CSR build ----------
__global__ __launch_bounds__(256)
void deg_count_kernel(const int* __restrict__ ei, int* __restrict__ deg) {
    int e = blockIdx.x * 256 + threadIdx.x;
    if (e < EE) atomicAdd(&deg[ei[EE + e]], 1);
}

__global__ __launch_bounds__(256)
void scan_partial_kernel(const int* __restrict__ deg, int* __restrict__ psum) {
    __shared__ int red[256];
    int i = blockIdx.x * 256 + threadIdx.x;
    red[threadIdx.x] = (i < NN) ? deg[i] : 0;
    __syncthreads();
    for (int o = 128; o > 0; o >>= 1) {
        if (threadIdx.x < o) red[threadIdx.x] += red[threadIdx.x + o];
        __syncthreads();
    }
    if (threadIdx.x == 0) psum[blockIdx.x] = red[0];
}

__global__ __launch_bounds__(256)
void scan_top_kernel(const int* __restrict__ psum, int* __restrict__ psx) {
    __shared__ int sh[256];
    int t = threadIdx.x;
    int v = (t < 196) ? psum[t] : 0;
    sh[t] = v;
    __syncthreads();
    for (int o = 1; o < 256; o <<= 1) {
        int add = (t >= o) ? sh[t - o] : 0;
        __syncthreads();
        sh[t] += add;
        __syncthreads();
    }
    if (t < 196) psx[t] = sh[t] - v;
}

__global__ __launch_bounds__(256)
void scan_final_kernel(const int* __restrict__ deg, const int* __restrict__ psx,
                       int* __restrict__ offs, int* __restrict__ cursor) {
    __shared__ int sh[256];
    int t = threadIdx.x;
    int i = blockIdx.x * 256 + t;
    int v = (i < NN) ? deg[i] : 0;
    sh[t] = v;
    __syncthreads();
    for (int o = 1; o < 256; o <<= 1) {
        int add = (t >= o) ? sh[t - o] : 0;
        __syncthreads();
        sh[t] += add;
        __syncthreads();
    }
    if (i < NN) {
        int excl = sh[t] - v + psx[blockIdx.x];
        offs[i] = excl;
        cursor[i] = excl;
    }
}

// ---------- scatter + eatt fused: csrc[pos]=src; eatt[l][pos][8h] = ea.M (fp16) ----------
__global__ __launch_bounds__(256)
void scatter_eatt_kernel(const int* __restrict__ ei, const float* __restrict__ edge_attr,
                         const float* __restrict__ M, int* __restrict__ cursor,
                         int* __restrict__ csrc, __half* __restrict__ eatt) {
    __shared__ float Ms[384];
    for (int i = threadIdx.x; i < 384; i += 256) Ms[i] = M[i];
    __syncthreads();
    int e = blockIdx.x * 256 + threadIdx.x;
    if (e >= EE) return;
    const float4* ep = reinterpret_cast<const float4*>(edge_attr + (size_t)e * 16);
    float4 a0 = ep[0], a1 = ep[1], a2 = ep[2], a3 = ep[3];
    float ea[16] = {a0.x, a0.y, a0.z, a0.w, a1.x, a1.y, a1.z, a1.w,
                    a2.x, a2.y, a2.z, a2.w, a3.x, a3.y, a3.z, a3.w};
    int src = ei[e], dst = ei[EE + e];
    int pos = atomicAdd(&cursor[dst], 1);
    csrc[pos] = src;
#pragma unroll
    for (int l = 0; l < 3; ++l) {
        __half o[8] __attribute__((aligned(16)));
#pragma unroll
        for (int h = 0; h < 8; ++h) {
            const float* mp = Ms + l * 128 + h * 16;
            float acc = 0.f;
#pragma unroll
            for (int d = 0; d < 16; ++d) acc += ea[d] * mp[d];
            o[h] = __float2half(acc);
        }
        *reinterpret_cast<uint4*>(eatt + ((size_t)l * EE + pos) * 8) =
            *reinterpret_cast<const uint4*>(o);
    }
}

// ---------- fused attention: ONE wave per dst, interleaved kv, fp16 eatt ----------
__global__ __launch_bounds__(64)
void fused_gat_kernel(const __half* __restrict__ qa, const __half* __restrict__ kv,
                      const __half* __restrict__ eatt_l,
                      const int* __restrict__ offs, const int* __restrict__ deg,
                      const int* __restrict__ csrc, float* __restrict__ hout) {
    int lane = threadIdx.x;
    int n = blockIdx.x;
    int h = lane >> 3;
    int c2h = lane & 7;          // half2 index within head
    int chh = h * 8 + c2h;       // half2 index within 128-ch row
    int ch = chh * 2;

    float2 q = __half22float2(*reinterpret_cast<const __half2*>(qa + (size_t)n * 128 + ch));

    int start = offs[n], d = deg[n];
    const __half* ebase = eatt_l + (size_t)start * 8 + h;
    const int* sbase = csrc + start;

    float m = -INFINITY, den = 0.f, acc0 = 0.f, acc1 = 0.f;
    int i = 0;
    for (; i + 4 <= d; i += 4) {
        int s0 = sbase[i], s1 = sbase[i + 1], s2 = sbase[i + 2], s3 = sbase[i + 3];
        float e0 = __half2float(ebase[(size_t)i * 8]);
        float e1 = __half2float(ebase[(size_t)(i + 1) * 8]);
        float e2 = __half2float(ebase[(size_t)(i + 2) * 8]);
        float e3 = __half2float(ebase[(size_t)(i + 3) * 8]);
        const __half2* p0h = reinterpret_cast<const __half2*>(kv + (size_t)s0 * 256);
        const __half2* p1h = reinterpret_cast<const __half2*>(kv + (size_t)s1 * 256);
        const __half2* p2h = reinterpret_cast<const __half2*>(kv + (size_t)s2 * 256);
        const __half2* p3h = reinterpret_cast<const __half2*>(kv + (size_t)s3 * 256);
        float2 k0 = __half22float2(p0h[chh]);
        float2 k1 = __half22float2(p1h[chh]);
        float2 k2 = __half22float2(p2h[chh]);
        float2 k3 = __half22float2(p3h[chh]);
        float2 v0 = __half22float2(p0h[64 + chh]);
        float2 v1 = __half22float2(p1h[64 + chh]);
        float2 v2 = __half22float2(p2h[64 + chh]);
        float2 v3 = __half22float2(p3h[64 + chh]);
        float p0 = q.x * k0.x + q.y * k0.y;
        float p1 = q.x * k1.x + q.y * k1.y;
        float p2 = q.x * k2.x + q.y * k2.y;
        float p3 = q.x * k3.x + q.y * k3.y;
        p0 += __shfl_xor(p0, 1); p0 += __shfl_xor(p0, 2); p0 += __shfl_xor(p0, 4);
        p1 += __shfl_xor(p1, 1); p1 += __shfl_xor(p1, 2); p1 += __shfl_xor(p1, 4);
        p2 += __shfl_xor(p2, 1); p2 += __shfl_xor(p2, 2); p2 += __shfl_xor(p2, 4);
        p3 += __shfl_xor(p3, 1); p3 += __shfl_xor(p3, 2); p3 += __shfl_xor(p3, 4);
        float a0 = p0 + e0; a0 = a0 > 0.f ? a0 : 0.2f * a0;
        float a1 = p1 + e1; a1 = a1 > 0.f ? a1 : 0.2f * a1;
        float a2 = p2 + e2; a2 = a2 > 0.f ? a2 : 0.2f * a2;
        float a3 = p3 + e3; a3 = a3 > 0.f ? a3 : 0.2f * a3;
        float mn, scl, p;
        mn = fmaxf(m, a0); scl = __expf(m - mn); p = __expf(a0 - mn);
        den = den * scl + p; acc0 = acc0 * scl + p * v0.x; acc1 = acc1 * scl + p * v0.y; m = mn;
        mn = fmaxf(m, a1); scl = __expf(m - mn); p = __expf(a1 - mn);
        den = den * scl + p; acc0 = acc0 * scl + p * v1.x; acc1 = acc1 * scl + p * v1.y; m = mn;
        mn = fmaxf(m, a2); scl = __expf(m - mn); p = __expf(a2 - mn);
        den = den * scl + p; acc0 = acc0 * scl + p * v2.x; acc1 = acc1 * scl + p * v2.y; m = mn;
        mn = fmaxf(m, a3); scl = __expf(m - mn); p = __expf(a3 - mn);
        den = den * scl + p; acc0 = acc0 * scl + p * v3.x; acc1 = acc1 * scl + p * v3.y; m = mn;
    }
    for (; i < d; ++i) {
        int s0 = sbase[i];
        float e0 = __half2float(ebase[(size_t)i * 8]);
        const __half2* p0h = reinterpret_cast<const __half2*>(kv + (size_t)s0 * 256);
        float2 k0 = __half22float2(p0h[chh]);
        float2 v0 = __half22float2(p0h[64 + chh]);
        float p0 = q.x * k0.x + q.y * k0.y;
        p0 += __shfl_xor(p0, 1); p0 += __shfl_xor(p0, 2); p0 += __shfl_xor(p0, 4);
        float a0 = p0 + e0; a0 = a0 > 0.f ? a0 : 0.2f * a0;
        float mn = fmaxf(m, a0);
        float scl = __expf(m - mn);
        float p = __expf(a0 - mn);
        den = den * scl + p; acc0 = acc0 * scl + p * v0.x; acc1 = acc1 * scl + p * v0.y; m = mn;
    }
    float inv = 1.f / (den + 1e-16f);
    *reinterpret_cast<float2*>(hout + (size_t)n * 128 + ch) = make_float2(acc0 * inv, acc1 * inv);
}

// ---------- BN stats (sum, sumsq per channel) ----------
__global__ __launch_bounds__(256)
void bn_stats_kernel(const float* __restrict__ h, float* __restrict__ sums, int nrows) {
    int t = threadIdx.x;
    int c = t & 127, half = t >> 7;
    float s1 = 0.f, s2 = 0.f;
    int rend = min(nrows, (int)(blockIdx.x * 64 + 64));
    for (int r = blockIdx.x * 64 + half; r < rend; r += 2) {
        float v = h[(size_t)r * 128 + c];
        s1 += v; s2 += v * v;
    }
    __shared__ float red[256];
    red[t] = s1; __syncthreads();
    if (half == 0) unsafeAtomicAdd(&sums[c], red[t] + red[t + 128]);
    __syncthreads();
    red[t] = s2; __syncthreads();
    if (half == 0) unsafeAtomicAdd(&sums[128 + c], red[t] + red[t + 128]);
}

// ---------- last layer: BN apply + segmented global max pool (batch sorted) ----------
__global__ __launch_bounds__(256)
void bn_pool_kernel(const float* __restrict__ h, const float* __restrict__ sums,
                    const float* __restrict__ scale, const float* __restrict__ shift,
                    const int* __restrict__ batch, unsigned* __restrict__ gkey) {
    int t = threadIdx.x;
    int c = t & 127, half = t >> 7;
    int r0 = blockIdx.x * 256;
    int rend = min(NN, r0 + 256);
    const float invN = 1.f / (float)NN;
    float mu = sums[c] * invN;
    float var = sums[128 + c] * invN - mu * mu;
    float iscl = rsqrtf(var + 1e-5f) * scale[c];
    float sh = shift[c];
    int curg = -1;
    float lmax = -INFINITY;
    for (int r = r0 + half; r < rend; r += 2) {
        int g = batch[r];
        if (g != curg) {
            if (curg >= 0) atomicMax(&gkey[curg * 128 + c], f2key(lmax));
            curg = g;
            lmax = -INFINITY;
        }
        float v = (h[(size_t)r * 128 + c] - mu) * iscl + sh;
        lmax = fmaxf(lmax, v);
    }
    if (curg >= 0) atomicMax(&gkey[curg * 128 + c], f2key(lmax));
}

// ---------- head MLP (single block) ----------
__global__ __launch_bounds__(256)
void head_kernel(const unsigned* __restrict__ gkey,
                 const float* __restrict__ W1, const float* __restrict__ b1,
                 const float* __restrict__ bn1s, const float* __restrict__ bn1b,
                 const float* __restrict__ W2, const float* __restrict__ b2,
                 const float* __restrict__ bn2s, const float* __restrict__ bn2b,
                 const float* __restrict__ Wout, const float* __restrict__ bout,
                 float* __restrict__ out) {
    __shared__ float g[64][128];
    __shared__ float z1[64][64];
    __shared__ float z2[64][32];
    int t = threadIdx.x;
    for (int i = t; i < 64 * 128; i += 256) g[i >> 7][i & 127] = key2f(gkey[i]);
    __syncthreads();
    for (int i = t; i < 64 * 64; i += 256) {
        int r = i >> 6, o = i & 63;
        const float* gr = g[r];
        const float* wr = W1 + (size_t)o * 128;
        float acc = b1[o];
        for (int k2 = 0; k2 < 128; ++k2) acc += gr[k2] * wr[k2];
        z1[r][o] = acc;
    }
    __syncthreads();
    if (t < 64) {
        float s1 = 0.f, s2 = 0.f;
        for (int r = 0; r < 64; ++r) { float v = z1[r][t]; s1 += v; s2 += v * v; }
        float mu = s1 * (1.f / 64.f), var = s2 * (1.f / 64.f) - mu * mu;
        float inv = rsqrtf(var + 1e-5f) * bn1s[t];
        float sh = bn1b[t];
        for (int r = 0; r < 64; ++r) {
            float v = (z1[r][t] - mu) * inv + sh;
            z1[r][t] = v > 0.f ? v : 0.f;
        }
    }
    __syncthreads();
    for (int i = t; i < 64 * 32; i += 256) {
        int r = i >> 5, o = i & 31;
        const float* wr = W2 + (size_t)o * 64;
        float acc = b2[o];
        for (int k2 = 0; k2 < 64; ++k2) acc += z1[r][k2] * wr[k2];
        z2[r][o] = acc;
    }
    __syncthreads();
    if (t < 32) {
        float s1 = 0.f, s2 = 0.f;
        for (int r = 0; r < 64; ++r) { float v = z2[r][t]; s1 += v; s2 += v * v; }
        float mu = s1 * (1.f / 64.f), var = s2 * (1.f / 64.f) - mu * mu;
        float inv = rsqrtf(var + 1e-5f) * bn2s[t];
        float sh = bn2b[t];
        for (int r = 0; r < 64; ++r) {
            float v = (z2[r][t] - mu) * inv + sh;
            z2[r][t] = v > 0.f ? v : 0.f;
        }
    }
    __syncthreads();
    for (int i = t; i < 64 * 64; i += 256) {
        int r = i >> 6, o = i & 63;
        const float* wr = Wout + (size_t)o * 32;
        float acc = bout[o];
        for (int k2 = 0; k2 < 32; ++k2) acc += z2[r][k2] * wr[k2];
        out[r * 64 + o] = acc;
    }
}

extern "C" void kernel_launch(void* const* d_in, const int* in_sizes, int n_in,
                              void* d_out, int out_size, void* d_ws, size_t ws_size,
                              hipStream_t stream) {
    const float* x         = (const float*)d_in[0];
    const int*   ei        = (const int*)d_in[1];
    const float* edge_attr = (const float*)d_in[2];
    const int*   batch     = (const int*)d_in[3];
    const float* lin_qkv   = (const float*)d_in[4];
    const float* lin_edge  = (const float*)d_in[5];
    const float* att       = (const float*)d_in[6];
    // d_in[7] gat_bias: cancels exactly under training-mode BN (mean-subtracted)
    const float* bn_scale  = (const float*)d_in[8];
    const float* bn_bias   = (const float*)d_in[9];
    const float* W1   = (const float*)d_in[10];
    const float* b1   = (const float*)d_in[11];
    const float* bn1s = (const float*)d_in[12];
    const float* bn1b = (const float*)d_in[13];
    const float* W2   = (const float*)d_in[14];
    const float* b2   = (const float*)d_in[15];
    const float* bn2s = (const float*)d_in[16];
    const float* bn2b = (const float*)d_in[17];
    const float* Wout = (const float*)d_in[18];
    const float* bout = (const float*)d_in[19];

    float* ws = (float*)d_ws;
    size_t off = 0;
    auto alloc = [&](size_t n) { float* p = ws + off; off += n; return p; };
    // contiguous zero-region first: deg | gkey | gsums[3][256]
    int*      deg   = (int*)alloc(NN);
    unsigned* gkey  = (unsigned*)alloc(64 * 128);
    float*    gsums = alloc(3 * 256);
    const size_t zeroBytes = ((size_t)NN + 64 * 128 + 3 * 256) * 4;
    float*  hout = alloc((size_t)NN * 128);
    __half* qa   = (__half*)alloc((size_t)NN * 64);
    __half* kv   = (__half*)alloc((size_t)NN * 128);   // k|v interleaved, fp16
    unsigned short* Apack = (unsigned short*)alloc((size_t)MB * 16384);  // MB*32768 ushorts
    unsigned short* Wpack = (unsigned short*)alloc(9 * 16384);           // 9*32768 ushorts
    int*    offs   = (int*)alloc(NN);
    int*    cursor = (int*)alloc(NN);
    int*    csrc   = (int*)alloc(EE);
    __half* eatt   = (__half*)alloc((size_t)3 * EE * 4);  // [l][EE][8] fp16
    int*    psum   = (int*)alloc(256);
    int*    psx    = (int*)alloc(256);
    float*  M      = alloc(3 * 128);

    const int edgeBlocks = (EE + 255) / 256;     // 1563
    const int scanBlocks = (NN + 255) / 256;     // 196
    const int packBlocks = MB * 8;               // 3128
    const int statBlocks = (NN + 63) / 64;       // 782

    hipMemsetAsync(deg, 0, zeroBytes, stream);
    wpack_kernel<<<144, 256, 0, stream>>>(lin_qkv, Wpack);
    compute_M_kernel<<<2, 256, 0, stream>>>(lin_edge, att, M);
    deg_count_kernel<<<edgeBlocks, 256, 0, stream>>>(ei, deg);
    scan_partial_kernel<<<scanBlocks, 256, 0, stream>>>(deg, psum);
    scan_top_kernel<<<1, 256, 0, stream>>>(psum, psx);
    scan_final_kernel<<<scanBlocks, 256, 0, stream>>>(deg, psx, offs, cursor);
    scatter_eatt_kernel<<<edgeBlocks, 256, 0, stream>>>(ei, edge_attr, M, cursor, csrc, eatt);
    pack_kernel<<<packBlocks, 256, 0, stream>>>(x, nullptr, nullptr, nullptr, 0, Apack);

    for (int l = 0; l < 3; ++l) {
        qkv_mfma_kernel<<<dim3(MB, 3), 256, 0, stream>>>(
            Apack, Wpack, l, att + (size_t)l * 384, qa, kv);

        fused_gat_kernel<<<NN, 64, 0, stream>>>(
            qa, kv, eatt + (size_t)l * EE * 8, offs, deg, csrc, hout);

        bn_stats_kernel<<<statBlocks, 256, 0, stream>>>(hout, gsums + l * 256, NN);

        if (l < 2) {
            pack_kernel<<<packBlocks, 256, 0, stream>>>(
                hout, gsums + l * 256, bn_scale + l * 128, bn_bias + l * 128, 1, Apack);
        } else {
            bn_pool_kernel<<<scanBlocks, 256, 0, stream>>>(
                hout, gsums + l * 256, bn_scale + l * 128, bn_bias + l * 128, batch, gkey);
        }
    }

    head_kernel<<<1, 256, 0, stream>>>(gkey, W1, b1, bn1s, bn1b, W2, b2, bn2s, bn2b, Wout, bout, (float*)d_out);
}

// Round 7
// 470.414 us; speedup vs baseline: 19.9346x; 1.1030x over previous
//
#include <hip/hip_runtime.h>
#include <hip/hip_bf16.h>
#include <hip/hip_fp16.h>
#include <cstddef>
#include <cstdint>

#define NN 50000
#define EE 400000
#define GG 64
#define MB 391   // ceil(NN/128)

typedef __attribute__((ext_vector_type(8))) short bf16x8;
typedef __attribute__((ext_vector_type(4))) float f32x4;

#define GLOAD_LDS16(g, l) __builtin_amdgcn_global_load_lds( \
    (const __attribute__((address_space(1))) void*)(g), \
    (__attribute__((address_space(3))) void*)(l), 16, 0, 0)

// ---------- helpers ----------
__device__ __forceinline__ unsigned f2key(float f) {
    unsigned u = __float_as_uint(f);
    return (u & 0x80000000u) ? ~u : (u | 0x80000000u);
}
__device__ __forceinline__ float key2f(unsigned k) {
    unsigned u = (k & 0x80000000u) ? (k ^ 0x80000000u) : ~k;
    return __uint_as_float(u);
}
__device__ __forceinline__ unsigned short f2bf(float f) {
    unsigned u = __float_as_uint(f);
    unsigned r = u + 0x7fffu + ((u >> 16) & 1u);
    return (unsigned short)(r >> 16);
}
__device__ __forceinline__ float bf2f(unsigned short b) {
    return __uint_as_float(((unsigned)b) << 16);
}

// ---------- M[l][h][d] = sum_c lin_edge[l][h*16+c][d] * att[l][2][h][c] ----------
__global__ void compute_M_kernel(const float* __restrict__ lin_edge,
                                 const float* __restrict__ att,
                                 float* __restrict__ M) {
    int t = blockIdx.x * 256 + threadIdx.x;
    if (t >= 3 * 128) return;
    int l = t >> 7, r = t & 127, h = r >> 4, d = r & 15;
    const float* le = lin_edge + (size_t)l * 128 * 16;
    const float* av = att + ((l * 3 + 2) * 128) + h * 16;
    float acc = 0.f;
#pragma unroll
    for (int c = 0; c < 16; ++c) acc += le[(h * 16 + c) * 16 + d] * av[c];
    M[t] = acc;
}

// ---------- weight packing: Wpack[l*3+mat][pc 8][kg 4][n 128][8k] bf16 ----------
__global__ __launch_bounds__(256)
void wpack_kernel(const float* __restrict__ lin_qkv, unsigned short* __restrict__ Wpack) {
    int g = blockIdx.x * 256 + threadIdx.x;   // [0, 9*4096)
    int lm = g >> 12;
    int r = g & 4095;
    int pc = r >> 9;
    int kg = (r >> 7) & 3;
    int n  = r & 127;
    int k0 = (pc & 3) * 32 + kg * 8;
    const float* row = lin_qkv + ((size_t)lm * 128 + n) * 128 + k0;
    unsigned short o[8] __attribute__((aligned(16)));
#pragma unroll
    for (int i = 0; i < 8; ++i) {
        float v = row[i];
        unsigned short h = f2bf(v);
        o[i] = (pc < 4) ? h : f2bf(v - bf2f(h));
    }
    *reinterpret_cast<uint4*>(Wpack + (size_t)g * 8) = *reinterpret_cast<const uint4*>(o);
}

// ---------- h packing (+optional BN+relu): Apack[mb][pc 8][kg 4][m 128][8k] ----------
__global__ __launch_bounds__(256)
void pack_kernel(const float* __restrict__ hin, const float* __restrict__ sums,
                 const float* __restrict__ scale, const float* __restrict__ shift,
                 int mode, unsigned short* __restrict__ Apack) {
    int s = blockIdx.x * 256 + threadIdx.x;   // [0, MB*2048)
    int mb = s >> 11;
    int r  = s & 2047;
    int kb = r >> 9;
    int kg = (r >> 7) & 3;
    int m  = r & 127;
    int node = mb * 128 + m;
    int k0 = kb * 32 + kg * 8;
    size_t hiSlot = ((size_t)(mb * 8 + kb) * 512 + (size_t)kg * 128 + m) * 8;
    size_t loSlot = ((size_t)(mb * 8 + kb + 4) * 512 + (size_t)kg * 128 + m) * 8;
    unsigned short hi[8] __attribute__((aligned(16)));
    unsigned short lo[8] __attribute__((aligned(16)));
    if (node < NN) {
        const float* row = hin + (size_t)node * 128 + k0;
#pragma unroll
        for (int i = 0; i < 8; ++i) {
            float v = row[i];
            if (mode) {
                int c = k0 + i;
                float mu = sums[c] * (1.f / NN);
                float var = sums[128 + c] * (1.f / NN) - mu * mu;
                v = (v - mu) * rsqrtf(var + 1e-5f) * scale[c] + shift[c];
                v = v > 0.f ? v : 0.f;
            }
            unsigned short h = f2bf(v);
            hi[i] = h;
            lo[i] = f2bf(v - bf2f(h));
        }
    } else {
#pragma unroll
        for (int i = 0; i < 8; ++i) { hi[i] = 0; lo[i] = 0; }
    }
    *reinterpret_cast<uint4*>(Apack + hiSlot) = *reinterpret_cast<const uint4*>(hi);
    *reinterpret_cast<uint4*>(Apack + loSlot) = *reinterpret_cast<const uint4*>(lo);
}

// ---------- QKV GEMM via MFMA, split-bf16 (K'=384), fp16 output ----------
// q -> qa[n][128]; k -> kv[n][0:128]; v -> kv[n][128:256]
__global__ __launch_bounds__(256, 3)
void qkv_mfma_kernel(const unsigned short* __restrict__ Apack,
                     const unsigned short* __restrict__ Wpack,
                     int layer,
                     const float* __restrict__ att_l,
                     __half* __restrict__ qa, __half* __restrict__ kv) {
    __shared__ unsigned short Ab[2][4096];
    __shared__ unsigned short Bb[2][4096];
    const int t = threadIdx.x;
    const int lane = t & 63;
    const int wave = t >> 6;
    const int wr = wave >> 1, wc = wave & 1;
    const int mb = blockIdx.x, mat = blockIdx.y;

    const unsigned short* Abase = Apack + (size_t)mb * 32768;
    const unsigned short* Bbase = Wpack + (size_t)(layer * 3 + mat) * 32768;

    f32x4 acc[4][4];
#pragma unroll
    for (int i = 0; i < 4; ++i)
#pragma unroll
        for (int j = 0; j < 4; ++j) acc[i][j] = (f32x4){0.f, 0.f, 0.f, 0.f};

    auto stage = [&](int c, int buf) {
        int ap = (c < 8) ? (c & 3) : (c - 4);   // A' = [hi, hi, lo]
        int bp = (c < 8) ? c : (c - 8);         // B' = [hi, lo, hi]
        const unsigned short* ga = Abase + (size_t)ap * 4096;
        const unsigned short* gb = Bbase + (size_t)bp * 4096;
        GLOAD_LDS16(ga + (size_t)(wave * 64 + lane) * 8,        &Ab[buf][(wave * 64) * 8]);
        GLOAD_LDS16(ga + (size_t)(256 + wave * 64 + lane) * 8,  &Ab[buf][(256 + wave * 64) * 8]);
        GLOAD_LDS16(gb + (size_t)(wave * 64 + lane) * 8,        &Bb[buf][(wave * 64) * 8]);
        GLOAD_LDS16(gb + (size_t)(256 + wave * 64 + lane) * 8,  &Bb[buf][(256 + wave * 64) * 8]);
    };

    stage(0, 0);
    __syncthreads();
    const int abase = ((lane >> 4) * 128 + wr * 64 + (lane & 15)) * 8;
    const int bbase = ((lane >> 4) * 128 + wc * 64 + (lane & 15)) * 8;
#pragma unroll
    for (int c = 0; c < 12; ++c) {
        int cur = c & 1;
        if (c < 11) stage(c + 1, cur ^ 1);
        bf16x8 aF[4], bF[4];
#pragma unroll
        for (int mf = 0; mf < 4; ++mf)
            aF[mf] = *reinterpret_cast<const bf16x8*>(&Ab[cur][abase + mf * 128]);
#pragma unroll
        for (int nf = 0; nf < 4; ++nf)
            bF[nf] = *reinterpret_cast<const bf16x8*>(&Bb[cur][bbase + nf * 128]);
#pragma unroll
        for (int mf = 0; mf < 4; ++mf)
#pragma unroll
            for (int nf = 0; nf < 4; ++nf)
                acc[mf][nf] = __builtin_amdgcn_mfma_f32_16x16x32_bf16(aF[mf], bF[nf], acc[mf][nf], 0, 0, 0);
        __syncthreads();
    }

    __half* outb = (mat == 0) ? qa : kv;
    const size_t stride = (mat == 0) ? 128 : 256;
    const int coloff = (mat == 2) ? 128 : 0;
    float sc[4];
#pragma unroll
    for (int nf = 0; nf < 4; ++nf) {
        int col = wc * 64 + nf * 16 + (lane & 15);
        sc[nf] = (mat == 2) ? 1.f : att_l[mat * 128 + col];
    }
    const int rowq = (lane >> 4) * 4;
#pragma unroll
    for (int mf = 0; mf < 4; ++mf) {
        int row0 = mb * 128 + wr * 64 + mf * 16 + rowq;
#pragma unroll
        for (int reg = 0; reg < 4; ++reg) {
            int row = row0 + reg;
            if (row < NN) {
#pragma unroll
                for (int nf = 0; nf < 4; ++nf) {
                    int col = wc * 64 + nf * 16 + (lane & 15);
                    outb[(size_t)row * stride + coloff + col] = __float2half(acc[mf][nf][reg] * sc[nf]);
                }
            }
        }
    }
}

// ---------- CSR build ----------
__global__ __launch_bounds__(256)
void deg_count_kernel(const int* __restrict__ ei, int* __restrict__ deg) {
    int e = blockIdx.x * 256 + threadIdx.x;
    if (e < EE) atomicAdd(&deg[ei[EE + e]], 1);
}

__global__ __launch_bounds__(256)
void scan_partial_kernel(const int* __restrict__ deg, int* __restrict__ psum) {
    __shared__ int red[256];
    int i = blockIdx.x * 256 + threadIdx.x;
    red[threadIdx.x] = (i < NN) ? deg[i] : 0;
    __syncthreads();
    for (int o = 128; o > 0; o >>= 1) {
        if (threadIdx.x < o) red[threadIdx.x] += red[threadIdx.x + o];
        __syncthreads();
    }
    if (threadIdx.x == 0) psum[blockIdx.x] = red[0];
}

__global__ __launch_bounds__(256)
void scan_top_kernel(const int* __restrict__ psum, int* __restrict__ psx) {
    __shared__ int sh[256];
    int t = threadIdx.x;
    int v = (t < 196) ? psum[t] : 0;
    sh[t] = v;
    __syncthreads();
    for (int o = 1; o < 256; o <<= 1) {
        int add = (t >= o) ? sh[t - o] : 0;
        __syncthreads();
        sh[t] += add;
        __syncthreads();
    }
    if (t < 196) psx[t] = sh[t] - v;
}

__global__ __launch_bounds__(256)
void scan_final_kernel(const int* __restrict__ deg, const int* __restrict__ psx,
                       int* __restrict__ offs, int* __restrict__ cursor) {
    __shared__ int sh[256];
    int t = threadIdx.x;
    int i = blockIdx.x * 256 + t;
    int v = (i < NN) ? deg[i] : 0;
    sh[t] = v;
    __syncthreads();
    for (int o = 1; o < 256; o <<= 1) {
        int add = (t >= o) ? sh[t - o] : 0;
        __syncthreads();
        sh[t] += add;
        __syncthreads();
    }
    if (i < NN) {
        int excl = sh[t] - v + psx[blockIdx.x];
        offs[i] = excl;
        cursor[i] = excl;
    }
}

// ---------- scatter + eatt fused: csrc[pos]=src; eatt[l][pos][8h] = ea.M (fp16) ----------
__global__ __launch_bounds__(256)
void scatter_eatt_kernel(const int* __restrict__ ei, const float* __restrict__ edge_attr,
                         const float* __restrict__ M, int* __restrict__ cursor,
                         int* __restrict__ csrc, __half* __restrict__ eatt) {
    __shared__ float Ms[384];
    for (int i = threadIdx.x; i < 384; i += 256) Ms[i] = M[i];
    __syncthreads();
    int e = blockIdx.x * 256 + threadIdx.x;
    if (e >= EE) return;
    const float4* ep = reinterpret_cast<const float4*>(edge_attr + (size_t)e * 16);
    float4 a0 = ep[0], a1 = ep[1], a2 = ep[2], a3 = ep[3];
    float ea[16] = {a0.x, a0.y, a0.z, a0.w, a1.x, a1.y, a1.z, a1.w,
                    a2.x, a2.y, a2.z, a2.w, a3.x, a3.y, a3.z, a3.w};
    int src = ei[e], dst = ei[EE + e];
    int pos = atomicAdd(&cursor[dst], 1);
    csrc[pos] = src;
#pragma unroll
    for (int l = 0; l < 3; ++l) {
        __half o[8] __attribute__((aligned(16)));
#pragma unroll
        for (int h = 0; h < 8; ++h) {
            const float* mp = Ms + l * 128 + h * 16;
            float acc = 0.f;
#pragma unroll
            for (int d = 0; d < 16; ++d) acc += ea[d] * mp[d];
            o[h] = __float2half(acc);
        }
        *reinterpret_cast<uint4*>(eatt + ((size_t)l * EE + pos) * 8) =
            *reinterpret_cast<const uint4*>(o);
    }
}

// ---------- fused attention: 2 waves/block, one dst per wave ----------
__global__ __launch_bounds__(128)
void fused_gat_kernel(const __half* __restrict__ qa, const __half* __restrict__ kv,
                      const __half* __restrict__ eatt_l,
                      const int* __restrict__ offs, const int* __restrict__ deg,
                      const int* __restrict__ csrc, float* __restrict__ hout) {
    int lane = threadIdx.x & 63;
    int n = blockIdx.x * 2 + (threadIdx.x >> 6);
    if (n >= NN) return;
    int h = lane >> 3;
    int c2h = lane & 7;          // half2 index within head
    int chh = h * 8 + c2h;       // half2 index within 128-ch row
    int ch = chh * 2;

    float2 q = __half22float2(*reinterpret_cast<const __half2*>(qa + (size_t)n * 128 + ch));

    int start = offs[n], d = deg[n];
    const __half* ebase = eatt_l + (size_t)start * 8 + h;
    const int* sbase = csrc + start;

    float m = -INFINITY, den = 0.f, acc0 = 0.f, acc1 = 0.f;
    int i = 0;
    for (; i + 4 <= d; i += 4) {
        int s0 = sbase[i], s1 = sbase[i + 1], s2 = sbase[i + 2], s3 = sbase[i + 3];
        float e0 = __half2float(ebase[(size_t)i * 8]);
        float e1 = __half2float(ebase[(size_t)(i + 1) * 8]);
        float e2 = __half2float(ebase[(size_t)(i + 2) * 8]);
        float e3 = __half2float(ebase[(size_t)(i + 3) * 8]);
        const __half2* p0h = reinterpret_cast<const __half2*>(kv + (size_t)s0 * 256);
        const __half2* p1h = reinterpret_cast<const __half2*>(kv + (size_t)s1 * 256);
        const __half2* p2h = reinterpret_cast<const __half2*>(kv + (size_t)s2 * 256);
        const __half2* p3h = reinterpret_cast<const __half2*>(kv + (size_t)s3 * 256);
        float2 k0 = __half22float2(p0h[chh]);
        float2 k1 = __half22float2(p1h[chh]);
        float2 k2 = __half22float2(p2h[chh]);
        float2 k3 = __half22float2(p3h[chh]);
        float2 v0 = __half22float2(p0h[64 + chh]);
        float2 v1 = __half22float2(p1h[64 + chh]);
        float2 v2 = __half22float2(p2h[64 + chh]);
        float2 v3 = __half22float2(p3h[64 + chh]);
        float p0 = q.x * k0.x + q.y * k0.y;
        float p1 = q.x * k1.x + q.y * k1.y;
        float p2 = q.x * k2.x + q.y * k2.y;
        float p3 = q.x * k3.x + q.y * k3.y;
        p0 += __shfl_xor(p0, 1); p0 += __shfl_xor(p0, 2); p0 += __shfl_xor(p0, 4);
        p1 += __shfl_xor(p1, 1); p1 += __shfl_xor(p1, 2); p1 += __shfl_xor(p1, 4);
        p2 += __shfl_xor(p2, 1); p2 += __shfl_xor(p2, 2); p2 += __shfl_xor(p2, 4);
        p3 += __shfl_xor(p3, 1); p3 += __shfl_xor(p3, 2); p3 += __shfl_xor(p3, 4);
        float a0 = p0 + e0; a0 = a0 > 0.f ? a0 : 0.2f * a0;
        float a1 = p1 + e1; a1 = a1 > 0.f ? a1 : 0.2f * a1;
        float a2 = p2 + e2; a2 = a2 > 0.f ? a2 : 0.2f * a2;
        float a3 = p3 + e3; a3 = a3 > 0.f ? a3 : 0.2f * a3;
        float mn, scl, p;
        mn = fmaxf(m, a0); scl = __expf(m - mn); p = __expf(a0 - mn);
        den = den * scl + p; acc0 = acc0 * scl + p * v0.x; acc1 = acc1 * scl + p * v0.y; m = mn;
        mn = fmaxf(m, a1); scl = __expf(m - mn); p = __expf(a1 - mn);
        den = den * scl + p; acc0 = acc0 * scl + p * v1.x; acc1 = acc1 * scl + p * v1.y; m = mn;
        mn = fmaxf(m, a2); scl = __expf(m - mn); p = __expf(a2 - mn);
        den = den * scl + p; acc0 = acc0 * scl + p * v2.x; acc1 = acc1 * scl + p * v2.y; m = mn;
        mn = fmaxf(m, a3); scl = __expf(m - mn); p = __expf(a3 - mn);
        den = den * scl + p; acc0 = acc0 * scl + p * v3.x; acc1 = acc1 * scl + p * v3.y; m = mn;
    }
    for (; i < d; ++i) {
        int s0 = sbase[i];
        float e0 = __half2float(ebase[(size_t)i * 8]);
        const __half2* p0h = reinterpret_cast<const __half2*>(kv + (size_t)s0 * 256);
        float2 k0 = __half22float2(p0h[chh]);
        float2 v0 = __half22float2(p0h[64 + chh]);
        float p0 = q.x * k0.x + q.y * k0.y;
        p0 += __shfl_xor(p0, 1); p0 += __shfl_xor(p0, 2); p0 += __shfl_xor(p0, 4);
        float a0 = p0 + e0; a0 = a0 > 0.f ? a0 : 0.2f * a0;
        float mn = fmaxf(m, a0);
        float scl = __expf(m - mn);
        float p = __expf(a0 - mn);
        den = den * scl + p; acc0 = acc0 * scl + p * v0.x; acc1 = acc1 * scl + p * v0.y; m = mn;
    }
    float inv = 1.f / (den + 1e-16f);
    *reinterpret_cast<float2*>(hout + (size_t)n * 128 + ch) = make_float2(acc0 * inv, acc1 * inv);
}

// ---------- BN stats (sum, sumsq per channel), float4-vectorized ----------
__global__ __launch_bounds__(256)
void bn_stats_kernel(const float* __restrict__ h, float* __restrict__ sums) {
    __shared__ float red[2][8][128];
    int t = threadIdx.x;
    int cg = t & 31;          // channel quad: channels cg*4 .. cg*4+3
    int rofs = t >> 5;        // 0..7
    int r0 = blockIdx.x * 64;
    int rend = min(NN, r0 + 64);
    float4 s1 = make_float4(0.f, 0.f, 0.f, 0.f);
    float4 s2 = make_float4(0.f, 0.f, 0.f, 0.f);
    for (int r = r0 + rofs; r < rend; r += 8) {
        float4 v = *reinterpret_cast<const float4*>(h + (size_t)r * 128 + cg * 4);
        s1.x += v.x; s1.y += v.y; s1.z += v.z; s1.w += v.w;
        s2.x += v.x * v.x; s2.y += v.y * v.y; s2.z += v.z * v.z; s2.w += v.w * v.w;
    }
    *reinterpret_cast<float4*>(&red[0][rofs][cg * 4]) = s1;
    *reinterpret_cast<float4*>(&red[1][rofs][cg * 4]) = s2;
    __syncthreads();
    if (t < 128) {
        float a = 0.f, b = 0.f;
#pragma unroll
        for (int i = 0; i < 8; ++i) { a += red[0][i][t]; b += red[1][i][t]; }
        unsafeAtomicAdd(&sums[t], a);
        unsafeAtomicAdd(&sums[128 + t], b);
    }
}

// ---------- last layer: BN apply + segmented global max pool (batch sorted) ----------
__global__ __launch_bounds__(256)
void bn_pool_kernel(const float* __restrict__ h, const float* __restrict__ sums,
                    const float* __restrict__ scale, const float* __restrict__ shift,
                    const int* __restrict__ batch, unsigned* __restrict__ gkey) {
    int t = threadIdx.x;
    int c = t & 127, half = t >> 7;
    int r0 = blockIdx.x * 32;
    int rend = min(NN, r0 + 32);
    const float invN = 1.f / (float)NN;
    float mu = sums[c] * invN;
    float var = sums[128 + c] * invN - mu * mu;
    float iscl = rsqrtf(var + 1e-5f) * scale[c];
    float sh = shift[c];
    int curg = -1;
    float lmax = -INFINITY;
    for (int r = r0 + half; r < rend; r += 2) {
        int g = batch[r];
        if (g != curg) {
            if (curg >= 0) atomicMax(&gkey[curg * 128 + c], f2key(lmax));
            curg = g;
            lmax = -INFINITY;
        }
        float v = (h[(size_t)r * 128 + c] - mu) * iscl + sh;
        lmax = fmaxf(lmax, v);
    }
    if (curg >= 0) atomicMax(&gkey[curg * 128 + c], f2key(lmax));
}

// ---------- head MLP (single block) ----------
__global__ __launch_bounds__(256)
void head_kernel(const unsigned* __restrict__ gkey,
                 const float* __restrict__ W1, const float* __restrict__ b1,
                 const float* __restrict__ bn1s, const float* __restrict__ bn1b,
                 const float* __restrict__ W2, const float* __restrict__ b2,
                 const float* __restrict__ bn2s, const float* __restrict__ bn2b,
                 const float* __restrict__ Wout, const float* __restrict__ bout,
                 float* __restrict__ out) {
    __shared__ float g[64][128];
    __shared__ float z1[64][64];
    __shared__ float z2[64][32];
    int t = threadIdx.x;
    for (int i = t; i < 64 * 128; i += 256) g[i >> 7][i & 127] = key2f(gkey[i]);
    __syncthreads();
    for (int i = t; i < 64 * 64; i += 256) {
        int r = i >> 6, o = i & 63;
        const float* gr = g[r];
        const float* wr = W1 + (size_t)o * 128;
        float acc = b1[o];
        for (int k2 = 0; k2 < 128; ++k2) acc += gr[k2] * wr[k2];
        z1[r][o] = acc;
    }
    __syncthreads();
    if (t < 64) {
        float s1 = 0.f, s2 = 0.f;
        for (int r = 0; r < 64; ++r) { float v = z1[r][t]; s1 += v; s2 += v * v; }
        float mu = s1 * (1.f / 64.f), var = s2 * (1.f / 64.f) - mu * mu;
        float inv = rsqrtf(var + 1e-5f) * bn1s[t];
        float sh = bn1b[t];
        for (int r = 0; r < 64; ++r) {
            float v = (z1[r][t] - mu) * inv + sh;
            z1[r][t] = v > 0.f ? v : 0.f;
        }
    }
    __syncthreads();
    for (int i = t; i < 64 * 32; i += 256) {
        int r = i >> 5, o = i & 31;
        const float* wr = W2 + (size_t)o * 64;
        float acc = b2[o];
        for (int k2 = 0; k2 < 64; ++k2) acc += z1[r][k2] * wr[k2];
        z2[r][o] = acc;
    }
    __syncthreads();
    if (t < 32) {
        float s1 = 0.f, s2 = 0.f;
        for (int r = 0; r < 64; ++r) { float v = z2[r][t]; s1 += v; s2 += v * v; }
        float mu = s1 * (1.f / 64.f), var = s2 * (1.f / 64.f) - mu * mu;
        float inv = rsqrtf(var + 1e-5f) * bn2s[t];
        float sh = bn2b[t];
        for (int r = 0; r < 64; ++r) {
            float v = (z2[r][t] - mu) * inv + sh;
            z2[r][t] = v > 0.f ? v : 0.f;
        }
    }
    __syncthreads();
    for (int i = t; i < 64 * 64; i += 256) {
        int r = i >> 6, o = i & 63;
        const float* wr = Wout + (size_t)o * 32;
        float acc = bout[o];
        for (int k2 = 0; k2 < 32; ++k2) acc += z2[r][k2] * wr[k2];
        out[r * 64 + o] = acc;
    }
}

extern "C" void kernel_launch(void* const* d_in, const int* in_sizes, int n_in,
                              void* d_out, int out_size, void* d_ws, size_t ws_size,
                              hipStream_t stream) {
    const float* x         = (const float*)d_in[0];
    const int*   ei        = (const int*)d_in[1];
    const float* edge_attr = (const float*)d_in[2];
    const int*   batch     = (const int*)d_in[3];
    const float* lin_qkv   = (const float*)d_in[4];
    const float* lin_edge  = (const float*)d_in[5];
    const float* att       = (const float*)d_in[6];
    // d_in[7] gat_bias: cancels exactly under training-mode BN (mean-subtracted)
    const float* bn_scale  = (const float*)d_in[8];
    const float* bn_bias   = (const float*)d_in[9];
    const float* W1   = (const float*)d_in[10];
    const float* b1   = (const float*)d_in[11];
    const float* bn1s = (const float*)d_in[12];
    const float* bn1b = (const float*)d_in[13];
    const float* W2   = (const float*)d_in[14];
    const float* b2   = (const float*)d_in[15];
    const float* bn2s = (const float*)d_in[16];
    const float* bn2b = (const float*)d_in[17];
    const float* Wout = (const float*)d_in[18];
    const float* bout = (const float*)d_in[19];

    float* ws = (float*)d_ws;
    size_t off = 0;
    auto alloc = [&](size_t n) { float* p = ws + off; off += n; return p; };
    // contiguous zero-region first: deg | gkey | gsums[3][256]
    int*      deg   = (int*)alloc(NN);
    unsigned* gkey  = (unsigned*)alloc(64 * 128);
    float*    gsums = alloc(3 * 256);
    const size_t zeroBytes = ((size_t)NN + 64 * 128 + 3 * 256) * 4;
    float*  hout = alloc((size_t)NN * 128);
    __half* qa   = (__half*)alloc((size_t)NN * 64);
    __half* kv   = (__half*)alloc((size_t)NN * 128);   // k|v interleaved, fp16
    unsigned short* Apack = (unsigned short*)alloc((size_t)MB * 16384);  // MB*32768 ushorts
    unsigned short* Wpack = (unsigned short*)alloc(9 * 16384);           // 9*32768 ushorts
    int*    offs   = (int*)alloc(NN);
    int*    cursor = (int*)alloc(NN);
    int*    csrc   = (int*)alloc(EE);
    __half* eatt   = (__half*)alloc((size_t)3 * EE * 4);  // [l][EE][8] fp16
    int*    psum   = (int*)alloc(256);
    int*    psx    = (int*)alloc(256);
    float*  M      = alloc(3 * 128);

    const int edgeBlocks = (EE + 255) / 256;     // 1563
    const int scanBlocks = (NN + 255) / 256;     // 196
    const int packBlocks = MB * 8;               // 3128
    const int statBlocks = (NN + 63) / 64;       // 782
    const int poolBlocks = (NN + 31) / 32;       // 1563
    const int gatBlocks  = (NN + 1) / 2;         // 25000

    hipMemsetAsync(deg, 0, zeroBytes, stream);
    wpack_kernel<<<144, 256, 0, stream>>>(lin_qkv, Wpack);
    compute_M_kernel<<<2, 256, 0, stream>>>(lin_edge, att, M);
    deg_count_kernel<<<edgeBlocks, 256, 0, stream>>>(ei, deg);
    scan_partial_kernel<<<scanBlocks, 256, 0, stream>>>(deg, psum);
    scan_top_kernel<<<1, 256, 0, stream>>>(psum, psx);
    scan_final_kernel<<<scanBlocks, 256, 0, stream>>>(deg, psx, offs, cursor);
    scatter_eatt_kernel<<<edgeBlocks, 256, 0, stream>>>(ei, edge_attr, M, cursor, csrc, eatt);
    pack_kernel<<<packBlocks, 256, 0, stream>>>(x, nullptr, nullptr, nullptr, 0, Apack);

    for (int l = 0; l < 3; ++l) {
        qkv_mfma_kernel<<<dim3(MB, 3), 256, 0, stream>>>(
            Apack, Wpack, l, att + (size_t)l * 384, qa, kv);

        fused_gat_kernel<<<gatBlocks, 128, 0, stream>>>(
            qa, kv, eatt + (size_t)l * EE * 8, offs, deg, csrc, hout);

        bn_stats_kernel<<<statBlocks, 256, 0, stream>>>(hout, gsums + l * 256);

        if (l < 2) {
            pack_kernel<<<packBlocks, 256, 0, stream>>>(
                hout, gsums + l * 256, bn_scale + l * 128, bn_bias + l * 128, 1, Apack);
        } else {
            bn_pool_kernel<<<poolBlocks, 256, 0, stream>>>(
                hout, gsums + l * 256, bn_scale + l * 128, bn_bias + l * 128, batch, gkey);
        }
    }

    head_kernel<<<1, 256, 0, stream>>>(gkey, W1, b1, bn1s, bn1b, W2, b2, bn2s, bn2b, Wout, bout, (float*)d_out);
}

// Round 8
// 430.435 us; speedup vs baseline: 21.7861x; 1.0929x over previous
//
#include <hip/hip_runtime.h>
#include <hip/hip_bf16.h>
#include <hip/hip_fp16.h>
#include <cstddef>
#include <cstdint>

#define NN 50000
#define EE 400000
#define GG 64
#define MB 391   // ceil(NN/128)

typedef __attribute__((ext_vector_type(8))) _Float16 f16x8;
typedef __attribute__((ext_vector_type(4))) float f32x4;

#define GLOAD_LDS16(g, l) __builtin_amdgcn_global_load_lds( \
    (const __attribute__((address_space(1))) void*)(g), \
    (__attribute__((address_space(3))) void*)(l), 16, 0, 0)

// ---------- helpers ----------
__device__ __forceinline__ unsigned f2key(float f) {
    unsigned u = __float_as_uint(f);
    return (u & 0x80000000u) ? ~u : (u | 0x80000000u);
}
__device__ __forceinline__ float key2f(unsigned k) {
    unsigned u = (k & 0x80000000u) ? (k ^ 0x80000000u) : ~k;
    return __uint_as_float(u);
}

// ---------- M[l][h][d] = sum_c lin_edge[l][h*16+c][d] * att[l][2][h][c] ----------
__global__ void compute_M_kernel(const float* __restrict__ lin_edge,
                                 const float* __restrict__ att,
                                 float* __restrict__ M) {
    int t = blockIdx.x * 256 + threadIdx.x;
    if (t >= 3 * 128) return;
    int l = t >> 7, r = t & 127, h = r >> 4, d = r & 15;
    const float* le = lin_edge + (size_t)l * 128 * 16;
    const float* av = att + ((l * 3 + 2) * 128) + h * 16;
    float acc = 0.f;
#pragma unroll
    for (int c = 0; c < 16; ++c) acc += le[(h * 16 + c) * 16 + d] * av[c];
    M[t] = acc;
}

// ---------- weight packing (fp16): Wpack[l*3+mat][kb 4][kg 4][n 128][8k] ----------
__global__ __launch_bounds__(256)
void wpack_kernel(const float* __restrict__ lin_qkv, __half* __restrict__ Wpack) {
    int g = blockIdx.x * 256 + threadIdx.x;   // [0, 9*2048)
    int lm = g >> 11;
    int r = g & 2047;
    int kb = r >> 9;
    int kg = (r >> 7) & 3;
    int n  = r & 127;
    int k0 = kb * 32 + kg * 8;
    const float* row = lin_qkv + ((size_t)lm * 128 + n) * 128 + k0;
    __half o[8] __attribute__((aligned(16)));
#pragma unroll
    for (int i = 0; i < 8; ++i) o[i] = __float2half(row[i]);
    *reinterpret_cast<uint4*>(Wpack + (size_t)g * 8) = *reinterpret_cast<const uint4*>(o);
}

// ---------- h packing (+optional BN+relu), fp16: Apack[mb][kb 4][kg 4][m 128][8k] ----------
__global__ __launch_bounds__(256)
void pack_kernel(const float* __restrict__ hin, const float* __restrict__ sums,
                 const float* __restrict__ scale, const float* __restrict__ shift,
                 int mode, __half* __restrict__ Apack) {
    int s = blockIdx.x * 256 + threadIdx.x;   // [0, MB*2048)
    int mb = s >> 11;
    int r  = s & 2047;
    int kb = r >> 9;
    int kg = (r >> 7) & 3;
    int m  = r & 127;
    int node = mb * 128 + m;
    int k0 = kb * 32 + kg * 8;
    size_t slot = ((size_t)(mb * 4 + kb) * 512 + (size_t)kg * 128 + m) * 8;
    __half o[8] __attribute__((aligned(16)));
    if (node < NN) {
        const float* row = hin + (size_t)node * 128 + k0;
#pragma unroll
        for (int i = 0; i < 8; ++i) {
            float v = row[i];
            if (mode) {
                int c = k0 + i;
                float mu = sums[c] * (1.f / NN);
                float var = sums[128 + c] * (1.f / NN) - mu * mu;
                v = (v - mu) * rsqrtf(var + 1e-5f) * scale[c] + shift[c];
                v = v > 0.f ? v : 0.f;
            }
            o[i] = __float2half(v);
        }
    } else {
#pragma unroll
        for (int i = 0; i < 8; ++i) o[i] = __float2half(0.f);
    }
    *reinterpret_cast<uint4*>(Apack + slot) = *reinterpret_cast<const uint4*>(o);
}

// ---------- QKV GEMM via fp16 MFMA (K=128, 4 chunks), fp16 output ----------
// q -> qa[n][128]; k -> kv[n][0:128]; v -> kv[n][128:256]
__global__ __launch_bounds__(256, 4)
void qkv_mfma_kernel(const __half* __restrict__ Apack,
                     const __half* __restrict__ Wpack,
                     int layer,
                     const float* __restrict__ att_l,
                     __half* __restrict__ qa, __half* __restrict__ kv) {
    __shared__ __half Ab[2][4096];
    __shared__ __half Bb[2][4096];
    const int t = threadIdx.x;
    const int lane = t & 63;
    const int wave = t >> 6;
    const int wr = wave >> 1, wc = wave & 1;
    const int mb = blockIdx.x, mat = blockIdx.y;

    const __half* Abase = Apack + (size_t)mb * 16384;
    const __half* Bbase = Wpack + (size_t)(layer * 3 + mat) * 16384;

    f32x4 acc[4][4];
#pragma unroll
    for (int i = 0; i < 4; ++i)
#pragma unroll
        for (int j = 0; j < 4; ++j) acc[i][j] = (f32x4){0.f, 0.f, 0.f, 0.f};

    auto stage = [&](int c, int buf) {
        const __half* ga = Abase + (size_t)c * 4096;
        const __half* gb = Bbase + (size_t)c * 4096;
        GLOAD_LDS16(ga + (size_t)(wave * 64 + lane) * 8,        &Ab[buf][(wave * 64) * 8]);
        GLOAD_LDS16(ga + (size_t)(256 + wave * 64 + lane) * 8,  &Ab[buf][(256 + wave * 64) * 8]);
        GLOAD_LDS16(gb + (size_t)(wave * 64 + lane) * 8,        &Bb[buf][(wave * 64) * 8]);
        GLOAD_LDS16(gb + (size_t)(256 + wave * 64 + lane) * 8,  &Bb[buf][(256 + wave * 64) * 8]);
    };

    stage(0, 0);
    __syncthreads();
    const int abase = ((lane >> 4) * 128 + wr * 64 + (lane & 15)) * 8;
    const int bbase = ((lane >> 4) * 128 + wc * 64 + (lane & 15)) * 8;
#pragma unroll
    for (int c = 0; c < 4; ++c) {
        int cur = c & 1;
        if (c < 3) stage(c + 1, cur ^ 1);
        f16x8 aF[4], bF[4];
#pragma unroll
        for (int mf = 0; mf < 4; ++mf)
            aF[mf] = *reinterpret_cast<const f16x8*>(&Ab[cur][abase + mf * 128]);
#pragma unroll
        for (int nf = 0; nf < 4; ++nf)
            bF[nf] = *reinterpret_cast<const f16x8*>(&Bb[cur][bbase + nf * 128]);
#pragma unroll
        for (int mf = 0; mf < 4; ++mf)
#pragma unroll
            for (int nf = 0; nf < 4; ++nf)
                acc[mf][nf] = __builtin_amdgcn_mfma_f32_16x16x32_f16(aF[mf], bF[nf], acc[mf][nf], 0, 0, 0);
        __syncthreads();
    }

    __half* outb = (mat == 0) ? qa : kv;
    const size_t stride = (mat == 0) ? 128 : 256;
    const int coloff = (mat == 2) ? 128 : 0;
    float sc[4];
#pragma unroll
    for (int nf = 0; nf < 4; ++nf) {
        int col = wc * 64 + nf * 16 + (lane & 15);
        sc[nf] = (mat == 2) ? 1.f : att_l[mat * 128 + col];
    }
    const int rowq = (lane >> 4) * 4;
#pragma unroll
    for (int mf = 0; mf < 4; ++mf) {
        int row0 = mb * 128 + wr * 64 + mf * 16 + rowq;
#pragma unroll
        for (int reg = 0; reg < 4; ++reg) {
            int row = row0 + reg;
            if (row < NN) {
#pragma unroll
                for (int nf = 0; nf < 4; ++nf) {
                    int col = wc * 64 + nf * 16 + (lane & 15);
                    outb[(size_t)row * stride + coloff + col] = __float2half(acc[mf][nf][reg] * sc[nf]);
                }
            }
        }
    }
}

// ---------- CSR build ----------
__global__ __launch_bounds__(256)
void deg_count_kernel(const int* __restrict__ ei, int* __restrict__ deg) {
    int e = blockIdx.x * 256 + threadIdx.x;
    if (e < EE) atomicAdd(&deg[ei[EE + e]], 1);
}

__global__ __launch_bounds__(256)
void scan_partial_kernel(const int* __restrict__ deg, int* __restrict__ psum) {
    __shared__ int red[256];
    int i = blockIdx.x * 256 + threadIdx.x;
    red[threadIdx.x] = (i < NN) ? deg[i] : 0;
    __syncthreads();
    for (int o = 128; o > 0; o >>= 1) {
        if (threadIdx.x < o) red[threadIdx.x] += red[threadIdx.x + o];
        __syncthreads();
    }
    if (threadIdx.x == 0) psum[blockIdx.x] = red[0];
}

__global__ __launch_bounds__(256)
void scan_top_kernel(const int* __restrict__ psum, int* __restrict__ psx) {
    __shared__ int sh[256];
    int t = threadIdx.x;
    int v = (t < 196) ? psum[t] : 0;
    sh[t] = v;
    __syncthreads();
    for (int o = 1; o < 256; o <<= 1) {
        int add = (t >= o) ? sh[t - o] : 0;
        __syncthreads();
        sh[t] += add;
        __syncthreads();
    }
    if (t < 196) psx[t] = sh[t] - v;
}

__global__ __launch_bounds__(256)
void scan_final_kernel(const int* __restrict__ deg, const int* __restrict__ psx,
                       int* __restrict__ offs, int* __restrict__ cursor) {
    __shared__ int sh[256];
    int t = threadIdx.x;
    int i = blockIdx.x * 256 + t;
    int v = (i < NN) ? deg[i] : 0;
    sh[t] = v;
    __syncthreads();
    for (int o = 1; o < 256; o <<= 1) {
        int add = (t >= o) ? sh[t - o] : 0;
        __syncthreads();
        sh[t] += add;
        __syncthreads();
    }
    if (i < NN) {
        int excl = sh[t] - v + psx[blockIdx.x];
        offs[i] = excl;
        cursor[i] = excl;
    }
}

// ---------- scatter + eatt fused: csrc[pos]=src; eatt[l][pos][8h] = ea.M (fp16) ----------
__global__ __launch_bounds__(256)
void scatter_eatt_kernel(const int* __restrict__ ei, const float* __restrict__ edge_attr,
                         const float* __restrict__ M, int* __restrict__ cursor,
                         int* __restrict__ csrc, __half* __restrict__ eatt) {
    __shared__ float Ms[384];
    for (int i = threadIdx.x; i < 384; i += 256) Ms[i] = M[i];
    __syncthreads();
    int e = blockIdx.x * 256 + threadIdx.x;
    if (e >= EE) return;
    const float4* ep = reinterpret_cast<const float4*>(edge_attr + (size_t)e * 16);
    float4 a0 = ep[0], a1 = ep[1], a2 = ep[2], a3 = ep[3];
    float ea[16] = {a0.x, a0.y, a0.z, a0.w, a1.x, a1.y, a1.z, a1.w,
                    a2.x, a2.y, a2.z, a2.w, a3.x, a3.y, a3.z, a3.w};
    int src = ei[e], dst = ei[EE + e];
    int pos = atomicAdd(&cursor[dst], 1);
    csrc[pos] = src;
#pragma unroll
    for (int l = 0; l < 3; ++l) {
        __half o[8] __attribute__((aligned(16)));
#pragma unroll
        for (int h = 0; h < 8; ++h) {
            const float* mp = Ms + l * 128 + h * 16;
            float acc = 0.f;
#pragma unroll
            for (int d = 0; d < 16; ++d) acc += ea[d] * mp[d];
            o[h] = __float2half(acc);
        }
        *reinterpret_cast<uint4*>(eatt + ((size_t)l * EE + pos) * 8) =
            *reinterpret_cast<const uint4*>(o);
    }
}

// ---------- fused attention: 2 waves/block, one dst per wave ----------
__global__ __launch_bounds__(128)
void fused_gat_kernel(const __half* __restrict__ qa, const __half* __restrict__ kv,
                      const __half* __restrict__ eatt_l,
                      const int* __restrict__ offs, const int* __restrict__ deg,
                      const int* __restrict__ csrc, float* __restrict__ hout) {
    int lane = threadIdx.x & 63;
    int n = blockIdx.x * 2 + (threadIdx.x >> 6);
    if (n >= NN) return;
    int h = lane >> 3;
    int c2h = lane & 7;          // half2 index within head
    int chh = h * 8 + c2h;       // half2 index within 128-ch row
    int ch = chh * 2;

    float2 q = __half22float2(*reinterpret_cast<const __half2*>(qa + (size_t)n * 128 + ch));

    int start = offs[n], d = deg[n];
    const __half* ebase = eatt_l + (size_t)start * 8 + h;
    const int* sbase = csrc + start;

    float m = -INFINITY, den = 0.f, acc0 = 0.f, acc1 = 0.f;
    int i = 0;
    for (; i + 4 <= d; i += 4) {
        int s0 = sbase[i], s1 = sbase[i + 1], s2 = sbase[i + 2], s3 = sbase[i + 3];
        float e0 = __half2float(ebase[(size_t)i * 8]);
        float e1 = __half2float(ebase[(size_t)(i + 1) * 8]);
        float e2 = __half2float(ebase[(size_t)(i + 2) * 8]);
        float e3 = __half2float(ebase[(size_t)(i + 3) * 8]);
        const __half2* p0h = reinterpret_cast<const __half2*>(kv + (size_t)s0 * 256);
        const __half2* p1h = reinterpret_cast<const __half2*>(kv + (size_t)s1 * 256);
        const __half2* p2h = reinterpret_cast<const __half2*>(kv + (size_t)s2 * 256);
        const __half2* p3h = reinterpret_cast<const __half2*>(kv + (size_t)s3 * 256);
        float2 k0 = __half22float2(p0h[chh]);
        float2 k1 = __half22float2(p1h[chh]);
        float2 k2 = __half22float2(p2h[chh]);
        float2 k3 = __half22float2(p3h[chh]);
        float2 v0 = __half22float2(p0h[64 + chh]);
        float2 v1 = __half22float2(p1h[64 + chh]);
        float2 v2 = __half22float2(p2h[64 + chh]);
        float2 v3 = __half22float2(p3h[64 + chh]);
        float p0 = q.x * k0.x + q.y * k0.y;
        float p1 = q.x * k1.x + q.y * k1.y;
        float p2 = q.x * k2.x + q.y * k2.y;
        float p3 = q.x * k3.x + q.y * k3.y;
        p0 += __shfl_xor(p0, 1); p0 += __shfl_xor(p0, 2); p0 += __shfl_xor(p0, 4);
        p1 += __shfl_xor(p1, 1); p1 += __shfl_xor(p1, 2); p1 += __shfl_xor(p1, 4);
        p2 += __shfl_xor(p2, 1); p2 += __shfl_xor(p2, 2); p2 += __shfl_xor(p2, 4);
        p3 += __shfl_xor(p3, 1); p3 += __shfl_xor(p3, 2); p3 += __shfl_xor(p3, 4);
        float a0 = p0 + e0; a0 = a0 > 0.f ? a0 : 0.2f * a0;
        float a1 = p1 + e1; a1 = a1 > 0.f ? a1 : 0.2f * a1;
        float a2 = p2 + e2; a2 = a2 > 0.f ? a2 : 0.2f * a2;
        float a3 = p3 + e3; a3 = a3 > 0.f ? a3 : 0.2f * a3;
        float mn, scl, p;
        mn = fmaxf(m, a0); scl = __expf(m - mn); p = __expf(a0 - mn);
        den = den * scl + p; acc0 = acc0 * scl + p * v0.x; acc1 = acc1 * scl + p * v0.y; m = mn;
        mn = fmaxf(m, a1); scl = __expf(m - mn); p = __expf(a1 - mn);
        den = den * scl + p; acc0 = acc0 * scl + p * v1.x; acc1 = acc1 * scl + p * v1.y; m = mn;
        mn = fmaxf(m, a2); scl = __expf(m - mn); p = __expf(a2 - mn);
        den = den * scl + p; acc0 = acc0 * scl + p * v2.x; acc1 = acc1 * scl + p * v2.y; m = mn;
        mn = fmaxf(m, a3); scl = __expf(m - mn); p = __expf(a3 - mn);
        den = den * scl + p; acc0 = acc0 * scl + p * v3.x; acc1 = acc1 * scl + p * v3.y; m = mn;
    }
    for (; i < d; ++i) {
        int s0 = sbase[i];
        float e0 = __half2float(ebase[(size_t)i * 8]);
        const __half2* p0h = reinterpret_cast<const __half2*>(kv + (size_t)s0 * 256);
        float2 k0 = __half22float2(p0h[chh]);
        float2 v0 = __half22float2(p0h[64 + chh]);
        float p0 = q.x * k0.x + q.y * k0.y;
        p0 += __shfl_xor(p0, 1); p0 += __shfl_xor(p0, 2); p0 += __shfl_xor(p0, 4);
        float a0 = p0 + e0; a0 = a0 > 0.f ? a0 : 0.2f * a0;
        float mn = fmaxf(m, a0);
        float scl = __expf(m - mn);
        float p = __expf(a0 - mn);
        den = den * scl + p; acc0 = acc0 * scl + p * v0.x; acc1 = acc1 * scl + p * v0.y; m = mn;
    }
    float inv = 1.f / (den + 1e-16f);
    *reinterpret_cast<float2*>(hout + (size_t)n * 128 + ch) = make_float2(acc0 * inv, acc1 * inv);
}

// ---------- BN stats (sum, sumsq per channel), float4-vectorized ----------
__global__ __launch_bounds__(256)
void bn_stats_kernel(const float* __restrict__ h, float* __restrict__ sums) {
    __shared__ float red[2][8][128];
    int t = threadIdx.x;
    int cg = t & 31;          // channel quad
    int rofs = t >> 5;        // 0..7
    int r0 = blockIdx.x * 64;
    int rend = min(NN, r0 + 64);
    float4 s1 = make_float4(0.f, 0.f, 0.f, 0.f);
    float4 s2 = make_float4(0.f, 0.f, 0.f, 0.f);
    for (int r = r0 + rofs; r < rend; r += 8) {
        float4 v = *reinterpret_cast<const float4*>(h + (size_t)r * 128 + cg * 4);
        s1.x += v.x; s1.y += v.y; s1.z += v.z; s1.w += v.w;
        s2.x += v.x * v.x; s2.y += v.y * v.y; s2.z += v.z * v.z; s2.w += v.w * v.w;
    }
    *reinterpret_cast<float4*>(&red[0][rofs][cg * 4]) = s1;
    *reinterpret_cast<float4*>(&red[1][rofs][cg * 4]) = s2;
    __syncthreads();
    if (t < 128) {
        float a = 0.f, b = 0.f;
#pragma unroll
        for (int i = 0; i < 8; ++i) { a += red[0][i][t]; b += red[1][i][t]; }
        unsafeAtomicAdd(&sums[t], a);
        unsafeAtomicAdd(&sums[128 + t], b);
    }
}

// ---------- last layer: BN apply + segmented global max pool (batch sorted) ----------
__global__ __launch_bounds__(256)
void bn_pool_kernel(const float* __restrict__ h, const float* __restrict__ sums,
                    const float* __restrict__ scale, const float* __restrict__ shift,
                    const int* __restrict__ batch, unsigned* __restrict__ gkey) {
    int t = threadIdx.x;
    int c = t & 127, half = t >> 7;
    int r0 = blockIdx.x * 32;
    int rend = min(NN, r0 + 32);
    const float invN = 1.f / (float)NN;
    float mu = sums[c] * invN;
    float var = sums[128 + c] * invN - mu * mu;
    float iscl = rsqrtf(var + 1e-5f) * scale[c];
    float sh = shift[c];
    int curg = -1;
    float lmax = -INFINITY;
    for (int r = r0 + half; r < rend; r += 2) {
        int g = batch[r];
        if (g != curg) {
            if (curg >= 0) atomicMax(&gkey[curg * 128 + c], f2key(lmax));
            curg = g;
            lmax = -INFINITY;
        }
        float v = (h[(size_t)r * 128 + c] - mu) * iscl + sh;
        lmax = fmaxf(lmax, v);
    }
    if (curg >= 0) atomicMax(&gkey[curg * 128 + c], f2key(lmax));
}

// ---------- head MLP (single block) ----------
__global__ __launch_bounds__(256)
void head_kernel(const unsigned* __restrict__ gkey,
                 const float* __restrict__ W1, const float* __restrict__ b1,
                 const float* __restrict__ bn1s, const float* __restrict__ bn1b,
                 const float* __restrict__ W2, const float* __restrict__ b2,
                 const float* __restrict__ bn2s, const float* __restrict__ bn2b,
                 const float* __restrict__ Wout, const float* __restrict__ bout,
                 float* __restrict__ out) {
    __shared__ float g[64][128];
    __shared__ float z1[64][64];
    __shared__ float z2[64][32];
    int t = threadIdx.x;
    for (int i = t; i < 64 * 128; i += 256) g[i >> 7][i & 127] = key2f(gkey[i]);
    __syncthreads();
    for (int i = t; i < 64 * 64; i += 256) {
        int r = i >> 6, o = i & 63;
        const float* gr = g[r];
        const float* wr = W1 + (size_t)o * 128;
        float acc = b1[o];
        for (int k2 = 0; k2 < 128; ++k2) acc += gr[k2] * wr[k2];
        z1[r][o] = acc;
    }
    __syncthreads();
    if (t < 64) {
        float s1 = 0.f, s2 = 0.f;
        for (int r = 0; r < 64; ++r) { float v = z1[r][t]; s1 += v; s2 += v * v; }
        float mu = s1 * (1.f / 64.f), var = s2 * (1.f / 64.f) - mu * mu;
        float inv = rsqrtf(var + 1e-5f) * bn1s[t];
        float sh = bn1b[t];
        for (int r = 0; r < 64; ++r) {
            float v = (z1[r][t] - mu) * inv + sh;
            z1[r][t] = v > 0.f ? v : 0.f;
        }
    }
    __syncthreads();
    for (int i = t; i < 64 * 32; i += 256) {
        int r = i >> 5, o = i & 31;
        const float* wr = W2 + (size_t)o * 64;
        float acc = b2[o];
        for (int k2 = 0; k2 < 64; ++k2) acc += z1[r][k2] * wr[k2];
        z2[r][o] = acc;
    }
    __syncthreads();
    if (t < 32) {
        float s1 = 0.f, s2 = 0.f;
        for (int r = 0; r < 64; ++r) { float v = z2[r][t]; s1 += v; s2 += v * v; }
        float mu = s1 * (1.f / 64.f), var = s2 * (1.f / 64.f) - mu * mu;
        float inv = rsqrtf(var + 1e-5f) * bn2s[t];
        float sh = bn2b[t];
        for (int r = 0; r < 64; ++r) {
            float v = (z2[r][t] - mu) * inv + sh;
            z2[r][t] = v > 0.f ? v : 0.f;
        }
    }
    __syncthreads();
    for (int i = t; i < 64 * 64; i += 256) {
        int r = i >> 6, o = i & 63;
        const float* wr = Wout + (size_t)o * 32;
        float acc = bout[o];
        for (int k2 = 0; k2 < 32; ++k2) acc += z2[r][k2] * wr[k2];
        out[r * 64 + o] = acc;
    }
}

extern "C" void kernel_launch(void* const* d_in, const int* in_sizes, int n_in,
                              void* d_out, int out_size, void* d_ws, size_t ws_size,
                              hipStream_t stream) {
    const float* x         = (const float*)d_in[0];
    const int*   ei        = (const int*)d_in[1];
    const float* edge_attr = (const float*)d_in[2];
    const int*   batch     = (const int*)d_in[3];
    const float* lin_qkv   = (const float*)d_in[4];
    const float* lin_edge  = (const float*)d_in[5];
    const float* att       = (const float*)d_in[6];
    // d_in[7] gat_bias: cancels exactly under training-mode BN (mean-subtracted)
    const float* bn_scale  = (const float*)d_in[8];
    const float* bn_bias   = (const float*)d_in[9];
    const float* W1   = (const float*)d_in[10];
    const float* b1   = (const float*)d_in[11];
    const float* bn1s = (const float*)d_in[12];
    const float* bn1b = (const float*)d_in[13];
    const float* W2   = (const float*)d_in[14];
    const float* b2   = (const float*)d_in[15];
    const float* bn2s = (const float*)d_in[16];
    const float* bn2b = (const float*)d_in[17];
    const float* Wout = (const float*)d_in[18];
    const float* bout = (const float*)d_in[19];

    float* ws = (float*)d_ws;
    size_t off = 0;
    auto alloc = [&](size_t n) { float* p = ws + off; off += n; return p; };
    // contiguous zero-region first: deg | gkey | gsums[3][256]
    int*      deg   = (int*)alloc(NN);
    unsigned* gkey  = (unsigned*)alloc(64 * 128);
    float*    gsums = alloc(3 * 256);
    const size_t zeroBytes = ((size_t)NN + 64 * 128 + 3 * 256) * 4;
    float*  hout = alloc((size_t)NN * 128);
    __half* qa   = (__half*)alloc((size_t)NN * 64);
    __half* kv   = (__half*)alloc((size_t)NN * 128);   // k|v interleaved, fp16
    __half* Apack = (__half*)alloc((size_t)MB * 8192);  // MB*16384 halves
    __half* Wpack = (__half*)alloc(9 * 8192);           // 9*16384 halves
    int*    offs   = (int*)alloc(NN);
    int*    cursor = (int*)alloc(NN);
    int*    csrc   = (int*)alloc(EE);
    __half* eatt   = (__half*)alloc((size_t)3 * EE * 4);  // [l][EE][8] fp16
    int*    psum   = (int*)alloc(256);
    int*    psx    = (int*)alloc(256);
    float*  M      = alloc(3 * 128);

    const int edgeBlocks = (EE + 255) / 256;     // 1563
    const int scanBlocks = (NN + 255) / 256;     // 196
    const int packBlocks = MB * 8;               // 3128
    const int statBlocks = (NN + 63) / 64;       // 782
    const int poolBlocks = (NN + 31) / 32;       // 1563
    const int gatBlocks  = (NN + 1) / 2;         // 25000

    hipMemsetAsync(deg, 0, zeroBytes, stream);
    wpack_kernel<<<72, 256, 0, stream>>>(lin_qkv, Wpack);
    compute_M_kernel<<<2, 256, 0, stream>>>(lin_edge, att, M);
    deg_count_kernel<<<edgeBlocks, 256, 0, stream>>>(ei, deg);
    scan_partial_kernel<<<scanBlocks, 256, 0, stream>>>(deg, psum);
    scan_top_kernel<<<1, 256, 0, stream>>>(psum, psx);
    scan_final_kernel<<<scanBlocks, 256, 0, stream>>>(deg, psx, offs, cursor);
    scatter_eatt_kernel<<<edgeBlocks, 256, 0, stream>>>(ei, edge_attr, M, cursor, csrc, eatt);
    pack_kernel<<<packBlocks, 256, 0, stream>>>(x, nullptr, nullptr, nullptr, 0, Apack);

    for (int l = 0; l < 3; ++l) {
        qkv_mfma_kernel<<<dim3(MB, 3), 256, 0, stream>>>(
            Apack, Wpack, l, att + (size_t)l * 384, qa, kv);

        fused_gat_kernel<<<gatBlocks, 128, 0, stream>>>(
            qa, kv, eatt + (size_t)l * EE * 8, offs, deg, csrc, hout);

        bn_stats_kernel<<<statBlocks, 256, 0, stream>>>(hout, gsums + l * 256);

        if (l < 2) {
            pack_kernel<<<packBlocks, 256, 0, stream>>>(
                hout, gsums + l * 256, bn_scale + l * 128, bn_bias + l * 128, 1, Apack);
        } else {
            bn_pool_kernel<<<poolBlocks, 256, 0, stream>>>(
                hout, gsums + l * 256, bn_scale + l * 128, bn_bias + l * 128, batch, gkey);
        }
    }

    head_kernel<<<1, 256, 0, stream>>>(gkey, W1, b1, bn1s, bn1b, W2, b2, bn2s, bn2b, Wout, bout, (float*)d_out);
}

// Round 9
// 385.982 us; speedup vs baseline: 24.2952x; 1.1152x over previous
//
#include <hip/hip_runtime.h>
#include <hip/hip_bf16.h>
#include <hip/hip_fp16.h>
#include <cstddef>
#include <cstdint>

#define NN 50000
#define EE 400000
#define GG 64
#define MB 391   // ceil(NN/128)

typedef __attribute__((ext_vector_type(8))) _Float16 f16x8;
typedef __attribute__((ext_vector_type(4))) float f32x4;

#define GLOAD_LDS16(g, l) __builtin_amdgcn_global_load_lds( \
    (const __attribute__((address_space(1))) void*)(g), \
    (__attribute__((address_space(3))) void*)(l), 16, 0, 0)

// ---------- helpers ----------
__device__ __forceinline__ unsigned f2key(float f) {
    unsigned u = __float_as_uint(f);
    return (u & 0x80000000u) ? ~u : (u | 0x80000000u);
}
__device__ __forceinline__ float key2f(unsigned k) {
    unsigned u = (k & 0x80000000u) ? (k ^ 0x80000000u) : ~k;
    return __uint_as_float(u);
}

// ---------- M[l][h][d] = sum_c lin_edge[l][h*16+c][d] * att[l][2][h][c] ----------
__global__ void compute_M_kernel(const float* __restrict__ lin_edge,
                                 const float* __restrict__ att,
                                 float* __restrict__ M) {
    int t = blockIdx.x * 256 + threadIdx.x;
    if (t >= 3 * 128) return;
    int l = t >> 7, r = t & 127, h = r >> 4, d = r & 15;
    const float* le = lin_edge + (size_t)l * 128 * 16;
    const float* av = att + ((l * 3 + 2) * 128) + h * 16;
    float acc = 0.f;
#pragma unroll
    for (int c = 0; c < 16; ++c) acc += le[(h * 16 + c) * 16 + d] * av[c];
    M[t] = acc;
}

// ---------- weight packing (fp16): Wpack[l*3+mat][kb 4][kg 4][n 128][8k] ----------
__global__ __launch_bounds__(256)
void wpack_kernel(const float* __restrict__ lin_qkv, __half* __restrict__ Wpack) {
    int g = blockIdx.x * 256 + threadIdx.x;   // [0, 9*2048)
    int lm = g >> 11;
    int r = g & 2047;
    int kb = r >> 9;
    int kg = (r >> 7) & 3;
    int n  = r & 127;
    int k0 = kb * 32 + kg * 8;
    const float* row = lin_qkv + ((size_t)lm * 128 + n) * 128 + k0;
    __half o[8] __attribute__((aligned(16)));
#pragma unroll
    for (int i = 0; i < 8; ++i) o[i] = __float2half(row[i]);
    *reinterpret_cast<uint4*>(Wpack + (size_t)g * 8) = *reinterpret_cast<const uint4*>(o);
}

// ---------- x packing (fp32 in, no BN): Apack[mb][kb 4][kg 4][m 128][8k] ----------
__global__ __launch_bounds__(256)
void pack_x_kernel(const float* __restrict__ hin, __half* __restrict__ Apack) {
    int s = blockIdx.x * 256 + threadIdx.x;   // [0, MB*2048)
    int mb = s >> 11;
    int r  = s & 2047;
    int kb = r >> 9;
    int kg = (r >> 7) & 3;
    int m  = r & 127;
    int node = mb * 128 + m;
    int k0 = kb * 32 + kg * 8;
    size_t slot = ((size_t)(mb * 4 + kb) * 512 + (size_t)kg * 128 + m) * 8;
    __half o[8] __attribute__((aligned(16)));
    if (node < NN) {
        const float* row = hin + (size_t)node * 128 + k0;
#pragma unroll
        for (int i = 0; i < 8; ++i) o[i] = __float2half(row[i]);
    } else {
#pragma unroll
        for (int i = 0; i < 8; ++i) o[i] = __float2half(0.f);
    }
    *reinterpret_cast<uint4*>(Apack + slot) = *reinterpret_cast<const uint4*>(o);
}

// ---------- h packing (fp16 in, BN+relu): Apack[mb][kb 4][kg 4][m 128][8k] ----------
__global__ __launch_bounds__(256)
void pack_h_kernel(const __half* __restrict__ hin, const float* __restrict__ sums,
                   const float* __restrict__ scale, const float* __restrict__ shift,
                   __half* __restrict__ Apack) {
    int s = blockIdx.x * 256 + threadIdx.x;   // [0, MB*2048)
    int mb = s >> 11;
    int r  = s & 2047;
    int kb = r >> 9;
    int kg = (r >> 7) & 3;
    int m  = r & 127;
    int node = mb * 128 + m;
    int k0 = kb * 32 + kg * 8;
    size_t slot = ((size_t)(mb * 4 + kb) * 512 + (size_t)kg * 128 + m) * 8;
    __half o[8] __attribute__((aligned(16)));
    if (node < NN) {
        const __half* row = hin + (size_t)node * 128 + k0;
        uint4 raw = *reinterpret_cast<const uint4*>(row);
        const __half* rh = reinterpret_cast<const __half*>(&raw);
#pragma unroll
        for (int i = 0; i < 8; ++i) {
            int c = k0 + i;
            float mu = sums[c] * (1.f / NN);
            float var = sums[128 + c] * (1.f / NN) - mu * mu;
            float v = (__half2float(rh[i]) - mu) * rsqrtf(var + 1e-5f) * scale[c] + shift[c];
            v = v > 0.f ? v : 0.f;
            o[i] = __float2half(v);
        }
    } else {
#pragma unroll
        for (int i = 0; i < 8; ++i) o[i] = __float2half(0.f);
    }
    *reinterpret_cast<uint4*>(Apack + slot) = *reinterpret_cast<const uint4*>(o);
}

// ---------- QKV GEMM via fp16 MFMA (K=128, 4 chunks), fp16 output ----------
// q -> qa[n][128]; k -> kv[n][0:128]; v -> kv[n][128:256]
__global__ __launch_bounds__(256, 4)
void qkv_mfma_kernel(const __half* __restrict__ Apack,
                     const __half* __restrict__ Wpack,
                     int layer,
                     const float* __restrict__ att_l,
                     __half* __restrict__ qa, __half* __restrict__ kv) {
    __shared__ __half Ab[2][4096];
    __shared__ __half Bb[2][4096];
    const int t = threadIdx.x;
    const int lane = t & 63;
    const int wave = t >> 6;
    const int wr = wave >> 1, wc = wave & 1;
    const int mb = blockIdx.x, mat = blockIdx.y;

    const __half* Abase = Apack + (size_t)mb * 16384;
    const __half* Bbase = Wpack + (size_t)(layer * 3 + mat) * 16384;

    f32x4 acc[4][4];
#pragma unroll
    for (int i = 0; i < 4; ++i)
#pragma unroll
        for (int j = 0; j < 4; ++j) acc[i][j] = (f32x4){0.f, 0.f, 0.f, 0.f};

    auto stage = [&](int c, int buf) {
        const __half* ga = Abase + (size_t)c * 4096;
        const __half* gb = Bbase + (size_t)c * 4096;
        GLOAD_LDS16(ga + (size_t)(wave * 64 + lane) * 8,        &Ab[buf][(wave * 64) * 8]);
        GLOAD_LDS16(ga + (size_t)(256 + wave * 64 + lane) * 8,  &Ab[buf][(256 + wave * 64) * 8]);
        GLOAD_LDS16(gb + (size_t)(wave * 64 + lane) * 8,        &Bb[buf][(wave * 64) * 8]);
        GLOAD_LDS16(gb + (size_t)(256 + wave * 64 + lane) * 8,  &Bb[buf][(256 + wave * 64) * 8]);
    };

    stage(0, 0);
    __syncthreads();
    const int abase = ((lane >> 4) * 128 + wr * 64 + (lane & 15)) * 8;
    const int bbase = ((lane >> 4) * 128 + wc * 64 + (lane & 15)) * 8;
#pragma unroll
    for (int c = 0; c < 4; ++c) {
        int cur = c & 1;
        if (c < 3) stage(c + 1, cur ^ 1);
        f16x8 aF[4], bF[4];
#pragma unroll
        for (int mf = 0; mf < 4; ++mf)
            aF[mf] = *reinterpret_cast<const f16x8*>(&Ab[cur][abase + mf * 128]);
#pragma unroll
        for (int nf = 0; nf < 4; ++nf)
            bF[nf] = *reinterpret_cast<const f16x8*>(&Bb[cur][bbase + nf * 128]);
#pragma unroll
        for (int mf = 0; mf < 4; ++mf)
#pragma unroll
            for (int nf = 0; nf < 4; ++nf)
                acc[mf][nf] = __builtin_amdgcn_mfma_f32_16x16x32_f16(aF[mf], bF[nf], acc[mf][nf], 0, 0, 0);
        __syncthreads();
    }

    __half* outb = (mat == 0) ? qa : kv;
    const size_t stride = (mat == 0) ? 128 : 256;
    const int coloff = (mat == 2) ? 128 : 0;
    float sc[4];
#pragma unroll
    for (int nf = 0; nf < 4; ++nf) {
        int col = wc * 64 + nf * 16 + (lane & 15);
        sc[nf] = (mat == 2) ? 1.f : att_l[mat * 128 + col];
    }
    const int rowq = (lane >> 4) * 4;
#pragma unroll
    for (int mf = 0; mf < 4; ++mf) {
        int row0 = mb * 128 + wr * 64 + mf * 16 + rowq;
#pragma unroll
        for (int reg = 0; reg < 4; ++reg) {
            int row = row0 + reg;
            if (row < NN) {
#pragma unroll
                for (int nf = 0; nf < 4; ++nf) {
                    int col = wc * 64 + nf * 16 + (lane & 15);
                    outb[(size_t)row * stride + coloff + col] = __float2half(acc[mf][nf][reg] * sc[nf]);
                }
            }
        }
    }
}

// ---------- CSR build ----------
__global__ __launch_bounds__(256)
void deg_count_kernel(const int* __restrict__ ei, int* __restrict__ deg) {
    int e = blockIdx.x * 256 + threadIdx.x;
    if (e < EE) atomicAdd(&deg[ei[EE + e]], 1);
}

__global__ __launch_bounds__(256)
void scan_partial_kernel(const int* __restrict__ deg, int* __restrict__ psum) {
    __shared__ int red[256];
    int i = blockIdx.x * 256 + threadIdx.x;
    red[threadIdx.x] = (i < NN) ? deg[i] : 0;
    __syncthreads();
    for (int o = 128; o > 0; o >>= 1) {
        if (threadIdx.x < o) red[threadIdx.x] += red[threadIdx.x + o];
        __syncthreads();
    }
    if (threadIdx.x == 0) psum[blockIdx.x] = red[0];
}

__global__ __launch_bounds__(256)
void scan_top_kernel(const int* __restrict__ psum, int* __restrict__ psx) {
    __shared__ int sh[256];
    int t = threadIdx.x;
    int v = (t < 196) ? psum[t] : 0;
    sh[t] = v;
    __syncthreads();
    for (int o = 1; o < 256; o <<= 1) {
        int add = (t >= o) ? sh[t - o] : 0;
        __syncthreads();
        sh[t] += add;
        __syncthreads();
    }
    if (t < 196) psx[t] = sh[t] - v;
}

__global__ __launch_bounds__(256)
void scan_final_kernel(const int* __restrict__ deg, const int* __restrict__ psx,
                       int* __restrict__ offs, int* __restrict__ cursor) {
    __shared__ int sh[256];
    int t = threadIdx.x;
    int i = blockIdx.x * 256 + t;
    int v = (i < NN) ? deg[i] : 0;
    sh[t] = v;
    __syncthreads();
    for (int o = 1; o < 256; o <<= 1) {
        int add = (t >= o) ? sh[t - o] : 0;
        __syncthreads();
        sh[t] += add;
        __syncthreads();
    }
    if (i < NN) {
        int excl = sh[t] - v + psx[blockIdx.x];
        offs[i] = excl;
        cursor[i] = excl;
    }
}

// ---------- scatter + eatt fused: csrc[pos]=src; eatt[l][pos][8h] = ea.M (fp16) ----------
__global__ __launch_bounds__(256)
void scatter_eatt_kernel(const int* __restrict__ ei, const float* __restrict__ edge_attr,
                         const float* __restrict__ M, int* __restrict__ cursor,
                         int* __restrict__ csrc, __half* __restrict__ eatt) {
    __shared__ float Ms[384];
    for (int i = threadIdx.x; i < 384; i += 256) Ms[i] = M[i];
    __syncthreads();
    int e = blockIdx.x * 256 + threadIdx.x;
    if (e >= EE) return;
    const float4* ep = reinterpret_cast<const float4*>(edge_attr + (size_t)e * 16);
    float4 a0 = ep[0], a1 = ep[1], a2 = ep[2], a3 = ep[3];
    float ea[16] = {a0.x, a0.y, a0.z, a0.w, a1.x, a1.y, a1.z, a1.w,
                    a2.x, a2.y, a2.z, a2.w, a3.x, a3.y, a3.z, a3.w};
    int src = ei[e], dst = ei[EE + e];
    int pos = atomicAdd(&cursor[dst], 1);
    csrc[pos] = src;
#pragma unroll
    for (int l = 0; l < 3; ++l) {
        __half o[8] __attribute__((aligned(16)));
#pragma unroll
        for (int h = 0; h < 8; ++h) {
            const float* mp = Ms + l * 128 + h * 16;
            float acc = 0.f;
#pragma unroll
            for (int d = 0; d < 16; ++d) acc += ea[d] * mp[d];
            o[h] = __float2half(acc);
        }
        *reinterpret_cast<uint4*>(eatt + ((size_t)l * EE + pos) * 8) =
            *reinterpret_cast<const uint4*>(o);
    }
}

// ---------- fused attention: direct-exp softmax, 8/4/1 unroll, fp16 out ----------
__global__ __launch_bounds__(128)
void fused_gat_kernel(const __half* __restrict__ qa, const __half* __restrict__ kv,
                      const __half* __restrict__ eatt_l,
                      const int* __restrict__ offs, const int* __restrict__ deg,
                      const int* __restrict__ csrc, __half* __restrict__ hout) {
    int lane = threadIdx.x & 63;
    int n = blockIdx.x * 2 + (threadIdx.x >> 6);
    if (n >= NN) return;
    int h = lane >> 3;
    int c2h = lane & 7;          // half2 index within head
    int chh = h * 8 + c2h;       // half2 index within 128-ch row

    float2 q = __half22float2(reinterpret_cast<const __half2*>(qa + (size_t)n * 128)[chh]);

    int start = offs[n], d = deg[n];
    const __half* ebase = eatt_l + (size_t)start * 8 + h;
    const int* sbase = csrc + start;

    float den = 0.f, acc0 = 0.f, acc1 = 0.f;
    int i = 0;
    for (; i + 8 <= d; i += 8) {
        int s[8]; float e[8]; __half2 kh[8], vh[8];
#pragma unroll
        for (int j = 0; j < 8; ++j) s[j] = sbase[i + j];
#pragma unroll
        for (int j = 0; j < 8; ++j) e[j] = __half2float(ebase[(size_t)(i + j) * 8]);
#pragma unroll
        for (int j = 0; j < 8; ++j) {
            const __half2* ph = reinterpret_cast<const __half2*>(kv + (size_t)s[j] * 256);
            kh[j] = ph[chh];
            vh[j] = ph[64 + chh];
        }
#pragma unroll
        for (int j = 0; j < 8; ++j) {
            float2 k = __half22float2(kh[j]);
            float p = q.x * k.x + q.y * k.y;
            p += __shfl_xor(p, 1); p += __shfl_xor(p, 2); p += __shfl_xor(p, 4);
            float a = p + e[j]; a = a > 0.f ? a : 0.2f * a;
            a = fminf(a, 60.f);
            float w = __expf(a);
            float2 v = __half22float2(vh[j]);
            den += w; acc0 += w * v.x; acc1 += w * v.y;
        }
    }
    for (; i + 4 <= d; i += 4) {
        int s[4]; float e[4]; __half2 kh[4], vh[4];
#pragma unroll
        for (int j = 0; j < 4; ++j) s[j] = sbase[i + j];
#pragma unroll
        for (int j = 0; j < 4; ++j) e[j] = __half2float(ebase[(size_t)(i + j) * 8]);
#pragma unroll
        for (int j = 0; j < 4; ++j) {
            const __half2* ph = reinterpret_cast<const __half2*>(kv + (size_t)s[j] * 256);
            kh[j] = ph[chh];
            vh[j] = ph[64 + chh];
        }
#pragma unroll
        for (int j = 0; j < 4; ++j) {
            float2 k = __half22float2(kh[j]);
            float p = q.x * k.x + q.y * k.y;
            p += __shfl_xor(p, 1); p += __shfl_xor(p, 2); p += __shfl_xor(p, 4);
            float a = p + e[j]; a = a > 0.f ? a : 0.2f * a;
            a = fminf(a, 60.f);
            float w = __expf(a);
            float2 v = __half22float2(vh[j]);
            den += w; acc0 += w * v.x; acc1 += w * v.y;
        }
    }
    for (; i < d; ++i) {
        int s0 = sbase[i];
        float e0 = __half2float(ebase[(size_t)i * 8]);
        const __half2* ph = reinterpret_cast<const __half2*>(kv + (size_t)s0 * 256);
        float2 k = __half22float2(ph[chh]);
        float2 v = __half22float2(ph[64 + chh]);
        float p = q.x * k.x + q.y * k.y;
        p += __shfl_xor(p, 1); p += __shfl_xor(p, 2); p += __shfl_xor(p, 4);
        float a = p + e0; a = a > 0.f ? a : 0.2f * a;
        a = fminf(a, 60.f);
        float w = __expf(a);
        den += w; acc0 += w * v.x; acc1 += w * v.y;
    }
    float inv = 1.f / (den + 1e-16f);
    reinterpret_cast<__half2*>(hout + (size_t)n * 128)[chh] =
        __float22half2_rn(make_float2(acc0 * inv, acc1 * inv));
}

// ---------- BN stats (sum, sumsq per channel), fp16 input, uint4 loads ----------
__global__ __launch_bounds__(256)
void bn_stats_kernel(const __half* __restrict__ h, float* __restrict__ sums) {
    __shared__ float red[2][16][128];
    int t = threadIdx.x;
    int cg = t & 15;          // channel octet: channels cg*8 .. cg*8+7
    int rofs = t >> 4;        // 0..15
    int r0 = blockIdx.x * 64;
    int rend = min(NN, r0 + 64);
    float s1[8], s2[8];
#pragma unroll
    for (int j = 0; j < 8; ++j) { s1[j] = 0.f; s2[j] = 0.f; }
    for (int r = r0 + rofs; r < rend; r += 16) {
        uint4 raw = *reinterpret_cast<const uint4*>(h + (size_t)r * 128 + cg * 8);
        const __half* rh = reinterpret_cast<const __half*>(&raw);
#pragma unroll
        for (int j = 0; j < 8; ++j) {
            float v = __half2float(rh[j]);
            s1[j] += v; s2[j] += v * v;
        }
    }
#pragma unroll
    for (int j = 0; j < 8; ++j) {
        red[0][rofs][cg * 8 + j] = s1[j];
        red[1][rofs][cg * 8 + j] = s2[j];
    }
    __syncthreads();
    if (t < 128) {
        float a = 0.f, b = 0.f;
#pragma unroll
        for (int i = 0; i < 16; ++i) { a += red[0][i][t]; b += red[1][i][t]; }
        unsafeAtomicAdd(&sums[t], a);
        unsafeAtomicAdd(&sums[128 + t], b);
    }
}

// ---------- last layer: BN apply + segmented global max pool (batch sorted) ----------
__global__ __launch_bounds__(256)
void bn_pool_kernel(const __half* __restrict__ h, const float* __restrict__ sums,
                    const float* __restrict__ scale, const float* __restrict__ shift,
                    const int* __restrict__ batch, unsigned* __restrict__ gkey) {
    int t = threadIdx.x;
    int c = t & 127, half = t >> 7;
    int r0 = blockIdx.x * 32;
    int rend = min(NN, r0 + 32);
    const float invN = 1.f / (float)NN;
    float mu = sums[c] * invN;
    float var = sums[128 + c] * invN - mu * mu;
    float iscl = rsqrtf(var + 1e-5f) * scale[c];
    float sh = shift[c];
    int curg = -1;
    float lmax = -INFINITY;
    for (int r = r0 + half; r < rend; r += 2) {
        int g = batch[r];
        if (g != curg) {
            if (curg >= 0) atomicMax(&gkey[curg * 128 + c], f2key(lmax));
            curg = g;
            lmax = -INFINITY;
        }
        float v = (__half2float(h[(size_t)r * 128 + c]) - mu) * iscl + sh;
        lmax = fmaxf(lmax, v);
    }
    if (curg >= 0) atomicMax(&gkey[curg * 128 + c], f2key(lmax));
}

// ---------- head MLP (single block) ----------
__global__ __launch_bounds__(256)
void head_kernel(const unsigned* __restrict__ gkey,
                 const float* __restrict__ W1, const float* __restrict__ b1,
                 const float* __restrict__ bn1s, const float* __restrict__ bn1b,
                 const float* __restrict__ W2, const float* __restrict__ b2,
                 const float* __restrict__ bn2s, const float* __restrict__ bn2b,
                 const float* __restrict__ Wout, const float* __restrict__ bout,
                 float* __restrict__ out) {
    __shared__ float g[64][128];
    __shared__ float z1[64][64];
    __shared__ float z2[64][32];
    int t = threadIdx.x;
    for (int i = t; i < 64 * 128; i += 256) g[i >> 7][i & 127] = key2f(gkey[i]);
    __syncthreads();
    for (int i = t; i < 64 * 64; i += 256) {
        int r = i >> 6, o = i & 63;
        const float* gr = g[r];
        const float* wr = W1 + (size_t)o * 128;
        float acc = b1[o];
        for (int k2 = 0; k2 < 128; ++k2) acc += gr[k2] * wr[k2];
        z1[r][o] = acc;
    }
    __syncthreads();
    if (t < 64) {
        float s1 = 0.f, s2 = 0.f;
        for (int r = 0; r < 64; ++r) { float v = z1[r][t]; s1 += v; s2 += v * v; }
        float mu = s1 * (1.f / 64.f), var = s2 * (1.f / 64.f) - mu * mu;
        float inv = rsqrtf(var + 1e-5f) * bn1s[t];
        float sh = bn1b[t];
        for (int r = 0; r < 64; ++r) {
            float v = (z1[r][t] - mu) * inv + sh;
            z1[r][t] = v > 0.f ? v : 0.f;
        }
    }
    __syncthreads();
    for (int i = t; i < 64 * 32; i += 256) {
        int r = i >> 5, o = i & 31;
        const float* wr = W2 + (size_t)o * 64;
        float acc = b2[o];
        for (int k2 = 0; k2 < 64; ++k2) acc += z1[r][k2] * wr[k2];
        z2[r][o] = acc;
    }
    __syncthreads();
    if (t < 32) {
        float s1 = 0.f, s2 = 0.f;
        for (int r = 0; r < 64; ++r) { float v = z2[r][t]; s1 += v; s2 += v * v; }
        float mu = s1 * (1.f / 64.f), var = s2 * (1.f / 64.f) - mu * mu;
        float inv = rsqrtf(var + 1e-5f) * bn2s[t];
        float sh = bn2b[t];
        for (int r = 0; r < 64; ++r) {
            float v = (z2[r][t] - mu) * inv + sh;
            z2[r][t] = v > 0.f ? v : 0.f;
        }
    }
    __syncthreads();
    for (int i = t; i < 64 * 64; i += 256) {
        int r = i >> 6, o = i & 63;
        const float* wr = Wout + (size_t)o * 32;
        float acc = bout[o];
        for (int k2 = 0; k2 < 32; ++k2) acc += z2[r][k2] * wr[k2];
        out[r * 64 + o] = acc;
    }
}

extern "C" void kernel_launch(void* const* d_in, const int* in_sizes, int n_in,
                              void* d_out, int out_size, void* d_ws, size_t ws_size,
                              hipStream_t stream) {
    const float* x         = (const float*)d_in[0];
    const int*   ei        = (const int*)d_in[1];
    const float* edge_attr = (const float*)d_in[2];
    const int*   batch     = (const int*)d_in[3];
    const float* lin_qkv   = (const float*)d_in[4];
    const float* lin_edge  = (const float*)d_in[5];
    const float* att       = (const float*)d_in[6];
    // d_in[7] gat_bias: cancels exactly under training-mode BN (mean-subtracted)
    const float* bn_scale  = (const float*)d_in[8];
    const float* bn_bias   = (const float*)d_in[9];
    const float* W1   = (const float*)d_in[10];
    const float* b1   = (const float*)d_in[11];
    const float* bn1s = (const float*)d_in[12];
    const float* bn1b = (const float*)d_in[13];
    const float* W2   = (const float*)d_in[14];
    const float* b2   = (const float*)d_in[15];
    const float* bn2s = (const float*)d_in[16];
    const float* bn2b = (const float*)d_in[17];
    const float* Wout = (const float*)d_in[18];
    const float* bout = (const float*)d_in[19];

    float* ws = (float*)d_ws;
    size_t off = 0;
    auto alloc = [&](size_t n) { float* p = ws + off; off += n; return p; };
    // contiguous zero-region first: deg | gkey | gsums[3][256]
    int*      deg   = (int*)alloc(NN);
    unsigned* gkey  = (unsigned*)alloc(64 * 128);
    float*    gsums = alloc(3 * 256);
    const size_t zeroBytes = ((size_t)NN + 64 * 128 + 3 * 256) * 4;
    __half* hout = (__half*)alloc((size_t)NN * 64);   // NN*128 halves
    __half* qa   = (__half*)alloc((size_t)NN * 64);
    __half* kv   = (__half*)alloc((size_t)NN * 128);  // k|v interleaved, fp16
    __half* Apack = (__half*)alloc((size_t)MB * 8192);  // MB*16384 halves
    __half* Wpack = (__half*)alloc(9 * 8192);           // 9*16384 halves
    int*    offs   = (int*)alloc(NN);
    int*    cursor = (int*)alloc(NN);
    int*    csrc   = (int*)alloc(EE);
    __half* eatt   = (__half*)alloc((size_t)3 * EE * 4);  // [l][EE][8] fp16
    int*    psum   = (int*)alloc(256);
    int*    psx    = (int*)alloc(256);
    float*  M      = alloc(3 * 128);

    const int edgeBlocks = (EE + 255) / 256;     // 1563
    const int scanBlocks = (NN + 255) / 256;     // 196
    const int packBlocks = MB * 8;               // 3128
    const int statBlocks = (NN + 63) / 64;       // 782
    const int poolBlocks = (NN + 31) / 32;       // 1563
    const int gatBlocks  = (NN + 1) / 2;         // 25000

    hipMemsetAsync(deg, 0, zeroBytes, stream);
    wpack_kernel<<<72, 256, 0, stream>>>(lin_qkv, Wpack);
    compute_M_kernel<<<2, 256, 0, stream>>>(lin_edge, att, M);
    deg_count_kernel<<<edgeBlocks, 256, 0, stream>>>(ei, deg);
    scan_partial_kernel<<<scanBlocks, 256, 0, stream>>>(deg, psum);
    scan_top_kernel<<<1, 256, 0, stream>>>(psum, psx);
    scan_final_kernel<<<scanBlocks, 256, 0, stream>>>(deg, psx, offs, cursor);
    scatter_eatt_kernel<<<edgeBlocks, 256, 0, stream>>>(ei, edge_attr, M, cursor, csrc, eatt);
    pack_x_kernel<<<packBlocks, 256, 0, stream>>>(x, Apack);

    for (int l = 0; l < 3; ++l) {
        qkv_mfma_kernel<<<dim3(MB, 3), 256, 0, stream>>>(
            Apack, Wpack, l, att + (size_t)l * 384, qa, kv);

        fused_gat_kernel<<<gatBlocks, 128, 0, stream>>>(
            qa, kv, eatt + (size_t)l * EE * 8, offs, deg, csrc, hout);

        bn_stats_kernel<<<statBlocks, 256, 0, stream>>>(hout, gsums + l * 256);

        if (l < 2) {
            pack_h_kernel<<<packBlocks, 256, 0, stream>>>(
                hout, gsums + l * 256, bn_scale + l * 128, bn_bias + l * 128, Apack);
        } else {
            bn_pool_kernel<<<poolBlocks, 256, 0, stream>>>(
                hout, gsums + l * 256, bn_scale + l * 128, bn_bias + l * 128, batch, gkey);
        }
    }

    head_kernel<<<1, 256, 0, stream>>>(gkey, W1, b1, bn1s, bn1b, W2, b2, bn2s, bn2b, Wout, bout, (float*)d_out);
}